// Round 2
// baseline (5538.645 us; speedup 1.0000x reference)
//
#include <hip/hip_runtime.h>
#include <stdint.h>

#define S_LEN 2048
#define DM    768
#define NHEAD 8
#define HDIM  96
#define HDP   128
#define FF    3072
#define NEXP  4
#define NTOK  4096
#define NBH   16

typedef unsigned short u16;
typedef short bf16x8 __attribute__((ext_vector_type(8)));
typedef float f32x4 __attribute__((ext_vector_type(4)));
typedef __attribute__((address_space(1))) void* gptr_t;
typedef __attribute__((address_space(3))) void* lptr_t;

__device__ __forceinline__ u16 f2bf(float f) {
  union { float f; uint32_t u; } v; v.f = f;
  uint32_t r = v.u + 0x7FFFu + ((v.u >> 16) & 1u);
  return (u16)(r >> 16);
}
__device__ __forceinline__ float bf2f(u16 h) {
  union { uint32_t u; float f; } v; v.u = ((uint32_t)h) << 16;
  return v.f;
}
__device__ __forceinline__ void split2(float f, u16& hi, u16& lo) {
  u16 h = f2bf(f);
  lo = f2bf(f - bf2f(h));
  hi = h;
}
__device__ __forceinline__ void gload16(const void* g, void* l) {
  __builtin_amdgcn_global_load_lds((gptr_t)(void*)g, (lptr_t)l, 16, 0, 0);
}

// ---------------------------------------------------------------------------
// Plain NT GEMM: C[M,N] = A[M,K] @ B[N,K]^T (both bf16 row-major with leading
// dims lda/ldb). MODE: 0 = write f32, 1 = accumulate f32, 2 = write bf16.
// ---------------------------------------------------------------------------
template<int MODE>
__global__ __launch_bounds__(256) void gemm_nt(
    const u16* __restrict__ A, const u16* __restrict__ B, void* __restrict__ Cv,
    int M, int N, int K, int lda, int ldb, long sA, long sB, long sC)
{
  __shared__ u16 As[128 * 32];
  __shared__ u16 Bs[128 * 32];
  const int z = blockIdx.z;
  const u16* Az = A + (long)z * sA;
  const u16* Bz = B + (long)z * sB;
  const int brow = blockIdx.y << 7;
  const int bcol = blockIdx.x << 7;
  const int tid = threadIdx.x;
  const int wid = tid >> 6;
  const int lane = tid & 63;
  const int wr = (wid >> 1) << 6;
  const int wc = (wid & 1) << 6;

  f32x4 acc[4][4] = {};
  const int a0 = (wid << 11) + (lane << 4);

  for (int k0 = 0; k0 < K; k0 += 32) {
#pragma unroll
    for (int c = 0; c < 2; ++c) {
      int ab = a0 + (c << 10);
      int row = ab >> 6;
      int kcol = (ab & 63) >> 1;
      int ld = (wid << 11) + (c << 10);
      gload16(Az + (long)(brow + row) * lda + (k0 + kcol), (char*)As + ld);
      gload16(Bz + (long)(bcol + row) * ldb + (k0 + kcol), (char*)Bs + ld);
    }
    __syncthreads();
    bf16x8 af[4], bfr[4];
    const int lr = lane & 15;
    const int lk = (lane >> 4) << 4;
#pragma unroll
    for (int m = 0; m < 4; ++m)
      af[m] = *(const bf16x8*)((const char*)As + (((wr + m * 16 + lr) << 6) + lk));
#pragma unroll
    for (int n = 0; n < 4; ++n)
      bfr[n] = *(const bf16x8*)((const char*)Bs + (((wc + n * 16 + lr) << 6) + lk));
#pragma unroll
    for (int m = 0; m < 4; ++m)
#pragma unroll
      for (int n = 0; n < 4; ++n)
        acc[m][n] = __builtin_amdgcn_mfma_f32_16x16x32_bf16(af[m], bfr[n], acc[m][n], 0, 0, 0);
    __syncthreads();
  }

  const int crow0 = brow + wr + ((lane >> 4) << 2);
  const int ccol0 = bcol + wc + (lane & 15);
  const long cbase = (long)z * sC;
#pragma unroll
  for (int m = 0; m < 4; ++m)
#pragma unroll
    for (int n = 0; n < 4; ++n)
#pragma unroll
      for (int j = 0; j < 4; ++j) {
        long idx = cbase + (long)(crow0 + m * 16 + j) * N + (ccol0 + n * 16);
        float v = acc[m][n][j];
        if constexpr (MODE == 2) ((u16*)Cv)[idx] = f2bf(v);
        else if constexpr (MODE == 1) ((float*)Cv)[idx] += v;
        else ((float*)Cv)[idx] = v;
      }
}

// ---------------------------------------------------------------------------
// Split (bf16x3) NT GEMM: C = (Ah+Al) @ (Bh+Bl)^T dropping Al*Bl.
// fp32-equivalent accuracy. MODE: 0 = write f32, 1 = accumulate f32.
// ---------------------------------------------------------------------------
template<int MODE>
__global__ __launch_bounds__(256) void gemm3_nt(
    const u16* __restrict__ Ah, const u16* __restrict__ Al,
    const u16* __restrict__ Bh, const u16* __restrict__ Bl,
    float* __restrict__ C,
    int M, int N, int K, int lda, int ldb, long sA, long sB, long sC)
{
  __shared__ u16 Ash[128 * 32], Asl[128 * 32], Bsh[128 * 32], Bsl[128 * 32];
  const int z = blockIdx.z;
  const u16* Azh = Ah + (long)z * sA;
  const u16* Azl = Al + (long)z * sA;
  const u16* Bzh = Bh + (long)z * sB;
  const u16* Bzl = Bl + (long)z * sB;
  const int brow = blockIdx.y << 7;
  const int bcol = blockIdx.x << 7;
  const int tid = threadIdx.x;
  const int wid = tid >> 6;
  const int lane = tid & 63;
  const int wr = (wid >> 1) << 6;
  const int wc = (wid & 1) << 6;

  f32x4 acc[4][4] = {};
  const int a0 = (wid << 11) + (lane << 4);

  for (int k0 = 0; k0 < K; k0 += 32) {
#pragma unroll
    for (int c = 0; c < 2; ++c) {
      int ab = a0 + (c << 10);
      int row = ab >> 6;
      int kcol = (ab & 63) >> 1;
      long ao = (long)(brow + row) * lda + (k0 + kcol);
      long bo = (long)(bcol + row) * ldb + (k0 + kcol);
      int ld = (wid << 11) + (c << 10);
      gload16(Azh + ao, (char*)Ash + ld);
      gload16(Azl + ao, (char*)Asl + ld);
      gload16(Bzh + bo, (char*)Bsh + ld);
      gload16(Bzl + bo, (char*)Bsl + ld);
    }
    __syncthreads();
    const int lr = lane & 15;
    const int lk = (lane >> 4) << 4;
    bf16x8 ah[4], al[4], bh[4], bl[4];
#pragma unroll
    for (int m = 0; m < 4; ++m) {
      int off = ((wr + m * 16 + lr) << 6) + lk;
      ah[m] = *(const bf16x8*)((const char*)Ash + off);
      al[m] = *(const bf16x8*)((const char*)Asl + off);
    }
#pragma unroll
    for (int n = 0; n < 4; ++n) {
      int off = ((wc + n * 16 + lr) << 6) + lk;
      bh[n] = *(const bf16x8*)((const char*)Bsh + off);
      bl[n] = *(const bf16x8*)((const char*)Bsl + off);
    }
#pragma unroll
    for (int m = 0; m < 4; ++m)
#pragma unroll
      for (int n = 0; n < 4; ++n) {
        acc[m][n] = __builtin_amdgcn_mfma_f32_16x16x32_bf16(al[m], bh[n], acc[m][n], 0, 0, 0);
        acc[m][n] = __builtin_amdgcn_mfma_f32_16x16x32_bf16(ah[m], bl[n], acc[m][n], 0, 0, 0);
        acc[m][n] = __builtin_amdgcn_mfma_f32_16x16x32_bf16(ah[m], bh[n], acc[m][n], 0, 0, 0);
      }
    __syncthreads();
  }

  const int crow0 = brow + wr + ((lane >> 4) << 2);
  const int ccol0 = bcol + wc + (lane & 15);
  const long cbase = (long)z * sC;
#pragma unroll
  for (int m = 0; m < 4; ++m)
#pragma unroll
    for (int n = 0; n < 4; ++n)
#pragma unroll
      for (int j = 0; j < 4; ++j) {
        long idx = cbase + (long)(crow0 + m * 16 + j) * N + (ccol0 + n * 16);
        if constexpr (MODE == 1) C[idx] += acc[m][n][j];
        else C[idx] = acc[m][n][j];
      }
}

// ---------------------------------------------------------------------------
// fp32 [R][C] -> bf16 hi/lo [C][R]  (weight convert + transpose + split)
// grid (C/32, R/32), block (32,8)
// ---------------------------------------------------------------------------
__global__ void wconv_t(const float* __restrict__ in, u16* __restrict__ outh,
                        u16* __restrict__ outl, int R, int C) {
  __shared__ float tile[32][33];
  int c0 = blockIdx.x << 5, r0 = blockIdx.y << 5;
  int tx = threadIdx.x;
  for (int rr = threadIdx.y; rr < 32; rr += 8)
    tile[rr][tx] = in[(long)(r0 + rr) * C + (c0 + tx)];
  __syncthreads();
  for (int rr = threadIdx.y; rr < 32; rr += 8) {
    u16 h, l; split2(tile[tx][rr], h, l);
    long o = (long)(c0 + rr) * R + (r0 + tx);
    outh[o] = h; outl[o] = l;
  }
}

// ---------------------------------------------------------------------------
// LayerNorm over D=768. One block (256 thr) per row.
// ---------------------------------------------------------------------------
__global__ __launch_bounds__(256) void ln_k(const float* __restrict__ in,
    const float* __restrict__ g, const float* __restrict__ b,
    float* __restrict__ outf, u16* __restrict__ outh, u16* __restrict__ outl) {
  int row = blockIdx.x;
  const float* x = in + (long)row * DM;
  int tid = threadIdx.x;
  float v[3], s = 0.f, ss = 0.f;
#pragma unroll
  for (int i = 0; i < 3; ++i) { v[i] = x[tid + (i << 8)]; s += v[i]; ss += v[i] * v[i]; }
  __shared__ float red[2][4];
  for (int o = 32; o; o >>= 1) { s += __shfl_down(s, o); ss += __shfl_down(ss, o); }
  int wid = tid >> 6, lane = tid & 63;
  if (!lane) { red[0][wid] = s; red[1][wid] = ss; }
  __syncthreads();
  s = red[0][0] + red[0][1] + red[0][2] + red[0][3];
  ss = red[1][0] + red[1][1] + red[1][2] + red[1][3];
  float mean = s * (1.f / DM);
  float var = ss * (1.f / DM) - mean * mean;
  float rs = rsqrtf(var + 1e-5f);
#pragma unroll
  for (int i = 0; i < 3; ++i) {
    int c = tid + (i << 8);
    float y = (v[i] - mean) * rs * g[c] + b[c];
    if (outf) outf[(long)row * DM + c] = y;
    if (outh) { u16 h, l; split2(y, h, l); outh[(long)row * DM + c] = h; outl[(long)row * DM + c] = l; }
  }
}

// ---------------------------------------------------------------------------
// 3D-RoPE tables: cos/sin [S][96].
// ---------------------------------------------------------------------------
__global__ void rope_tables_k(float* __restrict__ cosT, float* __restrict__ sinT) {
  int s = blockIdx.x, d = threadIdx.x;
  int xc = s & 15, y = (s >> 4) & 15, t = s >> 8;
  int axis = d / 32, fi = d & 15;
  int coord = axis == 0 ? xc : (axis == 1 ? y : t);
  float inv = powf(10000.0f, -(float)fi / 16.0f);
  float ang = (float)coord * inv;
  cosT[s * HDIM + d] = cosf(ang);
  sinT[s * HDIM + d] = sinf(ang);
}

// ---------------------------------------------------------------------------
// RoPE apply + head split + pad to 128 + hi/lo split.
// ---------------------------------------------------------------------------
__global__ __launch_bounds__(256) void rope_apply_k(const float* __restrict__ qkv,
    const float* __restrict__ cosT, const float* __restrict__ sinT,
    u16* __restrict__ qh, u16* __restrict__ ql,
    u16* __restrict__ kh, u16* __restrict__ kl) {
  int bs = blockIdx.x;
  int b = bs >> 11, s = bs & 2047;
  const float* base = qkv + ((long)(b * S_LEN + s) * 3) * DM;
  for (int idx = threadIdx.x; idx < DM; idx += 256) {
    int h = idx / HDIM, d = idx - h * HDIM;
    float c = cosT[s * HDIM + d], sn = sinT[s * HDIM + d];
    int pair = (d < 48) ? idx + 48 : idx - 48;
    float qv = base[idx], kv = base[DM + idx];
    float qr = (d < 48) ? -base[pair] : base[pair];
    float kr = (d < 48) ? -base[DM + pair] : base[DM + pair];
    long o = ((long)(b * NHEAD + h) * S_LEN + s) * HDP + d;
    u16 hh, ll;
    split2(qv * c + qr * sn, hh, ll); qh[o] = hh; ql[o] = ll;
    split2(kv * c + kr * sn, hh, ll); kh[o] = hh; kl[o] = ll;
  }
  int t = threadIdx.x;
  int h = t >> 5, d = HDIM + (t & 31);
  long o = ((long)(b * NHEAD + h) * S_LEN + s) * HDP + d;
  qh[o] = 0; ql[o] = 0; kh[o] = 0; kl[o] = 0;
}

// ---------------------------------------------------------------------------
// V transpose (+pad, +split): qkv f32 -> vT hi/lo [BH][128][S]
// ---------------------------------------------------------------------------
__global__ void v_transpose_k(const float* __restrict__ qkv,
                              u16* __restrict__ vh, u16* __restrict__ vl) {
  __shared__ float tile[32][33];
  int bh = blockIdx.z, b = bh >> 3, h = bh & 7;
  int s0 = blockIdx.x << 5, d0 = blockIdx.y << 5;
  int tx = threadIdx.x;
  for (int r = threadIdx.y; r < 32; r += 8) {
    int s = s0 + r, d = d0 + tx;
    float v = 0.f;
    if (d < HDIM) v = qkv[((long)(b * S_LEN + s) * 3 + 2) * DM + h * HDIM + d];
    tile[r][tx] = v;
  }
  __syncthreads();
  for (int r = threadIdx.y; r < 32; r += 8) {
    int d = d0 + r;
    u16 hh, ll; split2(tile[tx][r], hh, ll);
    long o = ((long)bh * HDP + d) * S_LEN + (s0 + tx);
    vh[o] = hh; vl[o] = ll;
  }
}

// ---------------------------------------------------------------------------
// Row softmax over 2048 scores; writes probs hi/lo IN PLACE over the f32 row
// (hi at u16[0..2047], lo at u16[2048..4095]).
// ---------------------------------------------------------------------------
__global__ __launch_bounds__(256) void softmax_k(float* __restrict__ scores, float scale) {
  long row = blockIdx.x;
  float* src = scores + row * S_LEN;
  int tid = threadIdx.x;
  float v[8], m = -1e30f;
#pragma unroll
  for (int i = 0; i < 8; ++i) { v[i] = src[tid + (i << 8)]; m = fmaxf(m, v[i]); }
  __shared__ float red[4], red2[4];
  for (int o = 32; o; o >>= 1) m = fmaxf(m, __shfl_down(m, o));
  int wid = tid >> 6, lane = tid & 63;
  if (!lane) red[wid] = m;
  __syncthreads();
  m = fmaxf(fmaxf(red[0], red[1]), fmaxf(red[2], red[3]));
  float sum = 0.f;
#pragma unroll
  for (int i = 0; i < 8; ++i) { v[i] = expf((v[i] - m) * scale); sum += v[i]; }
  for (int o = 32; o; o >>= 1) sum += __shfl_down(sum, o);
  if (!lane) red2[wid] = sum;
  __syncthreads();
  sum = red2[0] + red2[1] + red2[2] + red2[3];
  float inv = 1.0f / sum;
  u16* dh = (u16*)src;
  u16* dl = dh + S_LEN;
#pragma unroll
  for (int i = 0; i < 8; ++i) {
    u16 h, l; split2(v[i] * inv, h, l);
    dh[tid + (i << 8)] = h; dl[tid + (i << 8)] = l;
  }
}

// o_head f32 [BH][S][128] -> o_merged hi/lo bf16 [B,S,768]
__global__ void o_merge_k(const float* __restrict__ oh,
                          u16* __restrict__ omh, u16* __restrict__ oml) {
  long i = (long)blockIdx.x * 256 + threadIdx.x;
  if (i >= (long)NTOK * DM) return;
  int c = (int)(i % DM);
  long bs = i / DM;
  int b = (int)(bs >> 11), s = (int)(bs & 2047);
  int h = c / HDIM, d = c - h * HDIM;
  u16 hh, ll; split2(oh[(((long)(b * NHEAD + h) * S_LEN + s) << 7) + d], hh, ll);
  omh[i] = hh; oml[i] = ll;
}

// Router: comb[tok][e].
__global__ __launch_bounds__(256) void router_k(const float* __restrict__ x,
    const float* __restrict__ gw, float* __restrict__ comb) {
  int tok = blockIdx.x * 4 + (threadIdx.x >> 6);
  int lane = threadIdx.x & 63;
  const float* xr = x + (long)tok * DM;
  float a0 = 0, a1 = 0, a2 = 0, a3 = 0;
  for (int i = lane; i < DM; i += 64) {
    float xv = xr[i];
    const float* g = gw + i * 4;
    a0 += xv * g[0]; a1 += xv * g[1]; a2 += xv * g[2]; a3 += xv * g[3];
  }
  for (int o = 32; o; o >>= 1) {
    a0 += __shfl_down(a0, o); a1 += __shfl_down(a1, o);
    a2 += __shfl_down(a2, o); a3 += __shfl_down(a3, o);
  }
  if (lane == 0) {
    float p[4] = {a0, a1, a2, a3};
    float mx = fmaxf(fmaxf(p[0], p[1]), fmaxf(p[2], p[3]));
    float s = 0.f;
    for (int e = 0; e < 4; ++e) { p[e] = expf(p[e] - mx); s += p[e]; }
    for (int e = 0; e < 4; ++e) p[e] /= s;
    int i1 = 0;
    for (int e = 1; e < 4; ++e) if (p[e] > p[i1]) i1 = e;
    int i2 = -1;
    for (int e = 0; e < 4; ++e) if (e != i1 && (i2 < 0 || p[e] > p[i2])) i2 = e;
    float ssum = p[i1] + p[i2] + 1e-5f;
    float out[4] = {0, 0, 0, 0};
    out[i1] = p[i1] / ssum; out[i2] = p[i2] / ssum;
    for (int e = 0; e < 4; ++e) comb[tok * 4 + e] = out[e];
  }
}

// split silu: hb = split( silu(g) * u * w ) from f32 g,u
__global__ void silu3_k(const float* __restrict__ g, const float* __restrict__ u,
                        const float* __restrict__ comb, int e,
                        u16* __restrict__ hbh, u16* __restrict__ hbl, long n, int tok0) {
  long i = (long)blockIdx.x * 256 + threadIdx.x;
  if (i >= n) return;
  float w = 1.0f;
  if (comb) { int tok = tok0 + (int)(i / FF); w = comb[tok * 4 + e]; }
  float gv = g[i], uv = u[i];
  float h = gv / (1.0f + expf(-gv)) * uv * w;
  u16 hh, ll; split2(h, hh, ll);
  hbh[i] = hh; hbl[i] = ll;
}

// plain silu (bf16 in/out) for layer-2 MoE
__global__ void silu_mul_k(const u16* __restrict__ g, const u16* __restrict__ u,
                           const float* __restrict__ comb, int e,
                           u16* __restrict__ hb, long n, int tok0) {
  long i = (long)blockIdx.x * 256 + threadIdx.x;
  if (i >= n) return;
  float w = 1.0f;
  if (comb) { int tok = tok0 + (int)(i / FF); w = comb[tok * 4 + e]; }
  float gv = bf2f(g[i]);
  float uv = bf2f(u[i]);
  float sil = gv / (1.0f + expf(-gv));
  hb[i] = f2bf(sil * uv * w);
}

__global__ void add_k(float* __restrict__ dst, const float* __restrict__ src, long n) {
  long i = (long)blockIdx.x * 256 + threadIdx.x;
  if (i < n) dst[i] += src[i];
}

__global__ void f2b_k(const float* __restrict__ src, u16* __restrict__ dst, long n) {
  long i = (long)blockIdx.x * 256 + threadIdx.x;
  if (i < n) dst[i] = f2bf(src[i]);
}

__global__ void f2bsplit_k(const float* __restrict__ src, u16* __restrict__ dh,
                           u16* __restrict__ dl, long n) {
  long i = (long)blockIdx.x * 256 + threadIdx.x;
  if (i < n) { u16 h, l; split2(src[i], h, l); dh[i] = h; dl[i] = l; }
}

// ---------------------------------------------------------------------------
static void gemm_launch(const void* A, const void* B, void* C, int M, int N, int K,
                        int lda, int ldb, long sA, long sB, long sC, int nb,
                        int mode, hipStream_t st) {
  dim3 g(N >> 7, M >> 7, nb), blk(256, 1, 1);
  if (mode == 0)
    gemm_nt<0><<<g, blk, 0, st>>>((const u16*)A, (const u16*)B, C, M, N, K, lda, ldb, sA, sB, sC);
  else if (mode == 1)
    gemm_nt<1><<<g, blk, 0, st>>>((const u16*)A, (const u16*)B, C, M, N, K, lda, ldb, sA, sB, sC);
  else
    gemm_nt<2><<<g, blk, 0, st>>>((const u16*)A, (const u16*)B, C, M, N, K, lda, ldb, sA, sB, sC);
}

static void gemm3_launch(const void* Ah, const void* Al, const void* Bh, const void* Bl,
                         float* C, int M, int N, int K, int lda, int ldb,
                         long sA, long sB, long sC, int nb, int mode, hipStream_t st) {
  dim3 g(N >> 7, M >> 7, nb), blk(256, 1, 1);
  if (mode == 0)
    gemm3_nt<0><<<g, blk, 0, st>>>((const u16*)Ah, (const u16*)Al, (const u16*)Bh,
                                   (const u16*)Bl, C, M, N, K, lda, ldb, sA, sB, sC);
  else
    gemm3_nt<1><<<g, blk, 0, st>>>((const u16*)Ah, (const u16*)Al, (const u16*)Bh,
                                   (const u16*)Bl, C, M, N, K, lda, ldb, sA, sB, sC);
}

extern "C" void kernel_launch(void* const* d_in, const int* in_sizes, int n_in,
                              void* d_out, int out_size, void* d_ws, size_t ws_size,
                              hipStream_t stream) {
  (void)in_sizes; (void)n_in; (void)out_size;
  const float* x_in  = (const float*)d_in[0];
  const float* ln1_g = (const float*)d_in[4];
  const float* ln1_b = (const float*)d_in[5];
  const float* w_qkv = (const float*)d_in[6];
  const float* w_out = (const float*)d_in[7];
  const float* gatew = (const float*)d_in[8];
  const float* eg    = (const float*)d_in[9];
  const float* eu    = (const float*)d_in[10];
  const float* ed    = (const float*)d_in[11];
  const float* sg    = (const float*)d_in[12];
  const float* su    = (const float*)d_in[13];
  const float* sd    = (const float*)d_in[14];
  const float* ln2_g = (const float*)d_in[15];
  const float* ln2_b = (const float*)d_in[16];

  float* xc = (float*)d_out;
  char* W = (char*)d_ws;
  size_t off = 0;
  auto alloc = [&](size_t bytes) {
    size_t o = off; off = (off + bytes + 255) & ~(size_t)255; return o;
  };
  size_t o_cos  = alloc((size_t)S_LEN * HDIM * 4);
  size_t o_sin  = alloc((size_t)S_LEN * HDIM * 4);
  size_t o_xnh  = alloc((size_t)NTOK * DM * 2);
  size_t o_xnl  = alloc((size_t)NTOK * DM * 2);
  size_t o_qkv  = alloc((size_t)NTOK * 3 * DM * 4);
  size_t o_qph  = alloc((size_t)NBH * S_LEN * HDP * 2);
  size_t o_qpl  = alloc((size_t)NBH * S_LEN * HDP * 2);
  size_t o_kph  = alloc((size_t)NBH * S_LEN * HDP * 2);
  size_t o_kpl  = alloc((size_t)NBH * S_LEN * HDP * 2);
  size_t o_vth  = alloc((size_t)NBH * HDP * S_LEN * 2);
  size_t o_vtl  = alloc((size_t)NBH * HDP * S_LEN * 2);
  size_t o_oh   = alloc((size_t)NBH * S_LEN * HDP * 4);
  size_t o_omh  = alloc((size_t)NTOK * DM * 2);
  size_t o_oml  = alloc((size_t)NTOK * DM * 2);
  size_t o_tmp  = alloc((size_t)NTOK * DM * 4);
  size_t o_comb = alloc((size_t)NTOK * 4 * 4);
  size_t o_wqh  = alloc((size_t)3 * DM * DM * 2);
  size_t o_wql  = alloc((size_t)3 * DM * DM * 2);
  size_t o_woh  = alloc((size_t)DM * DM * 2);
  size_t o_wol  = alloc((size_t)DM * DM * 2);
  size_t o_sgh  = alloc((size_t)FF * DM * 2);
  size_t o_sgl  = alloc((size_t)FF * DM * 2);
  size_t o_suh  = alloc((size_t)FF * DM * 2);
  size_t o_sul  = alloc((size_t)FF * DM * 2);
  size_t o_sdh  = alloc((size_t)DM * FF * 2);
  size_t o_sdl  = alloc((size_t)DM * FF * 2);
  size_t o_egh  = alloc((size_t)FF * DM * 2);
  size_t o_egl  = alloc((size_t)FF * DM * 2);
  size_t o_euh  = alloc((size_t)FF * DM * 2);
  size_t o_eul  = alloc((size_t)FF * DM * 2);
  size_t o_edh  = alloc((size_t)DM * FF * 2);
  size_t o_edl  = alloc((size_t)DM * FF * 2);
  size_t fixed_end = off;

  size_t avail = ws_size > fixed_end ? ws_size - fixed_end : 0;
  int nz = 1;
  { const int c[4] = {8, 4, 2, 1};
    for (int i = 0; i < 4; ++i) if ((size_t)c[i] * S_LEN * S_LEN * 4 <= avail) { nz = c[i]; break; } }
  int mc = 1024;
  { const int c[3] = {4096, 2048, 1024};
    for (int i = 0; i < 3; ++i) if ((size_t)c[i] * FF * 12 <= avail) { mc = c[i]; break; } }

  size_t o_sc  = fixed_end;                       // nz*S*S f32 (probs hi/lo in place)
  size_t o_ga  = fixed_end;                       // mc*FF f32
  size_t o_ua  = o_ga + (size_t)mc * FF * 4;
  size_t o_hbh = o_ua + (size_t)mc * FF * 4;      // mc*FF bf16
  size_t o_hbl = o_hbh + (size_t)mc * FF * 2;
  // layer-2 plain buffers (bf16), also overlapping the region
  size_t o_ga16 = fixed_end;
  size_t o_ua16 = o_ga16 + (size_t)mc * FF * 2;
  size_t o_hb16 = o_ua16 + (size_t)mc * FF * 2;

  float* cosT = (float*)(W + o_cos);
  float* sinT = (float*)(W + o_sin);
  u16*   xnh  = (u16*)(W + o_xnh);
  u16*   xnl  = (u16*)(W + o_xnl);
  float* qkv  = (float*)(W + o_qkv);
  u16 *qph = (u16*)(W + o_qph), *qpl = (u16*)(W + o_qpl);
  u16 *kph = (u16*)(W + o_kph), *kpl = (u16*)(W + o_kpl);
  u16 *vth = (u16*)(W + o_vth), *vtl = (u16*)(W + o_vtl);
  float* oh  = (float*)(W + o_oh);
  u16 *omh = (u16*)(W + o_omh), *oml = (u16*)(W + o_oml);
  float* tmp  = (float*)(W + o_tmp);
  float* comb = (float*)(W + o_comb);
  u16 *wqh = (u16*)(W + o_wqh), *wql = (u16*)(W + o_wql);
  u16 *woh = (u16*)(W + o_woh), *wol = (u16*)(W + o_wol);
  u16 *sgh = (u16*)(W + o_sgh), *sgl = (u16*)(W + o_sgl);
  u16 *suh = (u16*)(W + o_suh), *sul = (u16*)(W + o_sul);
  u16 *sdh = (u16*)(W + o_sdh), *sdl = (u16*)(W + o_sdl);
  u16 *egh = (u16*)(W + o_egh), *egl = (u16*)(W + o_egl);
  u16 *euh = (u16*)(W + o_euh), *eul = (u16*)(W + o_eul);
  u16 *edh = (u16*)(W + o_edh), *edl = (u16*)(W + o_edl);
  float* scores = (float*)(W + o_sc);
  float* gaF = (float*)(W + o_ga);
  float* uaF = (float*)(W + o_ua);
  u16 *hbh = (u16*)(W + o_hbh), *hbl = (u16*)(W + o_hbl);
  u16 *ga16 = (u16*)(W + o_ga16), *ua16 = (u16*)(W + o_ua16), *hb16 = (u16*)(W + o_hb16);

  const long ND = (long)NTOK * DM;
  const int gND = (int)((ND + 255) / 256);

  hipMemcpyAsync(xc, x_in, (size_t)ND * 4, hipMemcpyDeviceToDevice, stream);
  rope_tables_k<<<S_LEN, HDIM, 0, stream>>>(cosT, sinT);

  dim3 tb(32, 8, 1);
  for (int l = 0; l < 2; ++l) {
    const float* wqkv_l = w_qkv + (size_t)l * DM * 3 * DM;
    const float* wout_l = w_out + (size_t)l * DM * DM;
    const float* gw_l   = gatew + (size_t)l * DM * 4;
    const float* eg_l = eg + (size_t)l * NEXP * DM * FF;
    const float* eu_l = eu + (size_t)l * NEXP * DM * FF;
    const float* ed_l = ed + (size_t)l * NEXP * FF * DM;
    const float* sg_l = sg + (size_t)l * DM * FF;
    const float* su_l = su + (size_t)l * DM * FF;
    const float* sd_l = sd + (size_t)l * FF * DM;

    wconv_t<<<dim3(3 * DM / 32, DM / 32), tb, 0, stream>>>(wqkv_l, wqh, wql, DM, 3 * DM);
    wconv_t<<<dim3(DM / 32, DM / 32), tb, 0, stream>>>(wout_l, woh, wol, DM, DM);
    wconv_t<<<dim3(FF / 32, DM / 32), tb, 0, stream>>>(sg_l, sgh, sgl, DM, FF);
    wconv_t<<<dim3(FF / 32, DM / 32), tb, 0, stream>>>(su_l, suh, sul, DM, FF);
    wconv_t<<<dim3(DM / 32, FF / 32), tb, 0, stream>>>(sd_l, sdh, sdl, FF, DM);

    // --- attention (fp32-equivalent via bf16x3) ---
    ln_k<<<NTOK, 256, 0, stream>>>(xc, ln1_g + l * DM, ln1_b + l * DM, nullptr, xnh, xnl);
    gemm3_launch(xnh, xnl, wqh, wql, qkv, NTOK, 3 * DM, DM, DM, DM, 0, 0, 0, 1, 0, stream);
    rope_apply_k<<<NTOK, 256, 0, stream>>>(qkv, cosT, sinT, qph, qpl, kph, kpl);
    v_transpose_k<<<dim3(S_LEN / 32, HDP / 32, NBH), tb, 0, stream>>>(qkv, vth, vtl);
    int ng = NBH / nz;
    for (int g = 0; g < ng; ++g) {
      size_t qo = (size_t)g * nz * S_LEN * HDP;
      float* ohg = oh + qo;
      gemm3_launch(qph + qo, qpl + qo, kph + qo, kpl + qo, scores,
                   S_LEN, S_LEN, HDP, HDP, HDP,
                   (long)S_LEN * HDP, (long)S_LEN * HDP, (long)S_LEN * S_LEN, nz, 0, stream);
      softmax_k<<<nz * S_LEN, 256, 0, stream>>>(scores, 0.10206207261596575f);
      gemm3_launch((u16*)scores, (u16*)scores + S_LEN,
                   vth + (size_t)g * nz * HDP * S_LEN, vtl + (size_t)g * nz * HDP * S_LEN,
                   ohg, S_LEN, HDP, S_LEN, 2 * S_LEN, S_LEN,
                   (long)2 * S_LEN * S_LEN, (long)HDP * S_LEN, (long)S_LEN * HDP, nz, 0, stream);
    }
    o_merge_k<<<gND, 256, 0, stream>>>(oh, omh, oml);
    gemm3_launch(omh, oml, woh, wol, tmp, NTOK, DM, DM, DM, DM, 0, 0, 0, 1, 0, stream);
    add_k<<<gND, 256, 0, stream>>>(xc, tmp, ND);

    // --- router on fp32 x ---
    router_k<<<NTOK / 4, 256, 0, stream>>>(xc, gw_l, comb);

    int nch = NTOK / mc;
    if (l == 0) {
      // layer-0 MoE must be fp32-accurate (feeds layer-1 router)
      f2bsplit_k<<<gND, 256, 0, stream>>>(xc, xnh, xnl, ND);
      for (int c = 0; c < nch; ++c) {
        const u16* xfh = xnh + (size_t)c * mc * DM;
        const u16* xfl = xnl + (size_t)c * mc * DM;
        float* moc = tmp + (size_t)c * mc * DM;
        long nmc = (long)mc * FF;
        int gsz = (int)((nmc + 255) / 256);
        gemm3_launch(xfh, xfl, sgh, sgl, gaF, mc, FF, DM, DM, DM, 0, 0, 0, 1, 0, stream);
        gemm3_launch(xfh, xfl, suh, sul, uaF, mc, FF, DM, DM, DM, 0, 0, 0, 1, 0, stream);
        silu3_k<<<gsz, 256, 0, stream>>>(gaF, uaF, nullptr, 0, hbh, hbl, nmc, c * mc);
        gemm3_launch(hbh, hbl, sdh, sdl, moc, mc, DM, FF, FF, FF, 0, 0, 0, 1, 0, stream);
        for (int e = 0; e < NEXP; ++e) {
          wconv_t<<<dim3(FF / 32, DM / 32), tb, 0, stream>>>(eg_l + (size_t)e * DM * FF, egh, egl, DM, FF);
          wconv_t<<<dim3(FF / 32, DM / 32), tb, 0, stream>>>(eu_l + (size_t)e * DM * FF, euh, eul, DM, FF);
          wconv_t<<<dim3(DM / 32, FF / 32), tb, 0, stream>>>(ed_l + (size_t)e * FF * DM, edh, edl, FF, DM);
          gemm3_launch(xfh, xfl, egh, egl, gaF, mc, FF, DM, DM, DM, 0, 0, 0, 1, 0, stream);
          gemm3_launch(xfh, xfl, euh, eul, uaF, mc, FF, DM, DM, DM, 0, 0, 0, 1, 0, stream);
          silu3_k<<<gsz, 256, 0, stream>>>(gaF, uaF, comb, e, hbh, hbl, nmc, c * mc);
          gemm3_launch(hbh, hbl, edh, edl, moc, mc, DM, FF, FF, FF, 0, 0, 0, 1, 1, stream);
        }
      }
    } else {
      // layer-1 MoE: plain bf16 (only feeds final output through LN)
      f2b_k<<<gND, 256, 0, stream>>>(xc, xnh, ND);
      for (int c = 0; c < nch; ++c) {
        const u16* xfh = xnh + (size_t)c * mc * DM;
        float* moc = tmp + (size_t)c * mc * DM;
        long nmc = (long)mc * FF;
        int gsz = (int)((nmc + 255) / 256);
        gemm_launch(xfh, sgh, ga16, mc, FF, DM, DM, DM, 0, 0, 0, 1, 2, stream);
        gemm_launch(xfh, suh, ua16, mc, FF, DM, DM, DM, 0, 0, 0, 1, 2, stream);
        silu_mul_k<<<gsz, 256, 0, stream>>>(ga16, ua16, nullptr, 0, hb16, nmc, c * mc);
        gemm_launch(hb16, sdh, moc, mc, DM, FF, FF, FF, 0, 0, 0, 1, 0, stream);
        for (int e = 0; e < NEXP; ++e) {
          wconv_t<<<dim3(FF / 32, DM / 32), tb, 0, stream>>>(eg_l + (size_t)e * DM * FF, egh, egl, DM, FF);
          wconv_t<<<dim3(FF / 32, DM / 32), tb, 0, stream>>>(eu_l + (size_t)e * DM * FF, euh, eul, DM, FF);
          wconv_t<<<dim3(DM / 32, FF / 32), tb, 0, stream>>>(ed_l + (size_t)e * FF * DM, edh, edl, FF, DM);
          gemm_launch(xfh, egh, ga16, mc, FF, DM, DM, DM, 0, 0, 0, 1, 2, stream);
          gemm_launch(xfh, euh, ua16, mc, FF, DM, DM, DM, 0, 0, 0, 1, 2, stream);
          silu_mul_k<<<gsz, 256, 0, stream>>>(ga16, ua16, comb, e, hb16, nmc, c * mc);
          gemm_launch(hb16, edh, moc, mc, DM, FF, FF, FF, 0, 0, 0, 1, 1, stream);
        }
      }
    }
    add_k<<<gND, 256, 0, stream>>>(xc, tmp, ND);
    ln_k<<<NTOK, 256, 0, stream>>>(xc, ln2_g + l * DM, ln2_b + l * DM, xc, nullptr, nullptr);
  }
}

// Round 3
// 3573.279 us; speedup vs baseline: 1.5500x; 1.5500x over previous
//
#include <hip/hip_runtime.h>
#include <stdint.h>

#define S_LEN 2048
#define DM    768
#define NHEAD 8
#define HDIM  96
#define HDP   128
#define FF    3072
#define FF2   6144
#define NEXP  4
#define NTOK  4096
#define NBH   16

typedef unsigned short u16;
typedef short bf16x8 __attribute__((ext_vector_type(8)));
typedef float f32x4 __attribute__((ext_vector_type(4)));
typedef __attribute__((address_space(1))) void* gptr_t;
typedef __attribute__((address_space(3))) void* lptr_t;

__device__ __forceinline__ u16 f2bf(float f) {
  union { float f; uint32_t u; } v; v.f = f;
  uint32_t r = v.u + 0x7FFFu + ((v.u >> 16) & 1u);
  return (u16)(r >> 16);
}
__device__ __forceinline__ float bf2f(u16 h) {
  union { uint32_t u; float f; } v; v.u = ((uint32_t)h) << 16;
  return v.f;
}
__device__ __forceinline__ void split2(float f, u16& hi, u16& lo) {
  u16 h = f2bf(f);
  lo = f2bf(f - bf2f(h));
  hi = h;
}
__device__ __forceinline__ void gload16(const void* g, void* l) {
  __builtin_amdgcn_global_load_lds((gptr_t)(void*)g, (lptr_t)l, 16, 0, 0);
}

// ---------------------------------------------------------------------------
// Plain NT GEMM, 2-phase double-buffered.
// C[M,N] = A[M,K] @ B[N,K]^T. MODE: 0 f32 write, 2 bf16 write, 3 atomic f32.
// blockIdx.z = batch * kspl + kchunk (kspl>1 requires MODE 3).
// ---------------------------------------------------------------------------
template<int MODE>
__global__ __launch_bounds__(256) void gemm_nt(
    const u16* __restrict__ A, const u16* __restrict__ B, void* __restrict__ Cv,
    int M, int N, int K, int lda, int ldb, long sA, long sB, long sC, int kspl)
{
  __shared__ u16 As[2][128 * 32];
  __shared__ u16 Bs[2][128 * 32];
  const int z = blockIdx.z;
  const int bh = z / kspl;
  const int kc = z - bh * kspl;
  const u16* Az = A + (long)bh * sA;
  const u16* Bz = B + (long)bh * sB;
  const int brow = blockIdx.y << 7;
  const int bcol = blockIdx.x << 7;
  const int tid = threadIdx.x;
  const int wid = tid >> 6;
  const int lane = tid & 63;
  const int wr = (wid >> 1) << 6;
  const int wc = (wid & 1) << 6;

  f32x4 acc[4][4] = {};
  const int a0 = (wid << 11) + (lane << 4);

  auto stage = [&](int buf, int k0) {
#pragma unroll
    for (int c = 0; c < 2; ++c) {
      int ab = a0 + (c << 10);
      int row = ab >> 6;
      int kcol = (ab & 63) >> 1;
      int ld = (wid << 11) + (c << 10);
      gload16(Az + (long)(brow + row) * lda + (k0 + kcol), (char*)As[buf] + ld);
      gload16(Bz + (long)(bcol + row) * ldb + (k0 + kcol), (char*)Bs[buf] + ld);
    }
  };

  const int kt = K / kspl;
  const int kbeg = kc * kt;
  const int nt = kt >> 5;
  stage(0, kbeg);
  __syncthreads();
  for (int t = 0; t < nt; ++t) {
    const int cur = t & 1;
    if (t + 1 < nt) stage(cur ^ 1, kbeg + ((t + 1) << 5));
    bf16x8 af[4], bfr[4];
    const int lr = lane & 15;
    const int lk = (lane >> 4) << 4;
#pragma unroll
    for (int m = 0; m < 4; ++m)
      af[m] = *(const bf16x8*)((const char*)As[cur] + (((wr + m * 16 + lr) << 6) + lk));
#pragma unroll
    for (int n = 0; n < 4; ++n)
      bfr[n] = *(const bf16x8*)((const char*)Bs[cur] + (((wc + n * 16 + lr) << 6) + lk));
#pragma unroll
    for (int m = 0; m < 4; ++m)
#pragma unroll
      for (int n = 0; n < 4; ++n)
        acc[m][n] = __builtin_amdgcn_mfma_f32_16x16x32_bf16(af[m], bfr[n], acc[m][n], 0, 0, 0);
    if (t + 1 < nt) __syncthreads();
  }

  const int crow0 = brow + wr + ((lane >> 4) << 2);
  const int ccol0 = bcol + wc + (lane & 15);
  const long cbase = (long)bh * sC;
#pragma unroll
  for (int m = 0; m < 4; ++m)
#pragma unroll
    for (int n = 0; n < 4; ++n)
#pragma unroll
      for (int j = 0; j < 4; ++j) {
        long idx = cbase + (long)(crow0 + m * 16 + j) * N + (ccol0 + n * 16);
        float v = acc[m][n][j];
        if constexpr (MODE == 2) ((u16*)Cv)[idx] = f2bf(v);
        else if constexpr (MODE == 3) unsafeAtomicAdd((float*)Cv + idx, v);
        else ((float*)Cv)[idx] = v;
      }
}

// ---------------------------------------------------------------------------
// Split (bf16x3) NT GEMM, 2-phase double-buffered: C = (Ah+Al)@(Bh+Bl)^T
// minus Al*Bl. fp32-equivalent. MODE: 0 f32 write, 3 atomic f32.
// ---------------------------------------------------------------------------
template<int MODE>
__global__ __launch_bounds__(256) void gemm3_nt(
    const u16* __restrict__ Ah, const u16* __restrict__ Al,
    const u16* __restrict__ Bh, const u16* __restrict__ Bl,
    float* __restrict__ C,
    int M, int N, int K, int lda, int ldb, long sA, long sB, long sC, int kspl)
{
  __shared__ u16 Ash[2][128 * 32], Asl[2][128 * 32];
  __shared__ u16 Bsh[2][128 * 32], Bsl[2][128 * 32];
  const int z = blockIdx.z;
  const int bh = z / kspl;
  const int kc = z - bh * kspl;
  const u16* Azh = Ah + (long)bh * sA;
  const u16* Azl = Al + (long)bh * sA;
  const u16* Bzh = Bh + (long)bh * sB;
  const u16* Bzl = Bl + (long)bh * sB;
  const int brow = blockIdx.y << 7;
  const int bcol = blockIdx.x << 7;
  const int tid = threadIdx.x;
  const int wid = tid >> 6;
  const int lane = tid & 63;
  const int wr = (wid >> 1) << 6;
  const int wc = (wid & 1) << 6;

  f32x4 acc[4][4] = {};
  const int a0 = (wid << 11) + (lane << 4);

  auto stage = [&](int buf, int k0) {
#pragma unroll
    for (int c = 0; c < 2; ++c) {
      int ab = a0 + (c << 10);
      int row = ab >> 6;
      int kcol = (ab & 63) >> 1;
      long ao = (long)(brow + row) * lda + (k0 + kcol);
      long bo = (long)(bcol + row) * ldb + (k0 + kcol);
      int ld = (wid << 11) + (c << 10);
      gload16(Azh + ao, (char*)Ash[buf] + ld);
      gload16(Azl + ao, (char*)Asl[buf] + ld);
      gload16(Bzh + bo, (char*)Bsh[buf] + ld);
      gload16(Bzl + bo, (char*)Bsl[buf] + ld);
    }
  };

  const int kt = K / kspl;
  const int kbeg = kc * kt;
  const int nt = kt >> 5;
  stage(0, kbeg);
  __syncthreads();
  for (int t = 0; t < nt; ++t) {
    const int cur = t & 1;
    if (t + 1 < nt) stage(cur ^ 1, kbeg + ((t + 1) << 5));
    const int lr = lane & 15;
    const int lk = (lane >> 4) << 4;
    bf16x8 ah[4], al[4], bh_[4], bl[4];
#pragma unroll
    for (int m = 0; m < 4; ++m) {
      int off = ((wr + m * 16 + lr) << 6) + lk;
      ah[m] = *(const bf16x8*)((const char*)Ash[cur] + off);
      al[m] = *(const bf16x8*)((const char*)Asl[cur] + off);
    }
#pragma unroll
    for (int n = 0; n < 4; ++n) {
      int off = ((wc + n * 16 + lr) << 6) + lk;
      bh_[n] = *(const bf16x8*)((const char*)Bsh[cur] + off);
      bl[n] = *(const bf16x8*)((const char*)Bsl[cur] + off);
    }
#pragma unroll
    for (int m = 0; m < 4; ++m)
#pragma unroll
      for (int n = 0; n < 4; ++n) {
        acc[m][n] = __builtin_amdgcn_mfma_f32_16x16x32_bf16(al[m], bh_[n], acc[m][n], 0, 0, 0);
        acc[m][n] = __builtin_amdgcn_mfma_f32_16x16x32_bf16(ah[m], bl[n], acc[m][n], 0, 0, 0);
        acc[m][n] = __builtin_amdgcn_mfma_f32_16x16x32_bf16(ah[m], bh_[n], acc[m][n], 0, 0, 0);
      }
    if (t + 1 < nt) __syncthreads();
  }

  const int crow0 = brow + wr + ((lane >> 4) << 2);
  const int ccol0 = bcol + wc + (lane & 15);
  const long cbase = (long)bh * sC;
#pragma unroll
  for (int m = 0; m < 4; ++m)
#pragma unroll
    for (int n = 0; n < 4; ++n)
#pragma unroll
      for (int j = 0; j < 4; ++j) {
        long idx = cbase + (long)(crow0 + m * 16 + j) * N + (ccol0 + n * 16);
        if constexpr (MODE == 3) unsafeAtomicAdd(&C[idx], acc[m][n][j]);
        else C[idx] = acc[m][n][j];
      }
}

// ---------------------------------------------------------------------------
// fp32 [R][C] -> bf16 hi/lo [C][R]  (weight convert + transpose + split)
// ---------------------------------------------------------------------------
__global__ void wconv_t(const float* __restrict__ in, u16* __restrict__ outh,
                        u16* __restrict__ outl, int R, int C) {
  __shared__ float tile[32][33];
  int c0 = blockIdx.x << 5, r0 = blockIdx.y << 5;
  int tx = threadIdx.x;
  for (int rr = threadIdx.y; rr < 32; rr += 8)
    tile[rr][tx] = in[(long)(r0 + rr) * C + (c0 + tx)];
  __syncthreads();
  for (int rr = threadIdx.y; rr < 32; rr += 8) {
    u16 h, l; split2(tile[tx][rr], h, l);
    long o = (long)(c0 + rr) * R + (r0 + tx);
    outh[o] = h; outl[o] = l;
  }
}

__global__ __launch_bounds__(256) void ln_k(const float* __restrict__ in,
    const float* __restrict__ g, const float* __restrict__ b,
    float* __restrict__ outf, u16* __restrict__ outh, u16* __restrict__ outl) {
  int row = blockIdx.x;
  const float* x = in + (long)row * DM;
  int tid = threadIdx.x;
  float v[3], s = 0.f, ss = 0.f;
#pragma unroll
  for (int i = 0; i < 3; ++i) { v[i] = x[tid + (i << 8)]; s += v[i]; ss += v[i] * v[i]; }
  __shared__ float red[2][4];
  for (int o = 32; o; o >>= 1) { s += __shfl_down(s, o); ss += __shfl_down(ss, o); }
  int wid = tid >> 6, lane = tid & 63;
  if (!lane) { red[0][wid] = s; red[1][wid] = ss; }
  __syncthreads();
  s = red[0][0] + red[0][1] + red[0][2] + red[0][3];
  ss = red[1][0] + red[1][1] + red[1][2] + red[1][3];
  float mean = s * (1.f / DM);
  float var = ss * (1.f / DM) - mean * mean;
  float rs = rsqrtf(var + 1e-5f);
#pragma unroll
  for (int i = 0; i < 3; ++i) {
    int c = tid + (i << 8);
    float y = (v[i] - mean) * rs * g[c] + b[c];
    if (outf) outf[(long)row * DM + c] = y;
    if (outh) { u16 h, l; split2(y, h, l); outh[(long)row * DM + c] = h; outl[(long)row * DM + c] = l; }
  }
}

__global__ void rope_tables_k(float* __restrict__ cosT, float* __restrict__ sinT) {
  int s = blockIdx.x, d = threadIdx.x;
  int xc = s & 15, y = (s >> 4) & 15, t = s >> 8;
  int axis = d / 32, fi = d & 15;
  int coord = axis == 0 ? xc : (axis == 1 ? y : t);
  float inv = powf(10000.0f, -(float)fi / 16.0f);
  float ang = (float)coord * inv;
  cosT[s * HDIM + d] = cosf(ang);
  sinT[s * HDIM + d] = sinf(ang);
}

__global__ __launch_bounds__(256) void rope_apply_k(const float* __restrict__ qkv,
    const float* __restrict__ cosT, const float* __restrict__ sinT,
    u16* __restrict__ qh, u16* __restrict__ ql,
    u16* __restrict__ kh, u16* __restrict__ kl) {
  int bs = blockIdx.x;
  int b = bs >> 11, s = bs & 2047;
  const float* base = qkv + ((long)(b * S_LEN + s) * 3) * DM;
  for (int idx = threadIdx.x; idx < DM; idx += 256) {
    int h = idx / HDIM, d = idx - h * HDIM;
    float c = cosT[s * HDIM + d], sn = sinT[s * HDIM + d];
    int pair = (d < 48) ? idx + 48 : idx - 48;
    float qv = base[idx], kv = base[DM + idx];
    float qr = (d < 48) ? -base[pair] : base[pair];
    float kr = (d < 48) ? -base[DM + pair] : base[DM + pair];
    long o = ((long)(b * NHEAD + h) * S_LEN + s) * HDP + d;
    u16 hh, ll;
    split2(qv * c + qr * sn, hh, ll); qh[o] = hh; ql[o] = ll;
    split2(kv * c + kr * sn, hh, ll); kh[o] = hh; kl[o] = ll;
  }
  int t = threadIdx.x;
  int h = t >> 5, d = HDIM + (t & 31);
  long o = ((long)(b * NHEAD + h) * S_LEN + s) * HDP + d;
  qh[o] = 0; ql[o] = 0; kh[o] = 0; kl[o] = 0;
}

__global__ void v_transpose_k(const float* __restrict__ qkv,
                              u16* __restrict__ vh, u16* __restrict__ vl) {
  __shared__ float tile[32][33];
  int bh = blockIdx.z, b = bh >> 3, h = bh & 7;
  int s0 = blockIdx.x << 5, d0 = blockIdx.y << 5;
  int tx = threadIdx.x;
  for (int r = threadIdx.y; r < 32; r += 8) {
    int s = s0 + r, d = d0 + tx;
    float v = 0.f;
    if (d < HDIM) v = qkv[((long)(b * S_LEN + s) * 3 + 2) * DM + h * HDIM + d];
    tile[r][tx] = v;
  }
  __syncthreads();
  for (int r = threadIdx.y; r < 32; r += 8) {
    int d = d0 + r;
    u16 hh, ll; split2(tile[tx][r], hh, ll);
    long o = ((long)bh * HDP + d) * S_LEN + (s0 + tx);
    vh[o] = hh; vl[o] = ll;
  }
}

// Row softmax; probs hi/lo written in place over the f32 row.
__global__ __launch_bounds__(256) void softmax_k(float* __restrict__ scores, float scale) {
  long row = blockIdx.x;
  float* src = scores + row * S_LEN;
  int tid = threadIdx.x;
  float v[8], m = -1e30f;
#pragma unroll
  for (int i = 0; i < 8; ++i) { v[i] = src[tid + (i << 8)]; m = fmaxf(m, v[i]); }
  __shared__ float red[4], red2[4];
  for (int o = 32; o; o >>= 1) m = fmaxf(m, __shfl_down(m, o));
  int wid = tid >> 6, lane = tid & 63;
  if (!lane) red[wid] = m;
  __syncthreads();
  m = fmaxf(fmaxf(red[0], red[1]), fmaxf(red[2], red[3]));
  float sum = 0.f;
#pragma unroll
  for (int i = 0; i < 8; ++i) { v[i] = expf((v[i] - m) * scale); sum += v[i]; }
  for (int o = 32; o; o >>= 1) sum += __shfl_down(sum, o);
  if (!lane) red2[wid] = sum;
  __syncthreads();
  sum = red2[0] + red2[1] + red2[2] + red2[3];
  float inv = 1.0f / sum;
  u16* dh = (u16*)src;
  u16* dl = dh + S_LEN;
#pragma unroll
  for (int i = 0; i < 8; ++i) {
    u16 h, l; split2(v[i] * inv, h, l);
    dh[tid + (i << 8)] = h; dl[tid + (i << 8)] = l;
  }
}

__global__ void o_merge_k(const float* __restrict__ oh,
                          u16* __restrict__ omh, u16* __restrict__ oml) {
  long i = (long)blockIdx.x * 256 + threadIdx.x;
  if (i >= (long)NTOK * DM) return;
  int c = (int)(i % DM);
  long bs = i / DM;
  int b = (int)(bs >> 11), s = (int)(bs & 2047);
  int h = c / HDIM, d = c - h * HDIM;
  u16 hh, ll; split2(oh[(((long)(b * NHEAD + h) * S_LEN + s) << 7) + d], hh, ll);
  omh[i] = hh; oml[i] = ll;
}

__global__ __launch_bounds__(256) void router_k(const float* __restrict__ x,
    const float* __restrict__ gw, float* __restrict__ comb) {
  int tok = blockIdx.x * 4 + (threadIdx.x >> 6);
  int lane = threadIdx.x & 63;
  const float* xr = x + (long)tok * DM;
  float a0 = 0, a1 = 0, a2 = 0, a3 = 0;
  for (int i = lane; i < DM; i += 64) {
    float xv = xr[i];
    const float* g = gw + i * 4;
    a0 += xv * g[0]; a1 += xv * g[1]; a2 += xv * g[2]; a3 += xv * g[3];
  }
  for (int o = 32; o; o >>= 1) {
    a0 += __shfl_down(a0, o); a1 += __shfl_down(a1, o);
    a2 += __shfl_down(a2, o); a3 += __shfl_down(a3, o);
  }
  if (lane == 0) {
    float p[4] = {a0, a1, a2, a3};
    float mx = fmaxf(fmaxf(p[0], p[1]), fmaxf(p[2], p[3]));
    float s = 0.f;
    for (int e = 0; e < 4; ++e) { p[e] = expf(p[e] - mx); s += p[e]; }
    for (int e = 0; e < 4; ++e) p[e] /= s;
    int i1 = 0;
    for (int e = 1; e < 4; ++e) if (p[e] > p[i1]) i1 = e;
    int i2 = -1;
    for (int e = 0; e < 4; ++e) if (e != i1 && (i2 < 0 || p[e] > p[i2])) i2 = e;
    float ssum = p[i1] + p[i2] + 1e-5f;
    float out[4] = {0, 0, 0, 0};
    out[i1] = p[i1] / ssum; out[i2] = p[i2] / ssum;
    for (int e = 0; e < 4; ++e) comb[tok * 4 + e] = out[e];
  }
}

// fused-gu f32 [tok][2FF]: hb = split(silu(g)*u*w)
__global__ void silu3_k(const float* __restrict__ gu, const float* __restrict__ comb,
                        int e, u16* __restrict__ hbh, u16* __restrict__ hbl,
                        long n, int tok0) {
  long i = (long)blockIdx.x * 256 + threadIdx.x;
  if (i >= n) return;
  int tl = (int)(i / FF), j = (int)(i - (long)tl * FF);
  float gv = gu[(long)tl * FF2 + j];
  float uv = gu[(long)tl * FF2 + FF + j];
  float w = comb ? comb[(tok0 + tl) * 4 + e] : 1.0f;
  float h = gv / (1.0f + expf(-gv)) * uv * w;
  u16 hh, ll; split2(h, hh, ll);
  hbh[i] = hh; hbl[i] = ll;
}

// fused-gu bf16 [tok][2FF]: hb = bf16(silu(g)*u*w)
__global__ void silu_mul_k(const u16* __restrict__ gu, const float* __restrict__ comb,
                           int e, u16* __restrict__ hb, long n, int tok0) {
  long i = (long)blockIdx.x * 256 + threadIdx.x;
  if (i >= n) return;
  int tl = (int)(i / FF), j = (int)(i - (long)tl * FF);
  float gv = bf2f(gu[(long)tl * FF2 + j]);
  float uv = bf2f(gu[(long)tl * FF2 + FF + j]);
  float w = comb ? comb[(tok0 + tl) * 4 + e] : 1.0f;
  hb[i] = f2bf(gv / (1.0f + expf(-gv)) * uv * w);
}

__global__ void add_k(float* __restrict__ dst, const float* __restrict__ src, long n) {
  long i = (long)blockIdx.x * 256 + threadIdx.x;
  if (i < n) dst[i] += src[i];
}

__global__ void zero_k(float* __restrict__ dst, long n) {
  long i = (long)blockIdx.x * 256 + threadIdx.x;
  if (i < n) dst[i] = 0.f;
}

__global__ void f2b_k(const float* __restrict__ src, u16* __restrict__ dst, long n) {
  long i = (long)blockIdx.x * 256 + threadIdx.x;
  if (i < n) dst[i] = f2bf(src[i]);
}

__global__ void f2bsplit_k(const float* __restrict__ src, u16* __restrict__ dh,
                           u16* __restrict__ dl, long n) {
  long i = (long)blockIdx.x * 256 + threadIdx.x;
  if (i < n) { u16 h, l; split2(src[i], h, l); dh[i] = h; dl[i] = l; }
}

// ---------------------------------------------------------------------------
static void gemm_launch(const void* A, const void* B, void* C, int M, int N, int K,
                        int lda, int ldb, long sA, long sB, long sC, int nb,
                        int kspl, int mode, hipStream_t st) {
  dim3 g(N >> 7, M >> 7, nb * kspl), blk(256, 1, 1);
  if (mode == 0)
    gemm_nt<0><<<g, blk, 0, st>>>((const u16*)A, (const u16*)B, C, M, N, K, lda, ldb, sA, sB, sC, kspl);
  else if (mode == 2)
    gemm_nt<2><<<g, blk, 0, st>>>((const u16*)A, (const u16*)B, C, M, N, K, lda, ldb, sA, sB, sC, kspl);
  else
    gemm_nt<3><<<g, blk, 0, st>>>((const u16*)A, (const u16*)B, C, M, N, K, lda, ldb, sA, sB, sC, kspl);
}

static void gemm3_launch(const void* Ah, const void* Al, const void* Bh, const void* Bl,
                         float* C, int M, int N, int K, int lda, int ldb,
                         long sA, long sB, long sC, int nb, int kspl, int mode,
                         hipStream_t st) {
  dim3 g(N >> 7, M >> 7, nb * kspl), blk(256, 1, 1);
  if (mode == 0)
    gemm3_nt<0><<<g, blk, 0, st>>>((const u16*)Ah, (const u16*)Al, (const u16*)Bh,
                                   (const u16*)Bl, C, M, N, K, lda, ldb, sA, sB, sC, kspl);
  else
    gemm3_nt<3><<<g, blk, 0, st>>>((const u16*)Ah, (const u16*)Al, (const u16*)Bh,
                                   (const u16*)Bl, C, M, N, K, lda, ldb, sA, sB, sC, kspl);
}

extern "C" void kernel_launch(void* const* d_in, const int* in_sizes, int n_in,
                              void* d_out, int out_size, void* d_ws, size_t ws_size,
                              hipStream_t stream) {
  (void)in_sizes; (void)n_in; (void)out_size;
  const float* x_in  = (const float*)d_in[0];
  const float* ln1_g = (const float*)d_in[4];
  const float* ln1_b = (const float*)d_in[5];
  const float* w_qkv = (const float*)d_in[6];
  const float* w_out = (const float*)d_in[7];
  const float* gatew = (const float*)d_in[8];
  const float* eg    = (const float*)d_in[9];
  const float* eu    = (const float*)d_in[10];
  const float* ed    = (const float*)d_in[11];
  const float* sg    = (const float*)d_in[12];
  const float* su    = (const float*)d_in[13];
  const float* sd    = (const float*)d_in[14];
  const float* ln2_g = (const float*)d_in[15];
  const float* ln2_b = (const float*)d_in[16];

  float* xc = (float*)d_out;
  char* W = (char*)d_ws;
  size_t off = 0;
  auto alloc = [&](size_t bytes) {
    size_t o = off; off = (off + bytes + 255) & ~(size_t)255; return o;
  };
  size_t o_cos  = alloc((size_t)S_LEN * HDIM * 4);
  size_t o_sin  = alloc((size_t)S_LEN * HDIM * 4);
  size_t o_xnh  = alloc((size_t)NTOK * DM * 2);
  size_t o_xnl  = alloc((size_t)NTOK * DM * 2);
  size_t o_qkv  = alloc((size_t)NTOK * 3 * DM * 4);
  size_t o_qph  = alloc((size_t)NBH * S_LEN * HDP * 2);
  size_t o_qpl  = alloc((size_t)NBH * S_LEN * HDP * 2);
  size_t o_kph  = alloc((size_t)NBH * S_LEN * HDP * 2);
  size_t o_kpl  = alloc((size_t)NBH * S_LEN * HDP * 2);
  size_t o_vth  = alloc((size_t)NBH * HDP * S_LEN * 2);
  size_t o_vtl  = alloc((size_t)NBH * HDP * S_LEN * 2);
  size_t o_oh   = alloc((size_t)NBH * S_LEN * HDP * 4);
  size_t o_omh  = alloc((size_t)NTOK * DM * 2);
  size_t o_oml  = alloc((size_t)NTOK * DM * 2);
  size_t o_tmp  = alloc((size_t)NTOK * DM * 4);
  size_t o_comb = alloc((size_t)NTOK * 4 * 4);
  size_t o_wqh  = alloc((size_t)3 * DM * DM * 2);
  size_t o_wql  = alloc((size_t)3 * DM * DM * 2);
  size_t o_woh  = alloc((size_t)DM * DM * 2);
  size_t o_wol  = alloc((size_t)DM * DM * 2);
  size_t o_sguh = alloc((size_t)FF2 * DM * 2);   // shared gate|up fused [2FF][DM]
  size_t o_sgul = alloc((size_t)FF2 * DM * 2);
  size_t o_sdh  = alloc((size_t)DM * FF * 2);
  size_t o_sdl  = alloc((size_t)DM * FF * 2);
  size_t o_eguh = alloc((size_t)FF2 * DM * 2);   // per-expert gate|up fused
  size_t o_egul = alloc((size_t)FF2 * DM * 2);
  size_t o_edh  = alloc((size_t)DM * FF * 2);
  size_t o_edl  = alloc((size_t)DM * FF * 2);
  size_t fixed_end = off;

  size_t avail = ws_size > fixed_end ? ws_size - fixed_end : 0;
  int nz = 1;
  { const int c[4] = {8, 4, 2, 1};
    for (int i = 0; i < 4; ++i) if ((size_t)c[i] * S_LEN * S_LEN * 4 <= avail) { nz = c[i]; break; } }
  int mc = 1024;
  { const int c[3] = {4096, 2048, 1024};
    for (int i = 0; i < 3; ++i) if ((size_t)c[i] * FF * 12 <= avail) { mc = c[i]; break; } }

  size_t o_sc   = fixed_end;                        // nz*S*S f32 (probs in place)
  size_t o_ga   = fixed_end;                        // mc*2FF f32 (fused gate|up)
  size_t o_hbh  = o_ga + (size_t)mc * FF2 * 4;
  size_t o_hbl  = o_hbh + (size_t)mc * FF * 2;
  size_t o_ga16 = fixed_end;                        // mc*2FF bf16 (layer-1)
  size_t o_hb16 = o_ga16 + (size_t)mc * FF2 * 2;

  float* cosT = (float*)(W + o_cos);
  float* sinT = (float*)(W + o_sin);
  u16*   xnh  = (u16*)(W + o_xnh);
  u16*   xnl  = (u16*)(W + o_xnl);
  float* qkv  = (float*)(W + o_qkv);
  u16 *qph = (u16*)(W + o_qph), *qpl = (u16*)(W + o_qpl);
  u16 *kph = (u16*)(W + o_kph), *kpl = (u16*)(W + o_kpl);
  u16 *vth = (u16*)(W + o_vth), *vtl = (u16*)(W + o_vtl);
  float* oh  = (float*)(W + o_oh);
  u16 *omh = (u16*)(W + o_omh), *oml = (u16*)(W + o_oml);
  float* tmp  = (float*)(W + o_tmp);
  float* comb = (float*)(W + o_comb);
  u16 *wqh = (u16*)(W + o_wqh), *wql = (u16*)(W + o_wql);
  u16 *woh = (u16*)(W + o_woh), *wol = (u16*)(W + o_wol);
  u16 *sguh = (u16*)(W + o_sguh), *sgul = (u16*)(W + o_sgul);
  u16 *sdh = (u16*)(W + o_sdh), *sdl = (u16*)(W + o_sdl);
  u16 *eguh = (u16*)(W + o_eguh), *egul = (u16*)(W + o_egul);
  u16 *edh = (u16*)(W + o_edh), *edl = (u16*)(W + o_edl);
  float* scores = (float*)(W + o_sc);
  float* gaF = (float*)(W + o_ga);
  u16 *hbh = (u16*)(W + o_hbh), *hbl = (u16*)(W + o_hbl);
  u16 *ga16 = (u16*)(W + o_ga16), *hb16 = (u16*)(W + o_hb16);

  const long ND = (long)NTOK * DM;
  const int gND = (int)((ND + 255) / 256);
  const long NOH = (long)NBH * S_LEN * HDP;
  const int gNOH = (int)((NOH + 255) / 256);

  hipMemcpyAsync(xc, x_in, (size_t)ND * 4, hipMemcpyDeviceToDevice, stream);
  rope_tables_k<<<S_LEN, HDIM, 0, stream>>>(cosT, sinT);

  dim3 tb(32, 8, 1);
  for (int l = 0; l < 2; ++l) {
    const float* wqkv_l = w_qkv + (size_t)l * DM * 3 * DM;
    const float* wout_l = w_out + (size_t)l * DM * DM;
    const float* gw_l   = gatew + (size_t)l * DM * 4;
    const float* eg_l = eg + (size_t)l * NEXP * DM * FF;
    const float* eu_l = eu + (size_t)l * NEXP * DM * FF;
    const float* ed_l = ed + (size_t)l * NEXP * FF * DM;
    const float* sg_l = sg + (size_t)l * DM * FF;
    const float* su_l = su + (size_t)l * DM * FF;
    const float* sd_l = sd + (size_t)l * FF * DM;

    wconv_t<<<dim3(3 * DM / 32, DM / 32), tb, 0, stream>>>(wqkv_l, wqh, wql, DM, 3 * DM);
    wconv_t<<<dim3(DM / 32, DM / 32), tb, 0, stream>>>(wout_l, woh, wol, DM, DM);
    wconv_t<<<dim3(FF / 32, DM / 32), tb, 0, stream>>>(sg_l, sguh, sgul, DM, FF);
    wconv_t<<<dim3(FF / 32, DM / 32), tb, 0, stream>>>(su_l, sguh + (size_t)FF * DM,
                                                       sgul + (size_t)FF * DM, DM, FF);
    wconv_t<<<dim3(DM / 32, FF / 32), tb, 0, stream>>>(sd_l, sdh, sdl, FF, DM);

    // --- attention (fp32-equivalent via bf16x3) ---
    ln_k<<<NTOK, 256, 0, stream>>>(xc, ln1_g + l * DM, ln1_b + l * DM, nullptr, xnh, xnl);
    gemm3_launch(xnh, xnl, wqh, wql, qkv, NTOK, 3 * DM, DM, DM, DM, 0, 0, 0, 1, 1, 0, stream);
    rope_apply_k<<<NTOK, 256, 0, stream>>>(qkv, cosT, sinT, qph, qpl, kph, kpl);
    v_transpose_k<<<dim3(S_LEN / 32, HDP / 32, NBH), tb, 0, stream>>>(qkv, vth, vtl);
    zero_k<<<gNOH, 256, 0, stream>>>(oh, NOH);
    int ng = NBH / nz;
    for (int g = 0; g < ng; ++g) {
      size_t qo = (size_t)g * nz * S_LEN * HDP;
      gemm3_launch(qph + qo, qpl + qo, kph + qo, kpl + qo, scores,
                   S_LEN, S_LEN, HDP, HDP, HDP,
                   (long)S_LEN * HDP, (long)S_LEN * HDP, (long)S_LEN * S_LEN, nz, 1, 0, stream);
      softmax_k<<<nz * S_LEN, 256, 0, stream>>>(scores, 0.10206207261596575f);
      // PV: split-K x8 for occupancy, atomic accumulate
      gemm3_launch((u16*)scores, (u16*)scores + S_LEN,
                   vth + (size_t)g * nz * HDP * S_LEN, vtl + (size_t)g * nz * HDP * S_LEN,
                   oh + qo, S_LEN, HDP, S_LEN, 2 * S_LEN, S_LEN,
                   (long)2 * S_LEN * S_LEN, (long)HDP * S_LEN, (long)S_LEN * HDP,
                   nz, 8, 3, stream);
    }
    o_merge_k<<<gND, 256, 0, stream>>>(oh, omh, oml);
    zero_k<<<gND, 256, 0, stream>>>(tmp, ND);
    gemm3_launch(omh, oml, woh, wol, tmp, NTOK, DM, DM, DM, DM, 0, 0, 0, 1, 2, 3, stream);
    add_k<<<gND, 256, 0, stream>>>(xc, tmp, ND);

    // --- router on fp32 x ---
    router_k<<<NTOK / 4, 256, 0, stream>>>(xc, gw_l, comb);

    int nch = NTOK / mc;
    zero_k<<<gND, 256, 0, stream>>>(tmp, ND);
    if (l == 0) {
      f2bsplit_k<<<gND, 256, 0, stream>>>(xc, xnh, xnl, ND);
      for (int c = 0; c < nch; ++c) {
        const u16 *xfh = xnh + (size_t)c * mc * DM, *xfl = xnl + (size_t)c * mc * DM;
        float* moc = tmp + (size_t)c * mc * DM;
        long nmc = (long)mc * FF;
        int gsz = (int)((nmc + 255) / 256);
        gemm3_launch(xfh, xfl, sguh, sgul, gaF, mc, FF2, DM, DM, DM, 0, 0, 0, 1, 1, 0, stream);
        silu3_k<<<gsz, 256, 0, stream>>>(gaF, nullptr, 0, hbh, hbl, nmc, c * mc);
        gemm3_launch(hbh, hbl, sdh, sdl, moc, mc, DM, FF, FF, FF, 0, 0, 0, 1, 4, 3, stream);
      }
      for (int e = 0; e < NEXP; ++e) {
        wconv_t<<<dim3(FF / 32, DM / 32), tb, 0, stream>>>(eg_l + (size_t)e * DM * FF, eguh, egul, DM, FF);
        wconv_t<<<dim3(FF / 32, DM / 32), tb, 0, stream>>>(eu_l + (size_t)e * DM * FF,
                                                           eguh + (size_t)FF * DM,
                                                           egul + (size_t)FF * DM, DM, FF);
        wconv_t<<<dim3(DM / 32, FF / 32), tb, 0, stream>>>(ed_l + (size_t)e * FF * DM, edh, edl, FF, DM);
        for (int c = 0; c < nch; ++c) {
          const u16 *xfh = xnh + (size_t)c * mc * DM, *xfl = xnl + (size_t)c * mc * DM;
          float* moc = tmp + (size_t)c * mc * DM;
          long nmc = (long)mc * FF;
          int gsz = (int)((nmc + 255) / 256);
          gemm3_launch(xfh, xfl, eguh, egul, gaF, mc, FF2, DM, DM, DM, 0, 0, 0, 1, 1, 0, stream);
          silu3_k<<<gsz, 256, 0, stream>>>(gaF, comb, e, hbh, hbl, nmc, c * mc);
          gemm3_launch(hbh, hbl, edh, edl, moc, mc, DM, FF, FF, FF, 0, 0, 0, 1, 4, 3, stream);
        }
      }
    } else {
      f2b_k<<<gND, 256, 0, stream>>>(xc, xnh, ND);
      for (int c = 0; c < nch; ++c) {
        const u16* xfh = xnh + (size_t)c * mc * DM;
        float* moc = tmp + (size_t)c * mc * DM;
        long nmc = (long)mc * FF;
        int gsz = (int)((nmc + 255) / 256);
        gemm_launch(xfh, sguh, ga16, mc, FF2, DM, DM, DM, 0, 0, 0, 1, 1, 2, stream);
        silu_mul_k<<<gsz, 256, 0, stream>>>(ga16, nullptr, 0, hb16, nmc, c * mc);
        gemm_launch(hb16, sdh, moc, mc, DM, FF, FF, FF, 0, 0, 0, 1, 4, 3, stream);
      }
      for (int e = 0; e < NEXP; ++e) {
        wconv_t<<<dim3(FF / 32, DM / 32), tb, 0, stream>>>(eg_l + (size_t)e * DM * FF, eguh, egul, DM, FF);
        wconv_t<<<dim3(FF / 32, DM / 32), tb, 0, stream>>>(eu_l + (size_t)e * DM * FF,
                                                           eguh + (size_t)FF * DM,
                                                           egul + (size_t)FF * DM, DM, FF);
        wconv_t<<<dim3(DM / 32, FF / 32), tb, 0, stream>>>(ed_l + (size_t)e * FF * DM, edh, edl, FF, DM);
        for (int c = 0; c < nch; ++c) {
          const u16* xfh = xnh + (size_t)c * mc * DM;
          float* moc = tmp + (size_t)c * mc * DM;
          long nmc = (long)mc * FF;
          int gsz = (int)((nmc + 255) / 256);
          gemm_launch(xfh, eguh, ga16, mc, FF2, DM, DM, DM, 0, 0, 0, 1, 1, 2, stream);
          silu_mul_k<<<gsz, 256, 0, stream>>>(ga16, comb, e, hb16, nmc, c * mc);
          gemm_launch(hb16, edh, moc, mc, DM, FF, FF, FF, 0, 0, 0, 1, 4, 3, stream);
        }
      }
    }
    add_k<<<gND, 256, 0, stream>>>(xc, tmp, ND);
    ln_k<<<NTOK, 256, 0, stream>>>(xc, ln2_g + l * DM, ln2_b + l * DM, xc, nullptr, nullptr);
  }
}

// Round 4
// 3444.118 us; speedup vs baseline: 1.6081x; 1.0375x over previous
//
#include <hip/hip_runtime.h>
#include <stdint.h>

#define S_LEN 2048
#define DM    768
#define NHEAD 8
#define HDIM  96
#define HDP   128
#define FF    3072
#define FF2   6144
#define NEXP  4
#define NTOK  4096
#define NBH   16

typedef unsigned short u16;
typedef short bf16x8 __attribute__((ext_vector_type(8)));
typedef float f32x4 __attribute__((ext_vector_type(4)));
typedef __attribute__((address_space(1))) void* gptr_t;
typedef __attribute__((address_space(3))) void* lptr_t;

__device__ __forceinline__ u16 f2bf(float f) {
  union { float f; uint32_t u; } v; v.f = f;
  uint32_t r = v.u + 0x7FFFu + ((v.u >> 16) & 1u);
  return (u16)(r >> 16);
}
__device__ __forceinline__ float bf2f(u16 h) {
  union { uint32_t u; float f; } v; v.u = ((uint32_t)h) << 16;
  return v.f;
}
__device__ __forceinline__ void split2(float f, u16& hi, u16& lo) {
  u16 h = f2bf(f);
  lo = f2bf(f - bf2f(h));
  hi = h;
}
__device__ __forceinline__ void gload16(const void* g, void* l) {
  __builtin_amdgcn_global_load_lds((gptr_t)(void*)g, (lptr_t)l, 16, 0, 0);
}

// ---------------------------------------------------------------------------
// Plain NT GEMM, 2-phase double-buffered.
// C[M,N] = A[M,K] @ B[N,K]^T. MODE: 0 f32 write, 2 bf16 write, 3 atomic f32.
// ---------------------------------------------------------------------------
template<int MODE>
__global__ __launch_bounds__(256) void gemm_nt(
    const u16* __restrict__ A, const u16* __restrict__ B, void* __restrict__ Cv,
    int M, int N, int K, int lda, int ldb, long sA, long sB, long sC, int kspl)
{
  __shared__ u16 As[2][128 * 32];
  __shared__ u16 Bs[2][128 * 32];
  const int z = blockIdx.z;
  const int bh = z / kspl;
  const int kc = z - bh * kspl;
  const u16* Az = A + (long)bh * sA;
  const u16* Bz = B + (long)bh * sB;
  const int brow = blockIdx.y << 7;
  const int bcol = blockIdx.x << 7;
  const int tid = threadIdx.x;
  const int wid = tid >> 6;
  const int lane = tid & 63;
  const int wr = (wid >> 1) << 6;
  const int wc = (wid & 1) << 6;

  f32x4 acc[4][4] = {};
  const int a0 = (wid << 11) + (lane << 4);

  auto stage = [&](int buf, int k0) {
#pragma unroll
    for (int c = 0; c < 2; ++c) {
      int ab = a0 + (c << 10);
      int row = ab >> 6;
      int kcol = (ab & 63) >> 1;
      int ld = (wid << 11) + (c << 10);
      gload16(Az + (long)(brow + row) * lda + (k0 + kcol), (char*)As[buf] + ld);
      gload16(Bz + (long)(bcol + row) * ldb + (k0 + kcol), (char*)Bs[buf] + ld);
    }
  };

  const int kt = K / kspl;
  const int kbeg = kc * kt;
  const int nt = kt >> 5;
  stage(0, kbeg);
  __syncthreads();
  for (int t = 0; t < nt; ++t) {
    const int cur = t & 1;
    if (t + 1 < nt) stage(cur ^ 1, kbeg + ((t + 1) << 5));
    bf16x8 af[4], bfr[4];
    const int lr = lane & 15;
    const int lk = (lane >> 4) << 4;
#pragma unroll
    for (int m = 0; m < 4; ++m)
      af[m] = *(const bf16x8*)((const char*)As[cur] + (((wr + m * 16 + lr) << 6) + lk));
#pragma unroll
    for (int n = 0; n < 4; ++n)
      bfr[n] = *(const bf16x8*)((const char*)Bs[cur] + (((wc + n * 16 + lr) << 6) + lk));
#pragma unroll
    for (int m = 0; m < 4; ++m)
#pragma unroll
      for (int n = 0; n < 4; ++n)
        acc[m][n] = __builtin_amdgcn_mfma_f32_16x16x32_bf16(af[m], bfr[n], acc[m][n], 0, 0, 0);
    if (t + 1 < nt) __syncthreads();
  }

  const int crow0 = brow + wr + ((lane >> 4) << 2);
  const int ccol0 = bcol + wc + (lane & 15);
  const long cbase = (long)bh * sC;
#pragma unroll
  for (int m = 0; m < 4; ++m)
#pragma unroll
    for (int n = 0; n < 4; ++n)
#pragma unroll
      for (int j = 0; j < 4; ++j) {
        long idx = cbase + (long)(crow0 + m * 16 + j) * N + (ccol0 + n * 16);
        float v = acc[m][n][j];
        if constexpr (MODE == 2) ((u16*)Cv)[idx] = f2bf(v);
        else if constexpr (MODE == 3) unsafeAtomicAdd((float*)Cv + idx, v);
        else ((float*)Cv)[idx] = v;
      }
}

// ---------------------------------------------------------------------------
// Split (bf16x3) NT GEMM, 2-phase double-buffered: C = (Ah+Al)@(Bh+Bl)^T
// minus Al*Bl. fp32-equivalent. MODE: 0 f32 write, 3 atomic f32.
// ---------------------------------------------------------------------------
template<int MODE>
__global__ __launch_bounds__(256) void gemm3_nt(
    const u16* __restrict__ Ah, const u16* __restrict__ Al,
    const u16* __restrict__ Bh, const u16* __restrict__ Bl,
    float* __restrict__ C,
    int M, int N, int K, int lda, int ldb, long sA, long sB, long sC, int kspl)
{
  __shared__ u16 Ash[2][128 * 32], Asl[2][128 * 32];
  __shared__ u16 Bsh[2][128 * 32], Bsl[2][128 * 32];
  const int z = blockIdx.z;
  const int bh = z / kspl;
  const int kc = z - bh * kspl;
  const u16* Azh = Ah + (long)bh * sA;
  const u16* Azl = Al + (long)bh * sA;
  const u16* Bzh = Bh + (long)bh * sB;
  const u16* Bzl = Bl + (long)bh * sB;
  const int brow = blockIdx.y << 7;
  const int bcol = blockIdx.x << 7;
  const int tid = threadIdx.x;
  const int wid = tid >> 6;
  const int lane = tid & 63;
  const int wr = (wid >> 1) << 6;
  const int wc = (wid & 1) << 6;

  f32x4 acc[4][4] = {};
  const int a0 = (wid << 11) + (lane << 4);

  auto stage = [&](int buf, int k0) {
#pragma unroll
    for (int c = 0; c < 2; ++c) {
      int ab = a0 + (c << 10);
      int row = ab >> 6;
      int kcol = (ab & 63) >> 1;
      long ao = (long)(brow + row) * lda + (k0 + kcol);
      long bo = (long)(bcol + row) * ldb + (k0 + kcol);
      int ld = (wid << 11) + (c << 10);
      gload16(Azh + ao, (char*)Ash[buf] + ld);
      gload16(Azl + ao, (char*)Asl[buf] + ld);
      gload16(Bzh + bo, (char*)Bsh[buf] + ld);
      gload16(Bzl + bo, (char*)Bsl[buf] + ld);
    }
  };

  const int kt = K / kspl;
  const int kbeg = kc * kt;
  const int nt = kt >> 5;
  stage(0, kbeg);
  __syncthreads();
  for (int t = 0; t < nt; ++t) {
    const int cur = t & 1;
    if (t + 1 < nt) stage(cur ^ 1, kbeg + ((t + 1) << 5));
    const int lr = lane & 15;
    const int lk = (lane >> 4) << 4;
    bf16x8 ah[4], al[4], bh_[4], bl[4];
#pragma unroll
    for (int m = 0; m < 4; ++m) {
      int off = ((wr + m * 16 + lr) << 6) + lk;
      ah[m] = *(const bf16x8*)((const char*)Ash[cur] + off);
      al[m] = *(const bf16x8*)((const char*)Asl[cur] + off);
    }
#pragma unroll
    for (int n = 0; n < 4; ++n) {
      int off = ((wc + n * 16 + lr) << 6) + lk;
      bh_[n] = *(const bf16x8*)((const char*)Bsh[cur] + off);
      bl[n] = *(const bf16x8*)((const char*)Bsl[cur] + off);
    }
#pragma unroll
    for (int m = 0; m < 4; ++m)
#pragma unroll
      for (int n = 0; n < 4; ++n) {
        acc[m][n] = __builtin_amdgcn_mfma_f32_16x16x32_bf16(al[m], bh_[n], acc[m][n], 0, 0, 0);
        acc[m][n] = __builtin_amdgcn_mfma_f32_16x16x32_bf16(ah[m], bl[n], acc[m][n], 0, 0, 0);
        acc[m][n] = __builtin_amdgcn_mfma_f32_16x16x32_bf16(ah[m], bh_[n], acc[m][n], 0, 0, 0);
      }
    if (t + 1 < nt) __syncthreads();
  }

  const int crow0 = brow + wr + ((lane >> 4) << 2);
  const int ccol0 = bcol + wc + (lane & 15);
  const long cbase = (long)bh * sC;
#pragma unroll
  for (int m = 0; m < 4; ++m)
#pragma unroll
    for (int n = 0; n < 4; ++n)
#pragma unroll
      for (int j = 0; j < 4; ++j) {
        long idx = cbase + (long)(crow0 + m * 16 + j) * N + (ccol0 + n * 16);
        if constexpr (MODE == 3) unsafeAtomicAdd(&C[idx], acc[m][n][j]);
        else C[idx] = acc[m][n][j];
      }
}

// ---------------------------------------------------------------------------
// Fused flash attention, bf16x3 exactness. One block = 128 Q rows of one
// (b,h). Grid (bh=16, qt=16). 4 waves x 32 Q rows. KV tiles of 64.
// K/V staged hi/lo in LDS (XOR-swizzled via pre-swizzled global source);
// P transposed through a per-wave LDS overlay on the K region.
// Writes O (/l, d<96) directly into merged [B,S,768] hi/lo bf16.
// ---------------------------------------------------------------------------
__global__ __launch_bounds__(256, 2) void fattn_k(
    const u16* __restrict__ qh, const u16* __restrict__ ql,
    const u16* __restrict__ kh, const u16* __restrict__ kl,
    const u16* __restrict__ vth, const u16* __restrict__ vtl,
    u16* __restrict__ omh, u16* __restrict__ oml, float scale)
{
  __shared__ u16 Ksh[64 * 128], Ksl[64 * 128];   // [kv][d] 256B rows (P overlay)
  __shared__ u16 Vsh[128 * 64], Vsl[128 * 64];   // [d][kv] 128B rows
  const int bh = blockIdx.x;
  const int qt = blockIdx.y;
  const int tid = threadIdx.x, wid = tid >> 6, lane = tid & 63;
  const int lr = lane & 15, lg = lane >> 4;
  const int q0 = qt * 128 + wid * 32;
  const long bhoff = (long)bh * S_LEN * HDP;
  const u16* Qh = qh + bhoff;  const u16* Ql = ql + bhoff;
  const u16* Kgh = kh + bhoff; const u16* Kgl = kl + bhoff;
  const u16* Vgh = vth + bhoff; const u16* Vgl = vtl + bhoff;   // [d][s]

  bf16x8 qfh[2][4], qfl[2][4];
#pragma unroll
  for (int m = 0; m < 2; ++m)
#pragma unroll
    for (int kk = 0; kk < 4; ++kk) {
      long o = (long)(q0 + m * 16 + lr) * HDP + kk * 32 + lg * 8;
      qfh[m][kk] = *(const bf16x8*)(Qh + o);
      qfl[m][kk] = *(const bf16x8*)(Ql + o);
    }

  f32x4 oacc[2][6] = {};
  float rm[2][4], rl[2][4];
#pragma unroll
  for (int m = 0; m < 2; ++m)
#pragma unroll
    for (int j = 0; j < 4; ++j) { rm[m][j] = -1e30f; rl[m][j] = 0.f; }

  for (int t = 0; t < S_LEN / 64; ++t) {
    __syncthreads();   // prev tile's P/V reads complete before restage
#pragma unroll
    for (int c = 0; c < 4; ++c) {
      int off = (tid + (c << 8)) << 4;          // linear LDS byte
      {
        int lb = off ^ ((((off >> 8) & 7)) << 4);  // K swizzle (256B rows)
        int row = lb >> 8, colh = (lb & 255) >> 1;
        long src = (long)(t * 64 + row) * HDP + colh;
        gload16(Kgh + src, (char*)Ksh + off);
        gload16(Kgl + src, (char*)Ksl + off);
      }
      {
        int lb = off ^ ((((off >> 7) & 7)) << 4);  // V swizzle (128B rows)
        int row = lb >> 7, colh = (lb & 127) >> 1;
        long src = (long)row * S_LEN + t * 64 + colh;
        gload16(Vgh + src, (char*)Vsh + off);
        gload16(Vgl + src, (char*)Vsl + off);
      }
    }
    __syncthreads();

    // --- QK^T (3-way split) ---
    f32x4 sacc[2][4] = {};
#pragma unroll
    for (int kk = 0; kk < 4; ++kk) {
      bf16x8 kbh[4], kbl[4];
#pragma unroll
      for (int n = 0; n < 4; ++n) {
        int byte = ((n * 16 + lr) << 8) + (kk << 6) + (lg << 4);
        byte ^= ((byte >> 8) & 7) << 4;
        kbh[n] = *(const bf16x8*)((const char*)Ksh + byte);
        kbl[n] = *(const bf16x8*)((const char*)Ksl + byte);
      }
#pragma unroll
      for (int m = 0; m < 2; ++m)
#pragma unroll
        for (int n = 0; n < 4; ++n) {
          sacc[m][n] = __builtin_amdgcn_mfma_f32_16x16x32_bf16(qfl[m][kk], kbh[n], sacc[m][n], 0, 0, 0);
          sacc[m][n] = __builtin_amdgcn_mfma_f32_16x16x32_bf16(qfh[m][kk], kbl[n], sacc[m][n], 0, 0, 0);
          sacc[m][n] = __builtin_amdgcn_mfma_f32_16x16x32_bf16(qfh[m][kk], kbh[n], sacc[m][n], 0, 0, 0);
        }
    }
    __syncthreads();   // all waves done reading K before P overlay write

    // --- online softmax (f32, in registers) ---
#pragma unroll
    for (int m = 0; m < 2; ++m)
#pragma unroll
      for (int j = 0; j < 4; ++j) {
        float mx = fmaxf(fmaxf(sacc[m][0][j], sacc[m][1][j]),
                         fmaxf(sacc[m][2][j], sacc[m][3][j])) * scale;
        mx = fmaxf(mx, __shfl_xor(mx, 1));
        mx = fmaxf(mx, __shfl_xor(mx, 2));
        mx = fmaxf(mx, __shfl_xor(mx, 4));
        mx = fmaxf(mx, __shfl_xor(mx, 8));
        float mnew = fmaxf(rm[m][j], mx);
        float corr = __expf(rm[m][j] - mnew);
        rm[m][j] = mnew;
        float ps = 0.f;
#pragma unroll
        for (int n = 0; n < 4; ++n) {
          float p = __expf(sacc[m][n][j] * scale - mnew);
          sacc[m][n][j] = p; ps += p;
        }
        ps += __shfl_xor(ps, 1); ps += __shfl_xor(ps, 2);
        ps += __shfl_xor(ps, 4); ps += __shfl_xor(ps, 8);
        rl[m][j] = rl[m][j] * corr + ps;
#pragma unroll
        for (int n2 = 0; n2 < 6; ++n2) oacc[m][n2][j] *= corr;
      }

    // --- P: C-layout -> A-frag via per-wave LDS overlay (swizzled) ---
    char* Pwh = (char*)Ksh + (wid << 12);
    char* Pwl = (char*)Ksl + (wid << 12);
#pragma unroll
    for (int m = 0; m < 2; ++m)
#pragma unroll
      for (int n = 0; n < 4; ++n)
#pragma unroll
        for (int j = 0; j < 4; ++j) {
          int row = m * 16 + lg * 4 + j;
          int byte = (row << 7) + ((n * 16 + lr) << 1);
          byte ^= ((byte >> 7) & 7) << 4;
          u16 h, l; split2(sacc[m][n][j], h, l);
          *(u16*)(Pwh + byte) = h;
          *(u16*)(Pwl + byte) = l;
        }
    bf16x8 pah[2][2], pal[2][2];
#pragma unroll
    for (int m = 0; m < 2; ++m)
#pragma unroll
      for (int kk = 0; kk < 2; ++kk) {
        int byte = ((m * 16 + lr) << 7) + (kk << 6) + (lg << 4);
        byte ^= ((byte >> 7) & 7) << 4;
        pah[m][kk] = *(const bf16x8*)(Pwh + byte);
        pal[m][kk] = *(const bf16x8*)(Pwl + byte);
      }

    // --- PV (3-way split), d<96 only ---
#pragma unroll
    for (int kk = 0; kk < 2; ++kk) {
      bf16x8 vbh[6], vbl[6];
#pragma unroll
      for (int n2 = 0; n2 < 6; ++n2) {
        int byte = ((n2 * 16 + lr) << 7) + (kk << 6) + (lg << 4);
        byte ^= ((byte >> 7) & 7) << 4;
        vbh[n2] = *(const bf16x8*)((const char*)Vsh + byte);
        vbl[n2] = *(const bf16x8*)((const char*)Vsl + byte);
      }
#pragma unroll
      for (int m = 0; m < 2; ++m)
#pragma unroll
        for (int n2 = 0; n2 < 6; ++n2) {
          oacc[m][n2] = __builtin_amdgcn_mfma_f32_16x16x32_bf16(pal[m][kk], vbh[n2], oacc[m][n2], 0, 0, 0);
          oacc[m][n2] = __builtin_amdgcn_mfma_f32_16x16x32_bf16(pah[m][kk], vbl[n2], oacc[m][n2], 0, 0, 0);
          oacc[m][n2] = __builtin_amdgcn_mfma_f32_16x16x32_bf16(pah[m][kk], vbh[n2], oacc[m][n2], 0, 0, 0);
        }
    }
  }

  // --- epilogue: normalize, write merged hi/lo bf16 [B,S,768] ---
  const int b = bh >> 3, h = bh & 7;
#pragma unroll
  for (int m = 0; m < 2; ++m)
#pragma unroll
    for (int j = 0; j < 4; ++j) {
      float inv = 1.0f / rl[m][j];
      int q = q0 + m * 16 + lg * 4 + j;
      long base = ((long)(b * S_LEN + q)) * DM + h * HDIM;
#pragma unroll
      for (int n2 = 0; n2 < 6; ++n2) {
        int d = n2 * 16 + lr;
        u16 hh, ll; split2(oacc[m][n2][j] * inv, hh, ll);
        omh[base + d] = hh; oml[base + d] = ll;
      }
    }
}

// ---------------------------------------------------------------------------
// fp32 [R][C] -> bf16 hi/lo [C][R]  (weight convert + transpose + split)
// ---------------------------------------------------------------------------
__global__ void wconv_t(const float* __restrict__ in, u16* __restrict__ outh,
                        u16* __restrict__ outl, int R, int C) {
  __shared__ float tile[32][33];
  int c0 = blockIdx.x << 5, r0 = blockIdx.y << 5;
  int tx = threadIdx.x;
  for (int rr = threadIdx.y; rr < 32; rr += 8)
    tile[rr][tx] = in[(long)(r0 + rr) * C + (c0 + tx)];
  __syncthreads();
  for (int rr = threadIdx.y; rr < 32; rr += 8) {
    u16 h, l; split2(tile[tx][rr], h, l);
    long o = (long)(c0 + rr) * R + (r0 + tx);
    outh[o] = h; outl[o] = l;
  }
}

__global__ __launch_bounds__(256) void ln_k(const float* __restrict__ in,
    const float* __restrict__ g, const float* __restrict__ b,
    float* __restrict__ outf, u16* __restrict__ outh, u16* __restrict__ outl) {
  int row = blockIdx.x;
  const float* x = in + (long)row * DM;
  int tid = threadIdx.x;
  float v[3], s = 0.f, ss = 0.f;
#pragma unroll
  for (int i = 0; i < 3; ++i) { v[i] = x[tid + (i << 8)]; s += v[i]; ss += v[i] * v[i]; }
  __shared__ float red[2][4];
  for (int o = 32; o; o >>= 1) { s += __shfl_down(s, o); ss += __shfl_down(ss, o); }
  int wid = tid >> 6, lane = tid & 63;
  if (!lane) { red[0][wid] = s; red[1][wid] = ss; }
  __syncthreads();
  s = red[0][0] + red[0][1] + red[0][2] + red[0][3];
  ss = red[1][0] + red[1][1] + red[1][2] + red[1][3];
  float mean = s * (1.f / DM);
  float var = ss * (1.f / DM) - mean * mean;
  float rs = rsqrtf(var + 1e-5f);
#pragma unroll
  for (int i = 0; i < 3; ++i) {
    int c = tid + (i << 8);
    float y = (v[i] - mean) * rs * g[c] + b[c];
    if (outf) outf[(long)row * DM + c] = y;
    if (outh) { u16 h, l; split2(y, h, l); outh[(long)row * DM + c] = h; outl[(long)row * DM + c] = l; }
  }
}

__global__ void rope_tables_k(float* __restrict__ cosT, float* __restrict__ sinT) {
  int s = blockIdx.x, d = threadIdx.x;
  int xc = s & 15, y = (s >> 4) & 15, t = s >> 8;
  int axis = d / 32, fi = d & 15;
  int coord = axis == 0 ? xc : (axis == 1 ? y : t);
  float inv = powf(10000.0f, -(float)fi / 16.0f);
  float ang = (float)coord * inv;
  cosT[s * HDIM + d] = cosf(ang);
  sinT[s * HDIM + d] = sinf(ang);
}

__global__ __launch_bounds__(256) void rope_apply_k(const float* __restrict__ qkv,
    const float* __restrict__ cosT, const float* __restrict__ sinT,
    u16* __restrict__ qh, u16* __restrict__ ql,
    u16* __restrict__ kh, u16* __restrict__ kl) {
  int bs = blockIdx.x;
  int b = bs >> 11, s = bs & 2047;
  const float* base = qkv + ((long)(b * S_LEN + s) * 3) * DM;
  for (int idx = threadIdx.x; idx < DM; idx += 256) {
    int h = idx / HDIM, d = idx - h * HDIM;
    float c = cosT[s * HDIM + d], sn = sinT[s * HDIM + d];
    int pair = (d < 48) ? idx + 48 : idx - 48;
    float qv = base[idx], kv = base[DM + idx];
    float qr = (d < 48) ? -base[pair] : base[pair];
    float kr = (d < 48) ? -base[DM + pair] : base[DM + pair];
    long o = ((long)(b * NHEAD + h) * S_LEN + s) * HDP + d;
    u16 hh, ll;
    split2(qv * c + qr * sn, hh, ll); qh[o] = hh; ql[o] = ll;
    split2(kv * c + kr * sn, hh, ll); kh[o] = hh; kl[o] = ll;
  }
  int t = threadIdx.x;
  int h = t >> 5, d = HDIM + (t & 31);
  long o = ((long)(b * NHEAD + h) * S_LEN + s) * HDP + d;
  qh[o] = 0; ql[o] = 0; kh[o] = 0; kl[o] = 0;
}

__global__ void v_transpose_k(const float* __restrict__ qkv,
                              u16* __restrict__ vh, u16* __restrict__ vl) {
  __shared__ float tile[32][33];
  int bh = blockIdx.z, b = bh >> 3, h = bh & 7;
  int s0 = blockIdx.x << 5, d0 = blockIdx.y << 5;
  int tx = threadIdx.x;
  for (int r = threadIdx.y; r < 32; r += 8) {
    int s = s0 + r, d = d0 + tx;
    float v = 0.f;
    if (d < HDIM) v = qkv[((long)(b * S_LEN + s) * 3 + 2) * DM + h * HDIM + d];
    tile[r][tx] = v;
  }
  __syncthreads();
  for (int r = threadIdx.y; r < 32; r += 8) {
    int d = d0 + r;
    u16 hh, ll; split2(tile[tx][r], hh, ll);
    long o = ((long)bh * HDP + d) * S_LEN + (s0 + tx);
    vh[o] = hh; vl[o] = ll;
  }
}

__global__ __launch_bounds__(256) void router_k(const float* __restrict__ x,
    const float* __restrict__ gw, float* __restrict__ comb) {
  int tok = blockIdx.x * 4 + (threadIdx.x >> 6);
  int lane = threadIdx.x & 63;
  const float* xr = x + (long)tok * DM;
  float a0 = 0, a1 = 0, a2 = 0, a3 = 0;
  for (int i = lane; i < DM; i += 64) {
    float xv = xr[i];
    const float* g = gw + i * 4;
    a0 += xv * g[0]; a1 += xv * g[1]; a2 += xv * g[2]; a3 += xv * g[3];
  }
  for (int o = 32; o; o >>= 1) {
    a0 += __shfl_down(a0, o); a1 += __shfl_down(a1, o);
    a2 += __shfl_down(a2, o); a3 += __shfl_down(a3, o);
  }
  if (lane == 0) {
    float p[4] = {a0, a1, a2, a3};
    float mx = fmaxf(fmaxf(p[0], p[1]), fmaxf(p[2], p[3]));
    float s = 0.f;
    for (int e = 0; e < 4; ++e) { p[e] = expf(p[e] - mx); s += p[e]; }
    for (int e = 0; e < 4; ++e) p[e] /= s;
    int i1 = 0;
    for (int e = 1; e < 4; ++e) if (p[e] > p[i1]) i1 = e;
    int i2 = -1;
    for (int e = 0; e < 4; ++e) if (e != i1 && (i2 < 0 || p[e] > p[i2])) i2 = e;
    float ssum = p[i1] + p[i2] + 1e-5f;
    float out[4] = {0, 0, 0, 0};
    out[i1] = p[i1] / ssum; out[i2] = p[i2] / ssum;
    for (int e = 0; e < 4; ++e) comb[tok * 4 + e] = out[e];
  }
}

// fused-gu f32 [tok][2FF]: hb = split(silu(g)*u*w)
__global__ void silu3_k(const float* __restrict__ gu, const float* __restrict__ comb,
                        int e, u16* __restrict__ hbh, u16* __restrict__ hbl,
                        long n, int tok0) {
  long i = (long)blockIdx.x * 256 + threadIdx.x;
  if (i >= n) return;
  int tl = (int)(i / FF), j = (int)(i - (long)tl * FF);
  float gv = gu[(long)tl * FF2 + j];
  float uv = gu[(long)tl * FF2 + FF + j];
  float w = comb ? comb[(tok0 + tl) * 4 + e] : 1.0f;
  float h = gv / (1.0f + expf(-gv)) * uv * w;
  u16 hh, ll; split2(h, hh, ll);
  hbh[i] = hh; hbl[i] = ll;
}

// fused-gu bf16 [tok][2FF]: hb = bf16(silu(g)*u*w)
__global__ void silu_mul_k(const u16* __restrict__ gu, const float* __restrict__ comb,
                           int e, u16* __restrict__ hb, long n, int tok0) {
  long i = (long)blockIdx.x * 256 + threadIdx.x;
  if (i >= n) return;
  int tl = (int)(i / FF), j = (int)(i - (long)tl * FF);
  float gv = bf2f(gu[(long)tl * FF2 + j]);
  float uv = bf2f(gu[(long)tl * FF2 + FF + j]);
  float w = comb ? comb[(tok0 + tl) * 4 + e] : 1.0f;
  hb[i] = f2bf(gv / (1.0f + expf(-gv)) * uv * w);
}

__global__ void add_k(float* __restrict__ dst, const float* __restrict__ src, long n) {
  long i = (long)blockIdx.x * 256 + threadIdx.x;
  if (i < n) dst[i] += src[i];
}

__global__ void zero_k(float* __restrict__ dst, long n) {
  long i = (long)blockIdx.x * 256 + threadIdx.x;
  if (i < n) dst[i] = 0.f;
}

__global__ void f2b_k(const float* __restrict__ src, u16* __restrict__ dst, long n) {
  long i = (long)blockIdx.x * 256 + threadIdx.x;
  if (i < n) dst[i] = f2bf(src[i]);
}

__global__ void f2bsplit_k(const float* __restrict__ src, u16* __restrict__ dh,
                           u16* __restrict__ dl, long n) {
  long i = (long)blockIdx.x * 256 + threadIdx.x;
  if (i < n) { u16 h, l; split2(src[i], h, l); dh[i] = h; dl[i] = l; }
}

// ---------------------------------------------------------------------------
static void gemm_launch(const void* A, const void* B, void* C, int M, int N, int K,
                        int lda, int ldb, long sA, long sB, long sC, int nb,
                        int kspl, int mode, hipStream_t st) {
  dim3 g(N >> 7, M >> 7, nb * kspl), blk(256, 1, 1);
  if (mode == 0)
    gemm_nt<0><<<g, blk, 0, st>>>((const u16*)A, (const u16*)B, C, M, N, K, lda, ldb, sA, sB, sC, kspl);
  else if (mode == 2)
    gemm_nt<2><<<g, blk, 0, st>>>((const u16*)A, (const u16*)B, C, M, N, K, lda, ldb, sA, sB, sC, kspl);
  else
    gemm_nt<3><<<g, blk, 0, st>>>((const u16*)A, (const u16*)B, C, M, N, K, lda, ldb, sA, sB, sC, kspl);
}

static void gemm3_launch(const void* Ah, const void* Al, const void* Bh, const void* Bl,
                         float* C, int M, int N, int K, int lda, int ldb,
                         long sA, long sB, long sC, int nb, int kspl, int mode,
                         hipStream_t st) {
  dim3 g(N >> 7, M >> 7, nb * kspl), blk(256, 1, 1);
  if (mode == 0)
    gemm3_nt<0><<<g, blk, 0, st>>>((const u16*)Ah, (const u16*)Al, (const u16*)Bh,
                                   (const u16*)Bl, C, M, N, K, lda, ldb, sA, sB, sC, kspl);
  else
    gemm3_nt<3><<<g, blk, 0, st>>>((const u16*)Ah, (const u16*)Al, (const u16*)Bh,
                                   (const u16*)Bl, C, M, N, K, lda, ldb, sA, sB, sC, kspl);
}

extern "C" void kernel_launch(void* const* d_in, const int* in_sizes, int n_in,
                              void* d_out, int out_size, void* d_ws, size_t ws_size,
                              hipStream_t stream) {
  (void)in_sizes; (void)n_in; (void)out_size;
  const float* x_in  = (const float*)d_in[0];
  const float* ln1_g = (const float*)d_in[4];
  const float* ln1_b = (const float*)d_in[5];
  const float* w_qkv = (const float*)d_in[6];
  const float* w_out = (const float*)d_in[7];
  const float* gatew = (const float*)d_in[8];
  const float* eg    = (const float*)d_in[9];
  const float* eu    = (const float*)d_in[10];
  const float* ed    = (const float*)d_in[11];
  const float* sg    = (const float*)d_in[12];
  const float* su    = (const float*)d_in[13];
  const float* sd    = (const float*)d_in[14];
  const float* ln2_g = (const float*)d_in[15];
  const float* ln2_b = (const float*)d_in[16];

  float* xc = (float*)d_out;
  char* W = (char*)d_ws;
  size_t off = 0;
  auto alloc = [&](size_t bytes) {
    size_t o = off; off = (off + bytes + 255) & ~(size_t)255; return o;
  };
  size_t o_cos  = alloc((size_t)S_LEN * HDIM * 4);
  size_t o_sin  = alloc((size_t)S_LEN * HDIM * 4);
  size_t o_xnh  = alloc((size_t)NTOK * DM * 2);
  size_t o_xnl  = alloc((size_t)NTOK * DM * 2);
  size_t o_qkv  = alloc((size_t)NTOK * 3 * DM * 4);
  size_t o_qph  = alloc((size_t)NBH * S_LEN * HDP * 2);
  size_t o_qpl  = alloc((size_t)NBH * S_LEN * HDP * 2);
  size_t o_kph  = alloc((size_t)NBH * S_LEN * HDP * 2);
  size_t o_kpl  = alloc((size_t)NBH * S_LEN * HDP * 2);
  size_t o_vth  = alloc((size_t)NBH * HDP * S_LEN * 2);
  size_t o_vtl  = alloc((size_t)NBH * HDP * S_LEN * 2);
  size_t o_omh  = alloc((size_t)NTOK * DM * 2);
  size_t o_oml  = alloc((size_t)NTOK * DM * 2);
  size_t o_tmp  = alloc((size_t)NTOK * DM * 4);
  size_t o_comb = alloc((size_t)NTOK * 4 * 4);
  size_t o_wqh  = alloc((size_t)3 * DM * DM * 2);
  size_t o_wql  = alloc((size_t)3 * DM * DM * 2);
  size_t o_woh  = alloc((size_t)DM * DM * 2);
  size_t o_wol  = alloc((size_t)DM * DM * 2);
  size_t o_sguh = alloc((size_t)FF2 * DM * 2);
  size_t o_sgul = alloc((size_t)FF2 * DM * 2);
  size_t o_sdh  = alloc((size_t)DM * FF * 2);
  size_t o_sdl  = alloc((size_t)DM * FF * 2);
  size_t o_eguh = alloc((size_t)FF2 * DM * 2);
  size_t o_egul = alloc((size_t)FF2 * DM * 2);
  size_t o_edh  = alloc((size_t)DM * FF * 2);
  size_t o_edl  = alloc((size_t)DM * FF * 2);
  size_t fixed_end = off;

  size_t avail = ws_size > fixed_end ? ws_size - fixed_end : 0;
  int mc = 1024;
  { const int c[3] = {4096, 2048, 1024};
    for (int i = 0; i < 3; ++i) if ((size_t)c[i] * FF * 12 <= avail) { mc = c[i]; break; } }

  size_t o_ga   = fixed_end;                        // mc*2FF f32 (fused gate|up)
  size_t o_hbh  = o_ga + (size_t)mc * FF2 * 4;
  size_t o_hbl  = o_hbh + (size_t)mc * FF * 2;
  size_t o_ga16 = fixed_end;                        // mc*2FF bf16 (layer-1)
  size_t o_hb16 = o_ga16 + (size_t)mc * FF2 * 2;

  float* cosT = (float*)(W + o_cos);
  float* sinT = (float*)(W + o_sin);
  u16*   xnh  = (u16*)(W + o_xnh);
  u16*   xnl  = (u16*)(W + o_xnl);
  float* qkv  = (float*)(W + o_qkv);
  u16 *qph = (u16*)(W + o_qph), *qpl = (u16*)(W + o_qpl);
  u16 *kph = (u16*)(W + o_kph), *kpl = (u16*)(W + o_kpl);
  u16 *vth = (u16*)(W + o_vth), *vtl = (u16*)(W + o_vtl);
  u16 *omh = (u16*)(W + o_omh), *oml = (u16*)(W + o_oml);
  float* tmp  = (float*)(W + o_tmp);
  float* comb = (float*)(W + o_comb);
  u16 *wqh = (u16*)(W + o_wqh), *wql = (u16*)(W + o_wql);
  u16 *woh = (u16*)(W + o_woh), *wol = (u16*)(W + o_wol);
  u16 *sguh = (u16*)(W + o_sguh), *sgul = (u16*)(W + o_sgul);
  u16 *sdh = (u16*)(W + o_sdh), *sdl = (u16*)(W + o_sdl);
  u16 *eguh = (u16*)(W + o_eguh), *egul = (u16*)(W + o_egul);
  u16 *edh = (u16*)(W + o_edh), *edl = (u16*)(W + o_edl);
  float* gaF = (float*)(W + o_ga);
  u16 *hbh = (u16*)(W + o_hbh), *hbl = (u16*)(W + o_hbl);
  u16 *ga16 = (u16*)(W + o_ga16), *hb16 = (u16*)(W + o_hb16);

  const long ND = (long)NTOK * DM;
  const int gND = (int)((ND + 255) / 256);

  hipMemcpyAsync(xc, x_in, (size_t)ND * 4, hipMemcpyDeviceToDevice, stream);
  rope_tables_k<<<S_LEN, HDIM, 0, stream>>>(cosT, sinT);

  dim3 tb(32, 8, 1);
  for (int l = 0; l < 2; ++l) {
    const float* wqkv_l = w_qkv + (size_t)l * DM * 3 * DM;
    const float* wout_l = w_out + (size_t)l * DM * DM;
    const float* gw_l   = gatew + (size_t)l * DM * 4;
    const float* eg_l = eg + (size_t)l * NEXP * DM * FF;
    const float* eu_l = eu + (size_t)l * NEXP * DM * FF;
    const float* ed_l = ed + (size_t)l * NEXP * FF * DM;
    const float* sg_l = sg + (size_t)l * DM * FF;
    const float* su_l = su + (size_t)l * DM * FF;
    const float* sd_l = sd + (size_t)l * FF * DM;

    wconv_t<<<dim3(3 * DM / 32, DM / 32), tb, 0, stream>>>(wqkv_l, wqh, wql, DM, 3 * DM);
    wconv_t<<<dim3(DM / 32, DM / 32), tb, 0, stream>>>(wout_l, woh, wol, DM, DM);
    wconv_t<<<dim3(FF / 32, DM / 32), tb, 0, stream>>>(sg_l, sguh, sgul, DM, FF);
    wconv_t<<<dim3(FF / 32, DM / 32), tb, 0, stream>>>(su_l, sguh + (size_t)FF * DM,
                                                       sgul + (size_t)FF * DM, DM, FF);
    wconv_t<<<dim3(DM / 32, FF / 32), tb, 0, stream>>>(sd_l, sdh, sdl, FF, DM);

    // --- attention (fp32-equivalent via bf16x3 + flash) ---
    ln_k<<<NTOK, 256, 0, stream>>>(xc, ln1_g + l * DM, ln1_b + l * DM, nullptr, xnh, xnl);
    gemm3_launch(xnh, xnl, wqh, wql, qkv, NTOK, 3 * DM, DM, DM, DM, 0, 0, 0, 1, 1, 0, stream);
    rope_apply_k<<<NTOK, 256, 0, stream>>>(qkv, cosT, sinT, qph, qpl, kph, kpl);
    v_transpose_k<<<dim3(S_LEN / 32, HDP / 32, NBH), tb, 0, stream>>>(qkv, vth, vtl);
    fattn_k<<<dim3(NBH, S_LEN / 128), dim3(256), 0, stream>>>(
        qph, qpl, kph, kpl, vth, vtl, omh, oml, 0.10206207261596575f);
    zero_k<<<gND, 256, 0, stream>>>(tmp, ND);
    gemm3_launch(omh, oml, woh, wol, tmp, NTOK, DM, DM, DM, DM, 0, 0, 0, 1, 2, 3, stream);
    add_k<<<gND, 256, 0, stream>>>(xc, tmp, ND);

    // --- router on fp32 x ---
    router_k<<<NTOK / 4, 256, 0, stream>>>(xc, gw_l, comb);

    int nch = NTOK / mc;
    zero_k<<<gND, 256, 0, stream>>>(tmp, ND);
    if (l == 0) {
      f2bsplit_k<<<gND, 256, 0, stream>>>(xc, xnh, xnl, ND);
      for (int c = 0; c < nch; ++c) {
        const u16 *xfh = xnh + (size_t)c * mc * DM, *xfl = xnl + (size_t)c * mc * DM;
        float* moc = tmp + (size_t)c * mc * DM;
        long nmc = (long)mc * FF;
        int gsz = (int)((nmc + 255) / 256);
        gemm3_launch(xfh, xfl, sguh, sgul, gaF, mc, FF2, DM, DM, DM, 0, 0, 0, 1, 1, 0, stream);
        silu3_k<<<gsz, 256, 0, stream>>>(gaF, nullptr, 0, hbh, hbl, nmc, c * mc);
        gemm3_launch(hbh, hbl, sdh, sdl, moc, mc, DM, FF, FF, FF, 0, 0, 0, 1, 4, 3, stream);
      }
      for (int e = 0; e < NEXP; ++e) {
        wconv_t<<<dim3(FF / 32, DM / 32), tb, 0, stream>>>(eg_l + (size_t)e * DM * FF, eguh, egul, DM, FF);
        wconv_t<<<dim3(FF / 32, DM / 32), tb, 0, stream>>>(eu_l + (size_t)e * DM * FF,
                                                           eguh + (size_t)FF * DM,
                                                           egul + (size_t)FF * DM, DM, FF);
        wconv_t<<<dim3(DM / 32, FF / 32), tb, 0, stream>>>(ed_l + (size_t)e * FF * DM, edh, edl, FF, DM);
        for (int c = 0; c < nch; ++c) {
          const u16 *xfh = xnh + (size_t)c * mc * DM, *xfl = xnl + (size_t)c * mc * DM;
          float* moc = tmp + (size_t)c * mc * DM;
          long nmc = (long)mc * FF;
          int gsz = (int)((nmc + 255) / 256);
          gemm3_launch(xfh, xfl, eguh, egul, gaF, mc, FF2, DM, DM, DM, 0, 0, 0, 1, 1, 0, stream);
          silu3_k<<<gsz, 256, 0, stream>>>(gaF, comb, e, hbh, hbl, nmc, c * mc);
          gemm3_launch(hbh, hbl, edh, edl, moc, mc, DM, FF, FF, FF, 0, 0, 0, 1, 4, 3, stream);
        }
      }
    } else {
      f2b_k<<<gND, 256, 0, stream>>>(xc, xnh, ND);
      for (int c = 0; c < nch; ++c) {
        const u16* xfh = xnh + (size_t)c * mc * DM;
        float* moc = tmp + (size_t)c * mc * DM;
        long nmc = (long)mc * FF;
        int gsz = (int)((nmc + 255) / 256);
        gemm_launch(xfh, sguh, ga16, mc, FF2, DM, DM, DM, 0, 0, 0, 1, 1, 2, stream);
        silu_mul_k<<<gsz, 256, 0, stream>>>(ga16, nullptr, 0, hb16, nmc, c * mc);
        gemm_launch(hb16, sdh, moc, mc, DM, FF, FF, FF, 0, 0, 0, 1, 4, 3, stream);
      }
      for (int e = 0; e < NEXP; ++e) {
        wconv_t<<<dim3(FF / 32, DM / 32), tb, 0, stream>>>(eg_l + (size_t)e * DM * FF, eguh, egul, DM, FF);
        wconv_t<<<dim3(FF / 32, DM / 32), tb, 0, stream>>>(eu_l + (size_t)e * DM * FF,
                                                           eguh + (size_t)FF * DM,
                                                           egul + (size_t)FF * DM, DM, FF);
        wconv_t<<<dim3(DM / 32, FF / 32), tb, 0, stream>>>(ed_l + (size_t)e * FF * DM, edh, edl, FF, DM);
        for (int c = 0; c < nch; ++c) {
          const u16* xfh = xnh + (size_t)c * mc * DM;
          float* moc = tmp + (size_t)c * mc * DM;
          long nmc = (long)mc * FF;
          int gsz = (int)((nmc + 255) / 256);
          gemm_launch(xfh, eguh, ga16, mc, FF2, DM, DM, DM, 0, 0, 0, 1, 1, 2, stream);
          silu_mul_k<<<gsz, 256, 0, stream>>>(ga16, comb, e, hb16, nmc, c * mc);
          gemm_launch(hb16, edh, moc, mc, DM, FF, FF, FF, 0, 0, 0, 1, 4, 3, stream);
        }
      }
    }
    add_k<<<gND, 256, 0, stream>>>(xc, tmp, ND);
    ln_k<<<NTOK, 256, 0, stream>>>(xc, ln2_g + l * DM, ln2_b + l * DM, xc, nullptr, nullptr);
  }
}

// Round 5
// 3034.839 us; speedup vs baseline: 1.8250x; 1.1349x over previous
//
#include <hip/hip_runtime.h>
#include <stdint.h>

#define S_LEN 2048
#define DM    768
#define NHEAD 8
#define HDIM  96
#define HDP   128
#define FF    3072
#define FF2   6144
#define NEXP  4
#define NTOK  4096
#define NBH   16

typedef unsigned short u16;
typedef short bf16x8 __attribute__((ext_vector_type(8)));
typedef float f32x4 __attribute__((ext_vector_type(4)));
typedef __attribute__((address_space(1))) void* gptr_t;
typedef __attribute__((address_space(3))) void* lptr_t;

__device__ __forceinline__ u16 f2bf(float f) {
  union { float f; uint32_t u; } v; v.f = f;
  uint32_t r = v.u + 0x7FFFu + ((v.u >> 16) & 1u);
  return (u16)(r >> 16);
}
__device__ __forceinline__ float bf2f(u16 h) {
  union { uint32_t u; float f; } v; v.u = ((uint32_t)h) << 16;
  return v.f;
}
__device__ __forceinline__ void split2(float f, u16& hi, u16& lo) {
  u16 h = f2bf(f);
  lo = f2bf(f - bf2f(h));
  hi = h;
}
__device__ __forceinline__ void gload16(const void* g, void* l) {
  __builtin_amdgcn_global_load_lds((gptr_t)(void*)g, (lptr_t)l, 16, 0, 0);
}

// ---------------------------------------------------------------------------
// Plain NT GEMM, 2-phase double-buffered.
// C[M,N] = A[M,K] @ B[N,K]^T. MODE: 0 f32 write, 2 bf16 write, 3 atomic f32.
// ---------------------------------------------------------------------------
template<int MODE>
__global__ __launch_bounds__(256) void gemm_nt(
    const u16* __restrict__ A, const u16* __restrict__ B, void* __restrict__ Cv,
    int M, int N, int K, int lda, int ldb, long sA, long sB, long sC, int kspl)
{
  __shared__ u16 As[2][128 * 32];
  __shared__ u16 Bs[2][128 * 32];
  const int z = blockIdx.z;
  const int bh = z / kspl;
  const int kc = z - bh * kspl;
  const u16* Az = A + (long)bh * sA;
  const u16* Bz = B + (long)bh * sB;
  const int brow = blockIdx.y << 7;
  const int bcol = blockIdx.x << 7;
  const int tid = threadIdx.x;
  const int wid = tid >> 6;
  const int lane = tid & 63;
  const int wr = (wid >> 1) << 6;
  const int wc = (wid & 1) << 6;

  f32x4 acc[4][4] = {};
  const int a0 = (wid << 11) + (lane << 4);

  auto stage = [&](int buf, int k0) {
#pragma unroll
    for (int c = 0; c < 2; ++c) {
      int ab = a0 + (c << 10);
      int row = ab >> 6;
      int kcol = (ab & 63) >> 1;
      int ld = (wid << 11) + (c << 10);
      gload16(Az + (long)(brow + row) * lda + (k0 + kcol), (char*)As[buf] + ld);
      gload16(Bz + (long)(bcol + row) * ldb + (k0 + kcol), (char*)Bs[buf] + ld);
    }
  };

  const int kt = K / kspl;
  const int kbeg = kc * kt;
  const int nt = kt >> 5;
  stage(0, kbeg);
  __syncthreads();
  for (int t = 0; t < nt; ++t) {
    const int cur = t & 1;
    if (t + 1 < nt) stage(cur ^ 1, kbeg + ((t + 1) << 5));
    bf16x8 af[4], bfr[4];
    const int lr = lane & 15;
    const int lk = (lane >> 4) << 4;
#pragma unroll
    for (int m = 0; m < 4; ++m)
      af[m] = *(const bf16x8*)((const char*)As[cur] + (((wr + m * 16 + lr) << 6) + lk));
#pragma unroll
    for (int n = 0; n < 4; ++n)
      bfr[n] = *(const bf16x8*)((const char*)Bs[cur] + (((wc + n * 16 + lr) << 6) + lk));
#pragma unroll
    for (int m = 0; m < 4; ++m)
#pragma unroll
      for (int n = 0; n < 4; ++n)
        acc[m][n] = __builtin_amdgcn_mfma_f32_16x16x32_bf16(af[m], bfr[n], acc[m][n], 0, 0, 0);
    if (t + 1 < nt) __syncthreads();
  }

  const int crow0 = brow + wr + ((lane >> 4) << 2);
  const int ccol0 = bcol + wc + (lane & 15);
  const long cbase = (long)bh * sC;
#pragma unroll
  for (int m = 0; m < 4; ++m)
#pragma unroll
    for (int n = 0; n < 4; ++n)
#pragma unroll
      for (int j = 0; j < 4; ++j) {
        long idx = cbase + (long)(crow0 + m * 16 + j) * N + (ccol0 + n * 16);
        float v = acc[m][n][j];
        if constexpr (MODE == 2) ((u16*)Cv)[idx] = f2bf(v);
        else if constexpr (MODE == 3) unsafeAtomicAdd((float*)Cv + idx, v);
        else ((float*)Cv)[idx] = v;
      }
}

// ---------------------------------------------------------------------------
// Split (bf16x3) NT GEMM, 2-phase double-buffered: C = (Ah+Al)@(Bh+Bl)^T
// minus Al*Bl. fp32-equivalent. MODE: 0 f32 write, 3 atomic f32.
// ---------------------------------------------------------------------------
template<int MODE>
__global__ __launch_bounds__(256) void gemm3_nt(
    const u16* __restrict__ Ah, const u16* __restrict__ Al,
    const u16* __restrict__ Bh, const u16* __restrict__ Bl,
    float* __restrict__ C,
    int M, int N, int K, int lda, int ldb, long sA, long sB, long sC, int kspl)
{
  __shared__ u16 Ash[2][128 * 32], Asl[2][128 * 32];
  __shared__ u16 Bsh[2][128 * 32], Bsl[2][128 * 32];
  const int z = blockIdx.z;
  const int bh = z / kspl;
  const int kc = z - bh * kspl;
  const u16* Azh = Ah + (long)bh * sA;
  const u16* Azl = Al + (long)bh * sA;
  const u16* Bzh = Bh + (long)bh * sB;
  const u16* Bzl = Bl + (long)bh * sB;
  const int brow = blockIdx.y << 7;
  const int bcol = blockIdx.x << 7;
  const int tid = threadIdx.x;
  const int wid = tid >> 6;
  const int lane = tid & 63;
  const int wr = (wid >> 1) << 6;
  const int wc = (wid & 1) << 6;

  f32x4 acc[4][4] = {};
  const int a0 = (wid << 11) + (lane << 4);

  auto stage = [&](int buf, int k0) {
#pragma unroll
    for (int c = 0; c < 2; ++c) {
      int ab = a0 + (c << 10);
      int row = ab >> 6;
      int kcol = (ab & 63) >> 1;
      long ao = (long)(brow + row) * lda + (k0 + kcol);
      long bo = (long)(bcol + row) * ldb + (k0 + kcol);
      int ld = (wid << 11) + (c << 10);
      gload16(Azh + ao, (char*)Ash[buf] + ld);
      gload16(Azl + ao, (char*)Asl[buf] + ld);
      gload16(Bzh + bo, (char*)Bsh[buf] + ld);
      gload16(Bzl + bo, (char*)Bsl[buf] + ld);
    }
  };

  const int kt = K / kspl;
  const int kbeg = kc * kt;
  const int nt = kt >> 5;
  stage(0, kbeg);
  __syncthreads();
  for (int t = 0; t < nt; ++t) {
    const int cur = t & 1;
    if (t + 1 < nt) stage(cur ^ 1, kbeg + ((t + 1) << 5));
    const int lr = lane & 15;
    const int lk = (lane >> 4) << 4;
    bf16x8 ah[4], al[4], bh_[4], bl[4];
#pragma unroll
    for (int m = 0; m < 4; ++m) {
      int off = ((wr + m * 16 + lr) << 6) + lk;
      ah[m] = *(const bf16x8*)((const char*)Ash[cur] + off);
      al[m] = *(const bf16x8*)((const char*)Asl[cur] + off);
    }
#pragma unroll
    for (int n = 0; n < 4; ++n) {
      int off = ((wc + n * 16 + lr) << 6) + lk;
      bh_[n] = *(const bf16x8*)((const char*)Bsh[cur] + off);
      bl[n] = *(const bf16x8*)((const char*)Bsl[cur] + off);
    }
#pragma unroll
    for (int m = 0; m < 4; ++m)
#pragma unroll
      for (int n = 0; n < 4; ++n) {
        acc[m][n] = __builtin_amdgcn_mfma_f32_16x16x32_bf16(al[m], bh_[n], acc[m][n], 0, 0, 0);
        acc[m][n] = __builtin_amdgcn_mfma_f32_16x16x32_bf16(ah[m], bl[n], acc[m][n], 0, 0, 0);
        acc[m][n] = __builtin_amdgcn_mfma_f32_16x16x32_bf16(ah[m], bh_[n], acc[m][n], 0, 0, 0);
      }
    if (t + 1 < nt) __syncthreads();
  }

  const int crow0 = brow + wr + ((lane >> 4) << 2);
  const int ccol0 = bcol + wc + (lane & 15);
  const long cbase = (long)bh * sC;
#pragma unroll
  for (int m = 0; m < 4; ++m)
#pragma unroll
    for (int n = 0; n < 4; ++n)
#pragma unroll
      for (int j = 0; j < 4; ++j) {
        long idx = cbase + (long)(crow0 + m * 16 + j) * N + (ccol0 + n * 16);
        if constexpr (MODE == 3) unsafeAtomicAdd(&C[idx], acc[m][n][j]);
        else C[idx] = acc[m][n][j];
      }
}

// ---------------------------------------------------------------------------
// Fused flash attention, bf16x3 exactness. One block = 64 Q rows of one
// (b,h). Grid (bh=16, qt=32) = 512 blocks -> 2 blocks/CU (64 KB LDS each).
// 4 waves x 16 Q rows. KV tiles of 64. K/V staged hi/lo in LDS (XOR-swizzled
// via pre-swizzled global source); P transposed through a per-wave LDS
// overlay on the K region. Writes O (/l, d<96) into merged [B,S,768] hi/lo.
// ---------------------------------------------------------------------------
__global__ __launch_bounds__(256, 2) void fattn_k(
    const u16* __restrict__ qh, const u16* __restrict__ ql,
    const u16* __restrict__ kh, const u16* __restrict__ kl,
    const u16* __restrict__ vth, const u16* __restrict__ vtl,
    u16* __restrict__ omh, u16* __restrict__ oml, float scale)
{
  __shared__ u16 Ksh[64 * 128], Ksl[64 * 128];   // [kv][d] 256B rows (P overlay)
  __shared__ u16 Vsh[128 * 64], Vsl[128 * 64];   // [d][kv] 128B rows
  const int bh = blockIdx.x;
  const int qt = blockIdx.y;
  const int tid = threadIdx.x, wid = tid >> 6, lane = tid & 63;
  const int lr = lane & 15, lg = lane >> 4;
  const int q0 = qt * 64 + wid * 16;
  const long bhoff = (long)bh * S_LEN * HDP;
  const u16* Qh = qh + bhoff;  const u16* Ql = ql + bhoff;
  const u16* Kgh = kh + bhoff; const u16* Kgl = kl + bhoff;
  const u16* Vgh = vth + bhoff; const u16* Vgl = vtl + bhoff;   // [d][s]

  bf16x8 qfh[4], qfl[4];
#pragma unroll
  for (int kk = 0; kk < 4; ++kk) {
    long o = (long)(q0 + lr) * HDP + kk * 32 + lg * 8;
    qfh[kk] = *(const bf16x8*)(Qh + o);
    qfl[kk] = *(const bf16x8*)(Ql + o);
  }

  f32x4 oacc[6] = {};
  float rm[4], rls[4];
#pragma unroll
  for (int j = 0; j < 4; ++j) { rm[j] = -1e30f; rls[j] = 0.f; }

  for (int t = 0; t < S_LEN / 64; ++t) {
    __syncthreads();   // prev tile's P/V reads complete before restage
#pragma unroll
    for (int c = 0; c < 4; ++c) {
      int off = (tid + (c << 8)) << 4;          // linear LDS byte
      {
        int lb = off ^ ((((off >> 8) & 7)) << 4);  // K swizzle (256B rows)
        int row = lb >> 8, colh = (lb & 255) >> 1;
        long src = (long)(t * 64 + row) * HDP + colh;
        gload16(Kgh + src, (char*)Ksh + off);
        gload16(Kgl + src, (char*)Ksl + off);
      }
      {
        int lb = off ^ ((((off >> 7) & 7)) << 4);  // V swizzle (128B rows)
        int row = lb >> 7, colh = (lb & 127) >> 1;
        long src = (long)row * S_LEN + t * 64 + colh;
        gload16(Vgh + src, (char*)Vsh + off);
        gload16(Vgl + src, (char*)Vsl + off);
      }
    }
    __syncthreads();

    // --- QK^T (3-way split) ---
    f32x4 sacc[4] = {};
#pragma unroll
    for (int kk = 0; kk < 4; ++kk) {
      bf16x8 kbh[4], kbl[4];
#pragma unroll
      for (int n = 0; n < 4; ++n) {
        int byte = ((n * 16 + lr) << 8) + (kk << 6) + (lg << 4);
        byte ^= ((byte >> 8) & 7) << 4;
        kbh[n] = *(const bf16x8*)((const char*)Ksh + byte);
        kbl[n] = *(const bf16x8*)((const char*)Ksl + byte);
      }
      __builtin_amdgcn_s_setprio(1);
#pragma unroll
      for (int n = 0; n < 4; ++n) {
        sacc[n] = __builtin_amdgcn_mfma_f32_16x16x32_bf16(qfl[kk], kbh[n], sacc[n], 0, 0, 0);
        sacc[n] = __builtin_amdgcn_mfma_f32_16x16x32_bf16(qfh[kk], kbl[n], sacc[n], 0, 0, 0);
        sacc[n] = __builtin_amdgcn_mfma_f32_16x16x32_bf16(qfh[kk], kbh[n], sacc[n], 0, 0, 0);
      }
      __builtin_amdgcn_s_setprio(0);
    }
    __syncthreads();   // all waves done reading K before P overlay write

    // --- online softmax (f32, in registers) ---
#pragma unroll
    for (int j = 0; j < 4; ++j) {
      float mx = fmaxf(fmaxf(sacc[0][j], sacc[1][j]),
                       fmaxf(sacc[2][j], sacc[3][j])) * scale;
      mx = fmaxf(mx, __shfl_xor(mx, 1));
      mx = fmaxf(mx, __shfl_xor(mx, 2));
      mx = fmaxf(mx, __shfl_xor(mx, 4));
      mx = fmaxf(mx, __shfl_xor(mx, 8));
      float mnew = fmaxf(rm[j], mx);
      float corr = __expf(rm[j] - mnew);
      rm[j] = mnew;
      float ps = 0.f;
#pragma unroll
      for (int n = 0; n < 4; ++n) {
        float p = __expf(sacc[n][j] * scale - mnew);
        sacc[n][j] = p; ps += p;
      }
      ps += __shfl_xor(ps, 1); ps += __shfl_xor(ps, 2);
      ps += __shfl_xor(ps, 4); ps += __shfl_xor(ps, 8);
      rls[j] = rls[j] * corr + ps;
#pragma unroll
      for (int n2 = 0; n2 < 6; ++n2) oacc[n2][j] *= corr;
    }

    // --- P: C-layout -> A-frag via per-wave LDS overlay (swizzled) ---
    char* Pwh = (char*)Ksh + (wid << 11);   // 2 KB per wave (16 rows x 128 B)
    char* Pwl = (char*)Ksl + (wid << 11);
#pragma unroll
    for (int n = 0; n < 4; ++n)
#pragma unroll
      for (int j = 0; j < 4; ++j) {
        int row = lg * 4 + j;
        int byte = (row << 7) + ((n * 16 + lr) << 1);
        byte ^= ((byte >> 7) & 7) << 4;
        u16 h, l; split2(sacc[n][j], h, l);
        *(u16*)(Pwh + byte) = h;
        *(u16*)(Pwl + byte) = l;
      }
    bf16x8 pah[2], pal[2];
#pragma unroll
    for (int kk = 0; kk < 2; ++kk) {
      int byte = (lr << 7) + (kk << 6) + (lg << 4);
      byte ^= ((byte >> 7) & 7) << 4;
      pah[kk] = *(const bf16x8*)(Pwh + byte);
      pal[kk] = *(const bf16x8*)(Pwl + byte);
    }

    // --- PV (3-way split), d<96 only ---
#pragma unroll
    for (int kk = 0; kk < 2; ++kk) {
      bf16x8 vbh[6], vbl[6];
#pragma unroll
      for (int n2 = 0; n2 < 6; ++n2) {
        int byte = ((n2 * 16 + lr) << 7) + (kk << 6) + (lg << 4);
        byte ^= ((byte >> 7) & 7) << 4;
        vbh[n2] = *(const bf16x8*)((const char*)Vsh + byte);
        vbl[n2] = *(const bf16x8*)((const char*)Vsl + byte);
      }
      __builtin_amdgcn_s_setprio(1);
#pragma unroll
      for (int n2 = 0; n2 < 6; ++n2) {
        oacc[n2] = __builtin_amdgcn_mfma_f32_16x16x32_bf16(pal[kk], vbh[n2], oacc[n2], 0, 0, 0);
        oacc[n2] = __builtin_amdgcn_mfma_f32_16x16x32_bf16(pah[kk], vbl[n2], oacc[n2], 0, 0, 0);
        oacc[n2] = __builtin_amdgcn_mfma_f32_16x16x32_bf16(pah[kk], vbh[n2], oacc[n2], 0, 0, 0);
      }
      __builtin_amdgcn_s_setprio(0);
    }
  }

  // --- epilogue: normalize, write merged hi/lo bf16 [B,S,768] ---
  const int b = bh >> 3, h = bh & 7;
#pragma unroll
  for (int j = 0; j < 4; ++j) {
    float inv = 1.0f / rls[j];
    int q = q0 + lg * 4 + j;
    long base = ((long)(b * S_LEN + q)) * DM + h * HDIM;
#pragma unroll
    for (int n2 = 0; n2 < 6; ++n2) {
      int d = n2 * 16 + lr;
      u16 hh, ll; split2(oacc[n2][j] * inv, hh, ll);
      omh[base + d] = hh; oml[base + d] = ll;
    }
  }
}

// ---------------------------------------------------------------------------
// fp32 [R][C] -> bf16 hi/lo [C][R]  (weight convert + transpose + split)
// ---------------------------------------------------------------------------
__global__ void wconv_t(const float* __restrict__ in, u16* __restrict__ outh,
                        u16* __restrict__ outl, int R, int C) {
  __shared__ float tile[32][33];
  int c0 = blockIdx.x << 5, r0 = blockIdx.y << 5;
  int tx = threadIdx.x;
  for (int rr = threadIdx.y; rr < 32; rr += 8)
    tile[rr][tx] = in[(long)(r0 + rr) * C + (c0 + tx)];
  __syncthreads();
  for (int rr = threadIdx.y; rr < 32; rr += 8) {
    u16 h, l; split2(tile[tx][rr], h, l);
    long o = (long)(c0 + rr) * R + (r0 + tx);
    outh[o] = h; outl[o] = l;
  }
}

__global__ __launch_bounds__(256) void ln_k(const float* __restrict__ in,
    const float* __restrict__ g, const float* __restrict__ b,
    float* __restrict__ outf, u16* __restrict__ outh, u16* __restrict__ outl) {
  int row = blockIdx.x;
  const float* x = in + (long)row * DM;
  int tid = threadIdx.x;
  float v[3], s = 0.f, ss = 0.f;
#pragma unroll
  for (int i = 0; i < 3; ++i) { v[i] = x[tid + (i << 8)]; s += v[i]; ss += v[i] * v[i]; }
  __shared__ float red[2][4];
  for (int o = 32; o; o >>= 1) { s += __shfl_down(s, o); ss += __shfl_down(ss, o); }
  int wid = tid >> 6, lane = tid & 63;
  if (!lane) { red[0][wid] = s; red[1][wid] = ss; }
  __syncthreads();
  s = red[0][0] + red[0][1] + red[0][2] + red[0][3];
  ss = red[1][0] + red[1][1] + red[1][2] + red[1][3];
  float mean = s * (1.f / DM);
  float var = ss * (1.f / DM) - mean * mean;
  float rs = rsqrtf(var + 1e-5f);
#pragma unroll
  for (int i = 0; i < 3; ++i) {
    int c = tid + (i << 8);
    float y = (v[i] - mean) * rs * g[c] + b[c];
    if (outf) outf[(long)row * DM + c] = y;
    if (outh) { u16 h, l; split2(y, h, l); outh[(long)row * DM + c] = h; outl[(long)row * DM + c] = l; }
  }
}

__global__ void rope_tables_k(float* __restrict__ cosT, float* __restrict__ sinT) {
  int s = blockIdx.x, d = threadIdx.x;
  int xc = s & 15, y = (s >> 4) & 15, t = s >> 8;
  int axis = d / 32, fi = d & 15;
  int coord = axis == 0 ? xc : (axis == 1 ? y : t);
  float inv = powf(10000.0f, -(float)fi / 16.0f);
  float ang = (float)coord * inv;
  cosT[s * HDIM + d] = cosf(ang);
  sinT[s * HDIM + d] = sinf(ang);
}

__global__ __launch_bounds__(256) void rope_apply_k(const float* __restrict__ qkv,
    const float* __restrict__ cosT, const float* __restrict__ sinT,
    u16* __restrict__ qh, u16* __restrict__ ql,
    u16* __restrict__ kh, u16* __restrict__ kl) {
  int bs = blockIdx.x;
  int b = bs >> 11, s = bs & 2047;
  const float* base = qkv + ((long)(b * S_LEN + s) * 3) * DM;
  for (int idx = threadIdx.x; idx < DM; idx += 256) {
    int h = idx / HDIM, d = idx - h * HDIM;
    float c = cosT[s * HDIM + d], sn = sinT[s * HDIM + d];
    int pair = (d < 48) ? idx + 48 : idx - 48;
    float qv = base[idx], kv = base[DM + idx];
    float qr = (d < 48) ? -base[pair] : base[pair];
    float kr = (d < 48) ? -base[DM + pair] : base[DM + pair];
    long o = ((long)(b * NHEAD + h) * S_LEN + s) * HDP + d;
    u16 hh, ll;
    split2(qv * c + qr * sn, hh, ll); qh[o] = hh; ql[o] = ll;
    split2(kv * c + kr * sn, hh, ll); kh[o] = hh; kl[o] = ll;
  }
  int t = threadIdx.x;
  int h = t >> 5, d = HDIM + (t & 31);
  long o = ((long)(b * NHEAD + h) * S_LEN + s) * HDP + d;
  qh[o] = 0; ql[o] = 0; kh[o] = 0; kl[o] = 0;
}

__global__ void v_transpose_k(const float* __restrict__ qkv,
                              u16* __restrict__ vh, u16* __restrict__ vl) {
  __shared__ float tile[32][33];
  int bh = blockIdx.z, b = bh >> 3, h = bh & 7;
  int s0 = blockIdx.x << 5, d0 = blockIdx.y << 5;
  int tx = threadIdx.x;
  for (int r = threadIdx.y; r < 32; r += 8) {
    int s = s0 + r, d = d0 + tx;
    float v = 0.f;
    if (d < HDIM) v = qkv[((long)(b * S_LEN + s) * 3 + 2) * DM + h * HDIM + d];
    tile[r][tx] = v;
  }
  __syncthreads();
  for (int r = threadIdx.y; r < 32; r += 8) {
    int d = d0 + r;
    u16 hh, ll; split2(tile[tx][r], hh, ll);
    long o = ((long)bh * HDP + d) * S_LEN + (s0 + tx);
    vh[o] = hh; vl[o] = ll;
  }
}

__global__ __launch_bounds__(256) void router_k(const float* __restrict__ x,
    const float* __restrict__ gw, float* __restrict__ comb) {
  int tok = blockIdx.x * 4 + (threadIdx.x >> 6);
  int lane = threadIdx.x & 63;
  const float* xr = x + (long)tok * DM;
  float a0 = 0, a1 = 0, a2 = 0, a3 = 0;
  for (int i = lane; i < DM; i += 64) {
    float xv = xr[i];
    const float* g = gw + i * 4;
    a0 += xv * g[0]; a1 += xv * g[1]; a2 += xv * g[2]; a3 += xv * g[3];
  }
  for (int o = 32; o; o >>= 1) {
    a0 += __shfl_down(a0, o); a1 += __shfl_down(a1, o);
    a2 += __shfl_down(a2, o); a3 += __shfl_down(a3, o);
  }
  if (lane == 0) {
    float p[4] = {a0, a1, a2, a3};
    float mx = fmaxf(fmaxf(p[0], p[1]), fmaxf(p[2], p[3]));
    float s = 0.f;
    for (int e = 0; e < 4; ++e) { p[e] = expf(p[e] - mx); s += p[e]; }
    for (int e = 0; e < 4; ++e) p[e] /= s;
    int i1 = 0;
    for (int e = 1; e < 4; ++e) if (p[e] > p[i1]) i1 = e;
    int i2 = -1;
    for (int e = 0; e < 4; ++e) if (e != i1 && (i2 < 0 || p[e] > p[i2])) i2 = e;
    float ssum = p[i1] + p[i2] + 1e-5f;
    float out[4] = {0, 0, 0, 0};
    out[i1] = p[i1] / ssum; out[i2] = p[i2] / ssum;
    for (int e = 0; e < 4; ++e) comb[tok * 4 + e] = out[e];
  }
}

// fused-gu f32 [tok][2FF]: hb = split(silu(g)*u*w)
__global__ void silu3_k(const float* __restrict__ gu, const float* __restrict__ comb,
                        int e, u16* __restrict__ hbh, u16* __restrict__ hbl,
                        long n, int tok0) {
  long i = (long)blockIdx.x * 256 + threadIdx.x;
  if (i >= n) return;
  int tl = (int)(i / FF), j = (int)(i - (long)tl * FF);
  float gv = gu[(long)tl * FF2 + j];
  float uv = gu[(long)tl * FF2 + FF + j];
  float w = comb ? comb[(tok0 + tl) * 4 + e] : 1.0f;
  float h = gv / (1.0f + expf(-gv)) * uv * w;
  u16 hh, ll; split2(h, hh, ll);
  hbh[i] = hh; hbl[i] = ll;
}

// fused-gu bf16 [tok][2FF]: hb = bf16(silu(g)*u*w)
__global__ void silu_mul_k(const u16* __restrict__ gu, const float* __restrict__ comb,
                           int e, u16* __restrict__ hb, long n, int tok0) {
  long i = (long)blockIdx.x * 256 + threadIdx.x;
  if (i >= n) return;
  int tl = (int)(i / FF), j = (int)(i - (long)tl * FF);
  float gv = bf2f(gu[(long)tl * FF2 + j]);
  float uv = bf2f(gu[(long)tl * FF2 + FF + j]);
  float w = comb ? comb[(tok0 + tl) * 4 + e] : 1.0f;
  hb[i] = f2bf(gv / (1.0f + expf(-gv)) * uv * w);
}

__global__ void add_k(float* __restrict__ dst, const float* __restrict__ src, long n) {
  long i = (long)blockIdx.x * 256 + threadIdx.x;
  if (i < n) dst[i] += src[i];
}

__global__ void zero_k(float* __restrict__ dst, long n) {
  long i = (long)blockIdx.x * 256 + threadIdx.x;
  if (i < n) dst[i] = 0.f;
}

__global__ void f2b_k(const float* __restrict__ src, u16* __restrict__ dst, long n) {
  long i = (long)blockIdx.x * 256 + threadIdx.x;
  if (i < n) dst[i] = f2bf(src[i]);
}

__global__ void f2bsplit_k(const float* __restrict__ src, u16* __restrict__ dh,
                           u16* __restrict__ dl, long n) {
  long i = (long)blockIdx.x * 256 + threadIdx.x;
  if (i < n) { u16 h, l; split2(src[i], h, l); dh[i] = h; dl[i] = l; }
}

// ---------------------------------------------------------------------------
static void gemm_launch(const void* A, const void* B, void* C, int M, int N, int K,
                        int lda, int ldb, long sA, long sB, long sC, int nb,
                        int kspl, int mode, hipStream_t st) {
  dim3 g(N >> 7, M >> 7, nb * kspl), blk(256, 1, 1);
  if (mode == 0)
    gemm_nt<0><<<g, blk, 0, st>>>((const u16*)A, (const u16*)B, C, M, N, K, lda, ldb, sA, sB, sC, kspl);
  else if (mode == 2)
    gemm_nt<2><<<g, blk, 0, st>>>((const u16*)A, (const u16*)B, C, M, N, K, lda, ldb, sA, sB, sC, kspl);
  else
    gemm_nt<3><<<g, blk, 0, st>>>((const u16*)A, (const u16*)B, C, M, N, K, lda, ldb, sA, sB, sC, kspl);
}

static void gemm3_launch(const void* Ah, const void* Al, const void* Bh, const void* Bl,
                         float* C, int M, int N, int K, int lda, int ldb,
                         long sA, long sB, long sC, int nb, int kspl, int mode,
                         hipStream_t st) {
  dim3 g(N >> 7, M >> 7, nb * kspl), blk(256, 1, 1);
  if (mode == 0)
    gemm3_nt<0><<<g, blk, 0, st>>>((const u16*)Ah, (const u16*)Al, (const u16*)Bh,
                                   (const u16*)Bl, C, M, N, K, lda, ldb, sA, sB, sC, kspl);
  else
    gemm3_nt<3><<<g, blk, 0, st>>>((const u16*)Ah, (const u16*)Al, (const u16*)Bh,
                                   (const u16*)Bl, C, M, N, K, lda, ldb, sA, sB, sC, kspl);
}

extern "C" void kernel_launch(void* const* d_in, const int* in_sizes, int n_in,
                              void* d_out, int out_size, void* d_ws, size_t ws_size,
                              hipStream_t stream) {
  (void)in_sizes; (void)n_in; (void)out_size;
  const float* x_in  = (const float*)d_in[0];
  const float* ln1_g = (const float*)d_in[4];
  const float* ln1_b = (const float*)d_in[5];
  const float* w_qkv = (const float*)d_in[6];
  const float* w_out = (const float*)d_in[7];
  const float* gatew = (const float*)d_in[8];
  const float* eg    = (const float*)d_in[9];
  const float* eu    = (const float*)d_in[10];
  const float* ed    = (const float*)d_in[11];
  const float* sg    = (const float*)d_in[12];
  const float* su    = (const float*)d_in[13];
  const float* sd    = (const float*)d_in[14];
  const float* ln2_g = (const float*)d_in[15];
  const float* ln2_b = (const float*)d_in[16];

  float* xc = (float*)d_out;
  char* W = (char*)d_ws;
  size_t off = 0;
  auto alloc = [&](size_t bytes) {
    size_t o = off; off = (off + bytes + 255) & ~(size_t)255; return o;
  };
  size_t o_cos  = alloc((size_t)S_LEN * HDIM * 4);
  size_t o_sin  = alloc((size_t)S_LEN * HDIM * 4);
  size_t o_xnh  = alloc((size_t)NTOK * DM * 2);
  size_t o_xnl  = alloc((size_t)NTOK * DM * 2);
  size_t o_qkv  = alloc((size_t)NTOK * 3 * DM * 4);
  size_t o_qph  = alloc((size_t)NBH * S_LEN * HDP * 2);
  size_t o_qpl  = alloc((size_t)NBH * S_LEN * HDP * 2);
  size_t o_kph  = alloc((size_t)NBH * S_LEN * HDP * 2);
  size_t o_kpl  = alloc((size_t)NBH * S_LEN * HDP * 2);
  size_t o_vth  = alloc((size_t)NBH * HDP * S_LEN * 2);
  size_t o_vtl  = alloc((size_t)NBH * HDP * S_LEN * 2);
  size_t o_omh  = alloc((size_t)NTOK * DM * 2);
  size_t o_oml  = alloc((size_t)NTOK * DM * 2);
  size_t o_tmp  = alloc((size_t)NTOK * DM * 4);
  size_t o_comb = alloc((size_t)NTOK * 4 * 4);
  size_t o_wqh  = alloc((size_t)3 * DM * DM * 2);
  size_t o_wql  = alloc((size_t)3 * DM * DM * 2);
  size_t o_woh  = alloc((size_t)DM * DM * 2);
  size_t o_wol  = alloc((size_t)DM * DM * 2);
  size_t o_sguh = alloc((size_t)FF2 * DM * 2);
  size_t o_sgul = alloc((size_t)FF2 * DM * 2);
  size_t o_sdh  = alloc((size_t)DM * FF * 2);
  size_t o_sdl  = alloc((size_t)DM * FF * 2);
  size_t o_eguh = alloc((size_t)FF2 * DM * 2);
  size_t o_egul = alloc((size_t)FF2 * DM * 2);
  size_t o_edh  = alloc((size_t)DM * FF * 2);
  size_t o_edl  = alloc((size_t)DM * FF * 2);
  size_t fixed_end = off;

  size_t avail = ws_size > fixed_end ? ws_size - fixed_end : 0;
  int mc = 1024;
  { const int c[3] = {4096, 2048, 1024};
    for (int i = 0; i < 3; ++i) if ((size_t)c[i] * FF * 12 <= avail) { mc = c[i]; break; } }

  size_t o_ga   = fixed_end;                        // mc*2FF f32 (fused gate|up)
  size_t o_hbh  = o_ga + (size_t)mc * FF2 * 4;
  size_t o_hbl  = o_hbh + (size_t)mc * FF * 2;
  size_t o_ga16 = fixed_end;                        // mc*2FF bf16 (layer-1)
  size_t o_hb16 = o_ga16 + (size_t)mc * FF2 * 2;

  float* cosT = (float*)(W + o_cos);
  float* sinT = (float*)(W + o_sin);
  u16*   xnh  = (u16*)(W + o_xnh);
  u16*   xnl  = (u16*)(W + o_xnl);
  float* qkv  = (float*)(W + o_qkv);
  u16 *qph = (u16*)(W + o_qph), *qpl = (u16*)(W + o_qpl);
  u16 *kph = (u16*)(W + o_kph), *kpl = (u16*)(W + o_kpl);
  u16 *vth = (u16*)(W + o_vth), *vtl = (u16*)(W + o_vtl);
  u16 *omh = (u16*)(W + o_omh), *oml = (u16*)(W + o_oml);
  float* tmp  = (float*)(W + o_tmp);
  float* comb = (float*)(W + o_comb);
  u16 *wqh = (u16*)(W + o_wqh), *wql = (u16*)(W + o_wql);
  u16 *woh = (u16*)(W + o_woh), *wol = (u16*)(W + o_wol);
  u16 *sguh = (u16*)(W + o_sguh), *sgul = (u16*)(W + o_sgul);
  u16 *sdh = (u16*)(W + o_sdh), *sdl = (u16*)(W + o_sdl);
  u16 *eguh = (u16*)(W + o_eguh), *egul = (u16*)(W + o_egul);
  u16 *edh = (u16*)(W + o_edh), *edl = (u16*)(W + o_edl);
  float* gaF = (float*)(W + o_ga);
  u16 *hbh = (u16*)(W + o_hbh), *hbl = (u16*)(W + o_hbl);
  u16 *ga16 = (u16*)(W + o_ga16), *hb16 = (u16*)(W + o_hb16);

  const long ND = (long)NTOK * DM;
  const int gND = (int)((ND + 255) / 256);

  hipMemcpyAsync(xc, x_in, (size_t)ND * 4, hipMemcpyDeviceToDevice, stream);
  rope_tables_k<<<S_LEN, HDIM, 0, stream>>>(cosT, sinT);

  dim3 tb(32, 8, 1);
  for (int l = 0; l < 2; ++l) {
    const float* wqkv_l = w_qkv + (size_t)l * DM * 3 * DM;
    const float* wout_l = w_out + (size_t)l * DM * DM;
    const float* gw_l   = gatew + (size_t)l * DM * 4;
    const float* eg_l = eg + (size_t)l * NEXP * DM * FF;
    const float* eu_l = eu + (size_t)l * NEXP * DM * FF;
    const float* ed_l = ed + (size_t)l * NEXP * FF * DM;
    const float* sg_l = sg + (size_t)l * DM * FF;
    const float* su_l = su + (size_t)l * DM * FF;
    const float* sd_l = sd + (size_t)l * FF * DM;

    wconv_t<<<dim3(3 * DM / 32, DM / 32), tb, 0, stream>>>(wqkv_l, wqh, wql, DM, 3 * DM);
    wconv_t<<<dim3(DM / 32, DM / 32), tb, 0, stream>>>(wout_l, woh, wol, DM, DM);
    wconv_t<<<dim3(FF / 32, DM / 32), tb, 0, stream>>>(sg_l, sguh, sgul, DM, FF);
    wconv_t<<<dim3(FF / 32, DM / 32), tb, 0, stream>>>(su_l, sguh + (size_t)FF * DM,
                                                       sgul + (size_t)FF * DM, DM, FF);
    wconv_t<<<dim3(DM / 32, FF / 32), tb, 0, stream>>>(sd_l, sdh, sdl, FF, DM);

    // --- attention (fp32-equivalent via bf16x3 + flash) ---
    ln_k<<<NTOK, 256, 0, stream>>>(xc, ln1_g + l * DM, ln1_b + l * DM, nullptr, xnh, xnl);
    gemm3_launch(xnh, xnl, wqh, wql, qkv, NTOK, 3 * DM, DM, DM, DM, 0, 0, 0, 1, 1, 0, stream);
    rope_apply_k<<<NTOK, 256, 0, stream>>>(qkv, cosT, sinT, qph, qpl, kph, kpl);
    v_transpose_k<<<dim3(S_LEN / 32, HDP / 32, NBH), tb, 0, stream>>>(qkv, vth, vtl);
    fattn_k<<<dim3(NBH, S_LEN / 64), dim3(256), 0, stream>>>(
        qph, qpl, kph, kpl, vth, vtl, omh, oml, 0.10206207261596575f);
    zero_k<<<gND, 256, 0, stream>>>(tmp, ND);
    gemm3_launch(omh, oml, woh, wol, tmp, NTOK, DM, DM, DM, DM, 0, 0, 0, 1, 2, 3, stream);
    add_k<<<gND, 256, 0, stream>>>(xc, tmp, ND);

    // --- router on fp32 x ---
    router_k<<<NTOK / 4, 256, 0, stream>>>(xc, gw_l, comb);

    int nch = NTOK / mc;
    zero_k<<<gND, 256, 0, stream>>>(tmp, ND);
    if (l == 0) {
      f2bsplit_k<<<gND, 256, 0, stream>>>(xc, xnh, xnl, ND);
      for (int c = 0; c < nch; ++c) {
        const u16 *xfh = xnh + (size_t)c * mc * DM, *xfl = xnl + (size_t)c * mc * DM;
        float* moc = tmp + (size_t)c * mc * DM;
        long nmc = (long)mc * FF;
        int gsz = (int)((nmc + 255) / 256);
        gemm3_launch(xfh, xfl, sguh, sgul, gaF, mc, FF2, DM, DM, DM, 0, 0, 0, 1, 1, 0, stream);
        silu3_k<<<gsz, 256, 0, stream>>>(gaF, nullptr, 0, hbh, hbl, nmc, c * mc);
        gemm3_launch(hbh, hbl, sdh, sdl, moc, mc, DM, FF, FF, FF, 0, 0, 0, 1, 4, 3, stream);
      }
      for (int e = 0; e < NEXP; ++e) {
        wconv_t<<<dim3(FF / 32, DM / 32), tb, 0, stream>>>(eg_l + (size_t)e * DM * FF, eguh, egul, DM, FF);
        wconv_t<<<dim3(FF / 32, DM / 32), tb, 0, stream>>>(eu_l + (size_t)e * DM * FF,
                                                           eguh + (size_t)FF * DM,
                                                           egul + (size_t)FF * DM, DM, FF);
        wconv_t<<<dim3(DM / 32, FF / 32), tb, 0, stream>>>(ed_l + (size_t)e * FF * DM, edh, edl, FF, DM);
        for (int c = 0; c < nch; ++c) {
          const u16 *xfh = xnh + (size_t)c * mc * DM, *xfl = xnl + (size_t)c * mc * DM;
          float* moc = tmp + (size_t)c * mc * DM;
          long nmc = (long)mc * FF;
          int gsz = (int)((nmc + 255) / 256);
          gemm3_launch(xfh, xfl, eguh, egul, gaF, mc, FF2, DM, DM, DM, 0, 0, 0, 1, 1, 0, stream);
          silu3_k<<<gsz, 256, 0, stream>>>(gaF, comb, e, hbh, hbl, nmc, c * mc);
          gemm3_launch(hbh, hbl, edh, edl, moc, mc, DM, FF, FF, FF, 0, 0, 0, 1, 4, 3, stream);
        }
      }
    } else {
      f2b_k<<<gND, 256, 0, stream>>>(xc, xnh, ND);
      for (int c = 0; c < nch; ++c) {
        const u16* xfh = xnh + (size_t)c * mc * DM;
        float* moc = tmp + (size_t)c * mc * DM;
        long nmc = (long)mc * FF;
        int gsz = (int)((nmc + 255) / 256);
        gemm_launch(xfh, sguh, ga16, mc, FF2, DM, DM, DM, 0, 0, 0, 1, 1, 2, stream);
        silu_mul_k<<<gsz, 256, 0, stream>>>(ga16, nullptr, 0, hb16, nmc, c * mc);
        gemm_launch(hb16, sdh, moc, mc, DM, FF, FF, FF, 0, 0, 0, 1, 4, 3, stream);
      }
      for (int e = 0; e < NEXP; ++e) {
        wconv_t<<<dim3(FF / 32, DM / 32), tb, 0, stream>>>(eg_l + (size_t)e * DM * FF, eguh, egul, DM, FF);
        wconv_t<<<dim3(FF / 32, DM / 32), tb, 0, stream>>>(eu_l + (size_t)e * DM * FF,
                                                           eguh + (size_t)FF * DM,
                                                           egul + (size_t)FF * DM, DM, FF);
        wconv_t<<<dim3(DM / 32, FF / 32), tb, 0, stream>>>(ed_l + (size_t)e * FF * DM, edh, edl, FF, DM);
        for (int c = 0; c < nch; ++c) {
          const u16* xfh = xnh + (size_t)c * mc * DM;
          float* moc = tmp + (size_t)c * mc * DM;
          long nmc = (long)mc * FF;
          int gsz = (int)((nmc + 255) / 256);
          gemm_launch(xfh, eguh, ga16, mc, FF2, DM, DM, DM, 0, 0, 0, 1, 1, 2, stream);
          silu_mul_k<<<gsz, 256, 0, stream>>>(ga16, comb, e, hb16, nmc, c * mc);
          gemm_launch(hb16, edh, moc, mc, DM, FF, FF, FF, 0, 0, 0, 1, 4, 3, stream);
        }
      }
    }
    add_k<<<gND, 256, 0, stream>>>(xc, tmp, ND);
    ln_k<<<NTOK, 256, 0, stream>>>(xc, ln2_g + l * DM, ln2_b + l * DM, xc, nullptr, nullptr);
  }
}

// Round 6
// 2773.680 us; speedup vs baseline: 1.9969x; 1.0942x over previous
//
#include <hip/hip_runtime.h>
#include <stdint.h>

#define S_LEN 2048
#define DM    768
#define NHEAD 8
#define HDIM  96
#define HDP   128
#define FF    3072
#define FF2   6144
#define NEXP  4
#define NTOK  4096
#define NBH   16

typedef unsigned short u16;
typedef short bf16x8 __attribute__((ext_vector_type(8)));
typedef float f32x4 __attribute__((ext_vector_type(4)));
typedef __attribute__((address_space(1))) void* gptr_t;
typedef __attribute__((address_space(3))) void* lptr_t;

__device__ __forceinline__ u16 f2bf(float f) {
  union { float f; uint32_t u; } v; v.f = f;
  uint32_t r = v.u + 0x7FFFu + ((v.u >> 16) & 1u);
  return (u16)(r >> 16);
}
__device__ __forceinline__ float bf2f(u16 h) {
  union { uint32_t u; float f; } v; v.u = ((uint32_t)h) << 16;
  return v.f;
}
__device__ __forceinline__ void split2(float f, u16& hi, u16& lo) {
  u16 h = f2bf(f);
  lo = f2bf(f - bf2f(h));
  hi = h;
}
__device__ __forceinline__ void gload16(const void* g, void* l) {
  __builtin_amdgcn_global_load_lds((gptr_t)(void*)g, (lptr_t)l, 16, 0, 0);
}

// ---------------------------------------------------------------------------
// Plain NT GEMM, 2-phase double-buffered.
// C[M,N] = A[M,K] @ B[N,K]^T. MODE: 0 f32 write, 2 bf16 write, 3 atomic f32.
// ---------------------------------------------------------------------------
template<int MODE>
__global__ __launch_bounds__(256) void gemm_nt(
    const u16* __restrict__ A, const u16* __restrict__ B, void* __restrict__ Cv,
    int M, int N, int K, int lda, int ldb, long sA, long sB, long sC, int kspl)
{
  __shared__ u16 As[2][128 * 32];
  __shared__ u16 Bs[2][128 * 32];
  const int z = blockIdx.z;
  const int bh = z / kspl;
  const int kc = z - bh * kspl;
  const u16* Az = A + (long)bh * sA;
  const u16* Bz = B + (long)bh * sB;
  const int brow = blockIdx.y << 7;
  const int bcol = blockIdx.x << 7;
  const int tid = threadIdx.x;
  const int wid = tid >> 6;
  const int lane = tid & 63;
  const int wr = (wid >> 1) << 6;
  const int wc = (wid & 1) << 6;

  f32x4 acc[4][4] = {};
  const int a0 = (wid << 11) + (lane << 4);

  auto stage = [&](int buf, int k0) {
#pragma unroll
    for (int c = 0; c < 2; ++c) {
      int ab = a0 + (c << 10);
      int row = ab >> 6;
      int kcol = (ab & 63) >> 1;
      int ld = (wid << 11) + (c << 10);
      gload16(Az + (long)(brow + row) * lda + (k0 + kcol), (char*)As[buf] + ld);
      gload16(Bz + (long)(bcol + row) * ldb + (k0 + kcol), (char*)Bs[buf] + ld);
    }
  };

  const int kt = K / kspl;
  const int kbeg = kc * kt;
  const int nt = kt >> 5;
  stage(0, kbeg);
  __syncthreads();
  for (int t = 0; t < nt; ++t) {
    const int cur = t & 1;
    if (t + 1 < nt) stage(cur ^ 1, kbeg + ((t + 1) << 5));
    bf16x8 af[4], bfr[4];
    const int lr = lane & 15;
    const int lk = (lane >> 4) << 4;
#pragma unroll
    for (int m = 0; m < 4; ++m)
      af[m] = *(const bf16x8*)((const char*)As[cur] + (((wr + m * 16 + lr) << 6) + lk));
#pragma unroll
    for (int n = 0; n < 4; ++n)
      bfr[n] = *(const bf16x8*)((const char*)Bs[cur] + (((wc + n * 16 + lr) << 6) + lk));
#pragma unroll
    for (int m = 0; m < 4; ++m)
#pragma unroll
      for (int n = 0; n < 4; ++n)
        acc[m][n] = __builtin_amdgcn_mfma_f32_16x16x32_bf16(af[m], bfr[n], acc[m][n], 0, 0, 0);
    if (t + 1 < nt) __syncthreads();
  }

  const int crow0 = brow + wr + ((lane >> 4) << 2);
  const int ccol0 = bcol + wc + (lane & 15);
  const long cbase = (long)bh * sC;
#pragma unroll
  for (int m = 0; m < 4; ++m)
#pragma unroll
    for (int n = 0; n < 4; ++n)
#pragma unroll
      for (int j = 0; j < 4; ++j) {
        long idx = cbase + (long)(crow0 + m * 16 + j) * N + (ccol0 + n * 16);
        float v = acc[m][n][j];
        if constexpr (MODE == 2) ((u16*)Cv)[idx] = f2bf(v);
        else if constexpr (MODE == 3) unsafeAtomicAdd((float*)Cv + idx, v);
        else ((float*)Cv)[idx] = v;
      }
}

// ---------------------------------------------------------------------------
// Split (bf16x3) NT GEMM, 2-phase double-buffered. fp32-equivalent.
// MODE: 0 f32 write, 3 atomic f32.
// ---------------------------------------------------------------------------
template<int MODE>
__global__ __launch_bounds__(256) void gemm3_nt(
    const u16* __restrict__ Ah, const u16* __restrict__ Al,
    const u16* __restrict__ Bh, const u16* __restrict__ Bl,
    float* __restrict__ C,
    int M, int N, int K, int lda, int ldb, long sA, long sB, long sC, int kspl)
{
  __shared__ u16 Ash[2][128 * 32], Asl[2][128 * 32];
  __shared__ u16 Bsh[2][128 * 32], Bsl[2][128 * 32];
  const int z = blockIdx.z;
  const int bh = z / kspl;
  const int kc = z - bh * kspl;
  const u16* Azh = Ah + (long)bh * sA;
  const u16* Azl = Al + (long)bh * sA;
  const u16* Bzh = Bh + (long)bh * sB;
  const u16* Bzl = Bl + (long)bh * sB;
  const int brow = blockIdx.y << 7;
  const int bcol = blockIdx.x << 7;
  const int tid = threadIdx.x;
  const int wid = tid >> 6;
  const int lane = tid & 63;
  const int wr = (wid >> 1) << 6;
  const int wc = (wid & 1) << 6;

  f32x4 acc[4][4] = {};
  const int a0 = (wid << 11) + (lane << 4);

  auto stage = [&](int buf, int k0) {
#pragma unroll
    for (int c = 0; c < 2; ++c) {
      int ab = a0 + (c << 10);
      int row = ab >> 6;
      int kcol = (ab & 63) >> 1;
      long ao = (long)(brow + row) * lda + (k0 + kcol);
      long bo = (long)(bcol + row) * ldb + (k0 + kcol);
      int ld = (wid << 11) + (c << 10);
      gload16(Azh + ao, (char*)Ash[buf] + ld);
      gload16(Azl + ao, (char*)Asl[buf] + ld);
      gload16(Bzh + bo, (char*)Bsh[buf] + ld);
      gload16(Bzl + bo, (char*)Bsl[buf] + ld);
    }
  };

  const int kt = K / kspl;
  const int kbeg = kc * kt;
  const int nt = kt >> 5;
  stage(0, kbeg);
  __syncthreads();
  for (int t = 0; t < nt; ++t) {
    const int cur = t & 1;
    if (t + 1 < nt) stage(cur ^ 1, kbeg + ((t + 1) << 5));
    const int lr = lane & 15;
    const int lk = (lane >> 4) << 4;
    bf16x8 ah[4], al[4], bh_[4], bl[4];
#pragma unroll
    for (int m = 0; m < 4; ++m) {
      int off = ((wr + m * 16 + lr) << 6) + lk;
      ah[m] = *(const bf16x8*)((const char*)Ash[cur] + off);
      al[m] = *(const bf16x8*)((const char*)Asl[cur] + off);
    }
#pragma unroll
    for (int n = 0; n < 4; ++n) {
      int off = ((wc + n * 16 + lr) << 6) + lk;
      bh_[n] = *(const bf16x8*)((const char*)Bsh[cur] + off);
      bl[n] = *(const bf16x8*)((const char*)Bsl[cur] + off);
    }
#pragma unroll
    for (int m = 0; m < 4; ++m)
#pragma unroll
      for (int n = 0; n < 4; ++n) {
        acc[m][n] = __builtin_amdgcn_mfma_f32_16x16x32_bf16(al[m], bh_[n], acc[m][n], 0, 0, 0);
        acc[m][n] = __builtin_amdgcn_mfma_f32_16x16x32_bf16(ah[m], bl[n], acc[m][n], 0, 0, 0);
        acc[m][n] = __builtin_amdgcn_mfma_f32_16x16x32_bf16(ah[m], bh_[n], acc[m][n], 0, 0, 0);
      }
    if (t + 1 < nt) __syncthreads();
  }

  const int crow0 = brow + wr + ((lane >> 4) << 2);
  const int ccol0 = bcol + wc + (lane & 15);
  const long cbase = (long)bh * sC;
#pragma unroll
  for (int m = 0; m < 4; ++m)
#pragma unroll
    for (int n = 0; n < 4; ++n)
#pragma unroll
      for (int j = 0; j < 4; ++j) {
        long idx = cbase + (long)(crow0 + m * 16 + j) * N + (ccol0 + n * 16);
        if constexpr (MODE == 3) unsafeAtomicAdd(&C[idx], acc[m][n][j]);
        else C[idx] = acc[m][n][j];
      }
}

// ---------------------------------------------------------------------------
// Indirect split GEMM for sparse MoE (compact expert token lists).
// MODE 0: gather-A rows via perm, write f32 compact C.
// MODE 1: compact-A, scatter-atomic f32 C to perm rows.
// Global compact position g = rowOff + local row; active iff g < *cntp.
// ---------------------------------------------------------------------------
template<int MODE>
__global__ __launch_bounds__(256) void gemm3i_nt(
    const u16* __restrict__ Ah, const u16* __restrict__ Al,
    const u16* __restrict__ Bh, const u16* __restrict__ Bl,
    float* __restrict__ C, int N, int K, int lda, int ldb, int ldc,
    const int* __restrict__ perm, const int* __restrict__ cntp,
    int rowOff, int kspl)
{
  const int cn = *cntp;
  const int brow = blockIdx.y << 7;
  if (rowOff + brow >= cn) return;
  __shared__ u16 Ash[2][128 * 32], Asl[2][128 * 32];
  __shared__ u16 Bsh[2][128 * 32], Bsl[2][128 * 32];
  const int kc = blockIdx.z;
  const int bcol = blockIdx.x << 7;
  const int tid = threadIdx.x;
  const int wid = tid >> 6;
  const int lane = tid & 63;
  const int wr = (wid >> 1) << 6;
  const int wc = (wid & 1) << 6;

  f32x4 acc[4][4] = {};
  const int a0 = (wid << 11) + (lane << 4);

  int arow[2];
#pragma unroll
  for (int c = 0; c < 2; ++c) {
    int ab = a0 + (c << 10);
    int row = ab >> 6;
    if constexpr (MODE == 0) {
      int g = rowOff + brow + row;
      arow[c] = (g < cn) ? perm[g] : perm[rowOff + brow];
    } else {
      arow[c] = brow + row;
    }
  }

  auto stage = [&](int buf, int k0) {
#pragma unroll
    for (int c = 0; c < 2; ++c) {
      int ab = a0 + (c << 10);
      int row = ab >> 6;
      int kcol = (ab & 63) >> 1;
      int ld = (wid << 11) + (c << 10);
      gload16(Ah + (long)arow[c] * lda + (k0 + kcol), (char*)Ash[buf] + ld);
      gload16(Al + (long)arow[c] * lda + (k0 + kcol), (char*)Asl[buf] + ld);
      long bo = (long)(bcol + row) * ldb + (k0 + kcol);
      gload16(Bh + bo, (char*)Bsh[buf] + ld);
      gload16(Bl + bo, (char*)Bsl[buf] + ld);
    }
  };

  const int kt = K / kspl;
  const int kbeg = kc * kt;
  const int nt = kt >> 5;
  stage(0, kbeg);
  __syncthreads();
  for (int t = 0; t < nt; ++t) {
    const int cur = t & 1;
    if (t + 1 < nt) stage(cur ^ 1, kbeg + ((t + 1) << 5));
    const int lr = lane & 15;
    const int lk = (lane >> 4) << 4;
    bf16x8 ah[4], al[4], bh_[4], bl[4];
#pragma unroll
    for (int m = 0; m < 4; ++m) {
      int off = ((wr + m * 16 + lr) << 6) + lk;
      ah[m] = *(const bf16x8*)((const char*)Ash[cur] + off);
      al[m] = *(const bf16x8*)((const char*)Asl[cur] + off);
    }
#pragma unroll
    for (int n = 0; n < 4; ++n) {
      int off = ((wc + n * 16 + lr) << 6) + lk;
      bh_[n] = *(const bf16x8*)((const char*)Bsh[cur] + off);
      bl[n] = *(const bf16x8*)((const char*)Bsl[cur] + off);
    }
#pragma unroll
    for (int m = 0; m < 4; ++m)
#pragma unroll
      for (int n = 0; n < 4; ++n) {
        acc[m][n] = __builtin_amdgcn_mfma_f32_16x16x32_bf16(al[m], bh_[n], acc[m][n], 0, 0, 0);
        acc[m][n] = __builtin_amdgcn_mfma_f32_16x16x32_bf16(ah[m], bl[n], acc[m][n], 0, 0, 0);
        acc[m][n] = __builtin_amdgcn_mfma_f32_16x16x32_bf16(ah[m], bh_[n], acc[m][n], 0, 0, 0);
      }
    if (t + 1 < nt) __syncthreads();
  }

  const int crow0 = brow + wr + ((lane >> 4) << 2);
  const int ccol0 = bcol + wc + (lane & 15);
#pragma unroll
  for (int m = 0; m < 4; ++m)
#pragma unroll
    for (int n = 0; n < 4; ++n)
#pragma unroll
      for (int j = 0; j < 4; ++j) {
        int cr = crow0 + m * 16 + j;
        int g = rowOff + cr;
        if (g < cn) {
          int col = ccol0 + n * 16;
          if constexpr (MODE == 0) C[(long)cr * ldc + col] = acc[m][n][j];
          else unsafeAtomicAdd(&C[(long)perm[g] * ldc + col], acc[m][n][j]);
        }
      }
}

// ---------------------------------------------------------------------------
// Indirect plain bf16 GEMM (layer-1 experts).
// MODE 2: gather-A, write bf16 compact. MODE 3: compact-A, scatter-atomic f32.
// ---------------------------------------------------------------------------
template<int MODE>
__global__ __launch_bounds__(256) void gemmi_nt(
    const u16* __restrict__ A, const u16* __restrict__ B, void* __restrict__ Cv,
    int N, int K, int lda, int ldb, int ldc,
    const int* __restrict__ perm, const int* __restrict__ cntp,
    int rowOff, int kspl)
{
  const int cn = *cntp;
  const int brow = blockIdx.y << 7;
  if (rowOff + brow >= cn) return;
  __shared__ u16 As[2][128 * 32];
  __shared__ u16 Bs[2][128 * 32];
  const int kc = blockIdx.z;
  const int bcol = blockIdx.x << 7;
  const int tid = threadIdx.x;
  const int wid = tid >> 6;
  const int lane = tid & 63;
  const int wr = (wid >> 1) << 6;
  const int wc = (wid & 1) << 6;

  f32x4 acc[4][4] = {};
  const int a0 = (wid << 11) + (lane << 4);

  int arow[2];
#pragma unroll
  for (int c = 0; c < 2; ++c) {
    int ab = a0 + (c << 10);
    int row = ab >> 6;
    if constexpr (MODE == 2) {
      int g = rowOff + brow + row;
      arow[c] = (g < cn) ? perm[g] : perm[rowOff + brow];
    } else {
      arow[c] = brow + row;
    }
  }

  auto stage = [&](int buf, int k0) {
#pragma unroll
    for (int c = 0; c < 2; ++c) {
      int ab = a0 + (c << 10);
      int row = ab >> 6;
      int kcol = (ab & 63) >> 1;
      int ld = (wid << 11) + (c << 10);
      gload16(A + (long)arow[c] * lda + (k0 + kcol), (char*)As[buf] + ld);
      gload16(B + (long)(bcol + row) * ldb + (k0 + kcol), (char*)Bs[buf] + ld);
    }
  };

  const int kt = K / kspl;
  const int kbeg = kc * kt;
  const int nt = kt >> 5;
  stage(0, kbeg);
  __syncthreads();
  for (int t = 0; t < nt; ++t) {
    const int cur = t & 1;
    if (t + 1 < nt) stage(cur ^ 1, kbeg + ((t + 1) << 5));
    bf16x8 af[4], bfr[4];
    const int lr = lane & 15;
    const int lk = (lane >> 4) << 4;
#pragma unroll
    for (int m = 0; m < 4; ++m)
      af[m] = *(const bf16x8*)((const char*)As[cur] + (((wr + m * 16 + lr) << 6) + lk));
#pragma unroll
    for (int n = 0; n < 4; ++n)
      bfr[n] = *(const bf16x8*)((const char*)Bs[cur] + (((wc + n * 16 + lr) << 6) + lk));
#pragma unroll
    for (int m = 0; m < 4; ++m)
#pragma unroll
      for (int n = 0; n < 4; ++n)
        acc[m][n] = __builtin_amdgcn_mfma_f32_16x16x32_bf16(af[m], bfr[n], acc[m][n], 0, 0, 0);
    if (t + 1 < nt) __syncthreads();
  }

  const int crow0 = brow + wr + ((lane >> 4) << 2);
  const int ccol0 = bcol + wc + (lane & 15);
#pragma unroll
  for (int m = 0; m < 4; ++m)
#pragma unroll
    for (int n = 0; n < 4; ++n)
#pragma unroll
      for (int j = 0; j < 4; ++j) {
        int cr = crow0 + m * 16 + j;
        int g = rowOff + cr;
        if (g < cn) {
          int col = ccol0 + n * 16;
          if constexpr (MODE == 2) ((u16*)Cv)[(long)cr * ldc + col] = f2bf(acc[m][n][j]);
          else unsafeAtomicAdd((float*)Cv + (long)perm[g] * ldc + col, acc[m][n][j]);
        }
      }
}

// ---------------------------------------------------------------------------
// Fused flash attention (unchanged from round 4's 64-row variant).
// ---------------------------------------------------------------------------
__global__ __launch_bounds__(256, 2) void fattn_k(
    const u16* __restrict__ qh, const u16* __restrict__ ql,
    const u16* __restrict__ kh, const u16* __restrict__ kl,
    const u16* __restrict__ vth, const u16* __restrict__ vtl,
    u16* __restrict__ omh, u16* __restrict__ oml, float scale)
{
  __shared__ u16 Ksh[64 * 128], Ksl[64 * 128];
  __shared__ u16 Vsh[128 * 64], Vsl[128 * 64];
  const int bh = blockIdx.x;
  const int qt = blockIdx.y;
  const int tid = threadIdx.x, wid = tid >> 6, lane = tid & 63;
  const int lr = lane & 15, lg = lane >> 4;
  const int q0 = qt * 64 + wid * 16;
  const long bhoff = (long)bh * S_LEN * HDP;
  const u16* Qh = qh + bhoff;  const u16* Ql = ql + bhoff;
  const u16* Kgh = kh + bhoff; const u16* Kgl = kl + bhoff;
  const u16* Vgh = vth + bhoff; const u16* Vgl = vtl + bhoff;

  bf16x8 qfh[4], qfl[4];
#pragma unroll
  for (int kk = 0; kk < 4; ++kk) {
    long o = (long)(q0 + lr) * HDP + kk * 32 + lg * 8;
    qfh[kk] = *(const bf16x8*)(Qh + o);
    qfl[kk] = *(const bf16x8*)(Ql + o);
  }

  f32x4 oacc[6] = {};
  float rm[4], rls[4];
#pragma unroll
  for (int j = 0; j < 4; ++j) { rm[j] = -1e30f; rls[j] = 0.f; }

  for (int t = 0; t < S_LEN / 64; ++t) {
    __syncthreads();
#pragma unroll
    for (int c = 0; c < 4; ++c) {
      int off = (tid + (c << 8)) << 4;
      {
        int lb = off ^ ((((off >> 8) & 7)) << 4);
        int row = lb >> 8, colh = (lb & 255) >> 1;
        long src = (long)(t * 64 + row) * HDP + colh;
        gload16(Kgh + src, (char*)Ksh + off);
        gload16(Kgl + src, (char*)Ksl + off);
      }
      {
        int lb = off ^ ((((off >> 7) & 7)) << 4);
        int row = lb >> 7, colh = (lb & 127) >> 1;
        long src = (long)row * S_LEN + t * 64 + colh;
        gload16(Vgh + src, (char*)Vsh + off);
        gload16(Vgl + src, (char*)Vsl + off);
      }
    }
    __syncthreads();

    f32x4 sacc[4] = {};
#pragma unroll
    for (int kk = 0; kk < 4; ++kk) {
      bf16x8 kbh[4], kbl[4];
#pragma unroll
      for (int n = 0; n < 4; ++n) {
        int byte = ((n * 16 + lr) << 8) + (kk << 6) + (lg << 4);
        byte ^= ((byte >> 8) & 7) << 4;
        kbh[n] = *(const bf16x8*)((const char*)Ksh + byte);
        kbl[n] = *(const bf16x8*)((const char*)Ksl + byte);
      }
      __builtin_amdgcn_s_setprio(1);
#pragma unroll
      for (int n = 0; n < 4; ++n) {
        sacc[n] = __builtin_amdgcn_mfma_f32_16x16x32_bf16(qfl[kk], kbh[n], sacc[n], 0, 0, 0);
        sacc[n] = __builtin_amdgcn_mfma_f32_16x16x32_bf16(qfh[kk], kbl[n], sacc[n], 0, 0, 0);
        sacc[n] = __builtin_amdgcn_mfma_f32_16x16x32_bf16(qfh[kk], kbh[n], sacc[n], 0, 0, 0);
      }
      __builtin_amdgcn_s_setprio(0);
    }
    __syncthreads();

#pragma unroll
    for (int j = 0; j < 4; ++j) {
      float mx = fmaxf(fmaxf(sacc[0][j], sacc[1][j]),
                       fmaxf(sacc[2][j], sacc[3][j])) * scale;
      mx = fmaxf(mx, __shfl_xor(mx, 1));
      mx = fmaxf(mx, __shfl_xor(mx, 2));
      mx = fmaxf(mx, __shfl_xor(mx, 4));
      mx = fmaxf(mx, __shfl_xor(mx, 8));
      float mnew = fmaxf(rm[j], mx);
      float corr = __expf(rm[j] - mnew);
      rm[j] = mnew;
      float ps = 0.f;
#pragma unroll
      for (int n = 0; n < 4; ++n) {
        float p = __expf(sacc[n][j] * scale - mnew);
        sacc[n][j] = p; ps += p;
      }
      ps += __shfl_xor(ps, 1); ps += __shfl_xor(ps, 2);
      ps += __shfl_xor(ps, 4); ps += __shfl_xor(ps, 8);
      rls[j] = rls[j] * corr + ps;
#pragma unroll
      for (int n2 = 0; n2 < 6; ++n2) oacc[n2][j] *= corr;
    }

    char* Pwh = (char*)Ksh + (wid << 11);
    char* Pwl = (char*)Ksl + (wid << 11);
#pragma unroll
    for (int n = 0; n < 4; ++n)
#pragma unroll
      for (int j = 0; j < 4; ++j) {
        int row = lg * 4 + j;
        int byte = (row << 7) + ((n * 16 + lr) << 1);
        byte ^= ((byte >> 7) & 7) << 4;
        u16 h, l; split2(sacc[n][j], h, l);
        *(u16*)(Pwh + byte) = h;
        *(u16*)(Pwl + byte) = l;
      }
    bf16x8 pah[2], pal[2];
#pragma unroll
    for (int kk = 0; kk < 2; ++kk) {
      int byte = (lr << 7) + (kk << 6) + (lg << 4);
      byte ^= ((byte >> 7) & 7) << 4;
      pah[kk] = *(const bf16x8*)(Pwh + byte);
      pal[kk] = *(const bf16x8*)(Pwl + byte);
    }

#pragma unroll
    for (int kk = 0; kk < 2; ++kk) {
      bf16x8 vbh[6], vbl[6];
#pragma unroll
      for (int n2 = 0; n2 < 6; ++n2) {
        int byte = ((n2 * 16 + lr) << 7) + (kk << 6) + (lg << 4);
        byte ^= ((byte >> 7) & 7) << 4;
        vbh[n2] = *(const bf16x8*)((const char*)Vsh + byte);
        vbl[n2] = *(const bf16x8*)((const char*)Vsl + byte);
      }
      __builtin_amdgcn_s_setprio(1);
#pragma unroll
      for (int n2 = 0; n2 < 6; ++n2) {
        oacc[n2] = __builtin_amdgcn_mfma_f32_16x16x32_bf16(pal[kk], vbh[n2], oacc[n2], 0, 0, 0);
        oacc[n2] = __builtin_amdgcn_mfma_f32_16x16x32_bf16(pah[kk], vbl[n2], oacc[n2], 0, 0, 0);
        oacc[n2] = __builtin_amdgcn_mfma_f32_16x16x32_bf16(pah[kk], vbh[n2], oacc[n2], 0, 0, 0);
      }
      __builtin_amdgcn_s_setprio(0);
    }
  }

  const int b = bh >> 3, h = bh & 7;
#pragma unroll
  for (int j = 0; j < 4; ++j) {
    float inv = 1.0f / rls[j];
    int q = q0 + lg * 4 + j;
    long base = ((long)(b * S_LEN + q)) * DM + h * HDIM;
#pragma unroll
    for (int n2 = 0; n2 < 6; ++n2) {
      int d = n2 * 16 + lr;
      u16 hh, ll; split2(oacc[n2][j] * inv, hh, ll);
      omh[base + d] = hh; oml[base + d] = ll;
    }
  }
}

// ---------------------------------------------------------------------------
__global__ void wconv_t(const float* __restrict__ in, u16* __restrict__ outh,
                        u16* __restrict__ outl, int R, int C) {
  __shared__ float tile[32][33];
  int c0 = blockIdx.x << 5, r0 = blockIdx.y << 5;
  int tx = threadIdx.x;
  for (int rr = threadIdx.y; rr < 32; rr += 8)
    tile[rr][tx] = in[(long)(r0 + rr) * C + (c0 + tx)];
  __syncthreads();
  for (int rr = threadIdx.y; rr < 32; rr += 8) {
    u16 h, l; split2(tile[tx][rr], h, l);
    long o = (long)(c0 + rr) * R + (r0 + tx);
    outh[o] = h; outl[o] = l;
  }
}

__global__ __launch_bounds__(256) void ln_k(const float* __restrict__ in,
    const float* __restrict__ g, const float* __restrict__ b,
    float* __restrict__ outf, u16* __restrict__ outh, u16* __restrict__ outl) {
  int row = blockIdx.x;
  const float* x = in + (long)row * DM;
  int tid = threadIdx.x;
  float v[3], s = 0.f, ss = 0.f;
#pragma unroll
  for (int i = 0; i < 3; ++i) { v[i] = x[tid + (i << 8)]; s += v[i]; ss += v[i] * v[i]; }
  __shared__ float red[2][4];
  for (int o = 32; o; o >>= 1) { s += __shfl_down(s, o); ss += __shfl_down(ss, o); }
  int wid = tid >> 6, lane = tid & 63;
  if (!lane) { red[0][wid] = s; red[1][wid] = ss; }
  __syncthreads();
  s = red[0][0] + red[0][1] + red[0][2] + red[0][3];
  ss = red[1][0] + red[1][1] + red[1][2] + red[1][3];
  float mean = s * (1.f / DM);
  float var = ss * (1.f / DM) - mean * mean;
  float rs = rsqrtf(var + 1e-5f);
#pragma unroll
  for (int i = 0; i < 3; ++i) {
    int c = tid + (i << 8);
    float y = (v[i] - mean) * rs * g[c] + b[c];
    if (outf) outf[(long)row * DM + c] = y;
    if (outh) { u16 h, l; split2(y, h, l); outh[(long)row * DM + c] = h; outl[(long)row * DM + c] = l; }
  }
}

__global__ void rope_tables_k(float* __restrict__ cosT, float* __restrict__ sinT) {
  int s = blockIdx.x, d = threadIdx.x;
  int xc = s & 15, y = (s >> 4) & 15, t = s >> 8;
  int axis = d / 32, fi = d & 15;
  int coord = axis == 0 ? xc : (axis == 1 ? y : t);
  float inv = powf(10000.0f, -(float)fi / 16.0f);
  float ang = (float)coord * inv;
  cosT[s * HDIM + d] = cosf(ang);
  sinT[s * HDIM + d] = sinf(ang);
}

__global__ __launch_bounds__(256) void rope_apply_k(const float* __restrict__ qkv,
    const float* __restrict__ cosT, const float* __restrict__ sinT,
    u16* __restrict__ qh, u16* __restrict__ ql,
    u16* __restrict__ kh, u16* __restrict__ kl) {
  int bs = blockIdx.x;
  int b = bs >> 11, s = bs & 2047;
  const float* base = qkv + ((long)(b * S_LEN + s) * 3) * DM;
  for (int idx = threadIdx.x; idx < DM; idx += 256) {
    int h = idx / HDIM, d = idx - h * HDIM;
    float c = cosT[s * HDIM + d], sn = sinT[s * HDIM + d];
    int pair = (d < 48) ? idx + 48 : idx - 48;
    float qv = base[idx], kv = base[DM + idx];
    float qr = (d < 48) ? -base[pair] : base[pair];
    float kr = (d < 48) ? -base[DM + pair] : base[DM + pair];
    long o = ((long)(b * NHEAD + h) * S_LEN + s) * HDP + d;
    u16 hh, ll;
    split2(qv * c + qr * sn, hh, ll); qh[o] = hh; ql[o] = ll;
    split2(kv * c + kr * sn, hh, ll); kh[o] = hh; kl[o] = ll;
  }
  int t = threadIdx.x;
  int h = t >> 5, d = HDIM + (t & 31);
  long o = ((long)(b * NHEAD + h) * S_LEN + s) * HDP + d;
  qh[o] = 0; ql[o] = 0; kh[o] = 0; kl[o] = 0;
}

__global__ void v_transpose_k(const float* __restrict__ qkv,
                              u16* __restrict__ vh, u16* __restrict__ vl) {
  __shared__ float tile[32][33];
  int bh = blockIdx.z, b = bh >> 3, h = bh & 7;
  int s0 = blockIdx.x << 5, d0 = blockIdx.y << 5;
  int tx = threadIdx.x;
  for (int r = threadIdx.y; r < 32; r += 8) {
    int s = s0 + r, d = d0 + tx;
    float v = 0.f;
    if (d < HDIM) v = qkv[((long)(b * S_LEN + s) * 3 + 2) * DM + h * HDIM + d];
    tile[r][tx] = v;
  }
  __syncthreads();
  for (int r = threadIdx.y; r < 32; r += 8) {
    int d = d0 + r;
    u16 hh, ll; split2(tile[tx][r], hh, ll);
    long o = ((long)bh * HDP + d) * S_LEN + (s0 + tx);
    vh[o] = hh; vl[o] = ll;
  }
}

// Router: comb[tok][e] + top-2 bitmask per token.
__global__ __launch_bounds__(256) void router_k(const float* __restrict__ x,
    const float* __restrict__ gw, float* __restrict__ comb, int* __restrict__ mask) {
  int tok = blockIdx.x * 4 + (threadIdx.x >> 6);
  int lane = threadIdx.x & 63;
  const float* xr = x + (long)tok * DM;
  float a0 = 0, a1 = 0, a2 = 0, a3 = 0;
  for (int i = lane; i < DM; i += 64) {
    float xv = xr[i];
    const float* g = gw + i * 4;
    a0 += xv * g[0]; a1 += xv * g[1]; a2 += xv * g[2]; a3 += xv * g[3];
  }
  for (int o = 32; o; o >>= 1) {
    a0 += __shfl_down(a0, o); a1 += __shfl_down(a1, o);
    a2 += __shfl_down(a2, o); a3 += __shfl_down(a3, o);
  }
  if (lane == 0) {
    float p[4] = {a0, a1, a2, a3};
    float mx = fmaxf(fmaxf(p[0], p[1]), fmaxf(p[2], p[3]));
    float s = 0.f;
    for (int e = 0; e < 4; ++e) { p[e] = expf(p[e] - mx); s += p[e]; }
    for (int e = 0; e < 4; ++e) p[e] /= s;
    int i1 = 0;
    for (int e = 1; e < 4; ++e) if (p[e] > p[i1]) i1 = e;
    int i2 = -1;
    for (int e = 0; e < 4; ++e) if (e != i1 && (i2 < 0 || p[e] > p[i2])) i2 = e;
    float ssum = p[i1] + p[i2] + 1e-5f;
    float out[4] = {0, 0, 0, 0};
    out[i1] = p[i1] / ssum; out[i2] = p[i2] / ssum;
    for (int e = 0; e < 4; ++e) comb[tok * 4 + e] = out[e];
    mask[tok] = (1 << i1) | (1 << i2);
  }
}

// Deterministic per-expert compaction: perm[e][pos]=tok (token-index order).
__global__ void scan_k(const int* __restrict__ mask, int* __restrict__ perm,
                       int* __restrict__ cnt) {
  __shared__ int sd[256];
  __shared__ int base;
  int tid = threadIdx.x;
  for (int e = 0; e < NEXP; ++e) {
    if (tid == 0) base = 0;
    __syncthreads();
    for (int c = 0; c < NTOK / 256; ++c) {
      int tok = c * 256 + tid;
      int f = (mask[tok] >> e) & 1;
      sd[tid] = f;
      __syncthreads();
      for (int s = 1; s < 256; s <<= 1) {
        int v = (tid >= s) ? sd[tid - s] : 0;
        __syncthreads();
        sd[tid] += v;
        __syncthreads();
      }
      if (f) perm[e * NTOK + base + sd[tid] - 1] = tok;
      int tot = sd[255];
      __syncthreads();
      if (tid == 0) base += tot;
      __syncthreads();
    }
    if (tid == 0) cnt[e] = base;
    __syncthreads();
  }
}

// dense fused-gu f32 silu (shared expert)
__global__ void silu3_k(const float* __restrict__ gu, const float* __restrict__ comb,
                        int e, u16* __restrict__ hbh, u16* __restrict__ hbl,
                        long n, int tok0) {
  long i = (long)blockIdx.x * 256 + threadIdx.x;
  if (i >= n) return;
  int tl = (int)(i / FF), j = (int)(i - (long)tl * FF);
  float gv = gu[(long)tl * FF2 + j];
  float uv = gu[(long)tl * FF2 + FF + j];
  float w = comb ? comb[(tok0 + tl) * 4 + e] : 1.0f;
  float h = gv / (1.0f + expf(-gv)) * uv * w;
  u16 hh, ll; split2(h, hh, ll);
  hbh[i] = hh; hbl[i] = ll;
}

// dense fused-gu bf16 silu (layer-1 shared)
__global__ void silu_mul_k(const u16* __restrict__ gu, const float* __restrict__ comb,
                           int e, u16* __restrict__ hb, long n, int tok0) {
  long i = (long)blockIdx.x * 256 + threadIdx.x;
  if (i >= n) return;
  int tl = (int)(i / FF), j = (int)(i - (long)tl * FF);
  float gv = bf2f(gu[(long)tl * FF2 + j]);
  float uv = bf2f(gu[(long)tl * FF2 + FF + j]);
  float w = comb ? comb[(tok0 + tl) * 4 + e] : 1.0f;
  hb[i] = f2bf(gv / (1.0f + expf(-gv)) * uv * w);
}

// compact f32 silu (layer-0 experts): grid (FF/256, mc)
__global__ void silu3i_k(const float* __restrict__ gu, const float* __restrict__ comb,
                         const int* __restrict__ perm, const int* __restrict__ cntp,
                         int e, u16* __restrict__ hbh, u16* __restrict__ hbl, int rowOff) {
  int pos = blockIdx.y;
  if (rowOff + pos >= *cntp) return;
  int j = blockIdx.x * 256 + threadIdx.x;
  float gv = gu[(long)pos * FF2 + j];
  float uv = gu[(long)pos * FF2 + FF + j];
  float w = comb[perm[rowOff + pos] * 4 + e];
  float h = gv / (1.0f + expf(-gv)) * uv * w;
  u16 hh, ll; split2(h, hh, ll);
  long o = (long)pos * FF + j;
  hbh[o] = hh; hbl[o] = ll;
}

// compact bf16 silu (layer-1 experts)
__global__ void silui_k(const u16* __restrict__ gu, const float* __restrict__ comb,
                        const int* __restrict__ perm, const int* __restrict__ cntp,
                        int e, u16* __restrict__ hb, int rowOff) {
  int pos = blockIdx.y;
  if (rowOff + pos >= *cntp) return;
  int j = blockIdx.x * 256 + threadIdx.x;
  float gv = bf2f(gu[(long)pos * FF2 + j]);
  float uv = bf2f(gu[(long)pos * FF2 + FF + j]);
  float w = comb[perm[rowOff + pos] * 4 + e];
  hb[(long)pos * FF + j] = f2bf(gv / (1.0f + expf(-gv)) * uv * w);
}

__global__ void add_k(float* __restrict__ dst, const float* __restrict__ src, long n) {
  long i = (long)blockIdx.x * 256 + threadIdx.x;
  if (i < n) dst[i] += src[i];
}

__global__ void zero_k(float* __restrict__ dst, long n) {
  long i = (long)blockIdx.x * 256 + threadIdx.x;
  if (i < n) dst[i] = 0.f;
}

__global__ void f2b_k(const float* __restrict__ src, u16* __restrict__ dst, long n) {
  long i = (long)blockIdx.x * 256 + threadIdx.x;
  if (i < n) dst[i] = f2bf(src[i]);
}

__global__ void f2bsplit_k(const float* __restrict__ src, u16* __restrict__ dh,
                           u16* __restrict__ dl, long n) {
  long i = (long)blockIdx.x * 256 + threadIdx.x;
  if (i < n) { u16 h, l; split2(src[i], h, l); dh[i] = h; dl[i] = l; }
}

// ---------------------------------------------------------------------------
static void gemm_launch(const void* A, const void* B, void* C, int M, int N, int K,
                        int lda, int ldb, long sA, long sB, long sC, int nb,
                        int kspl, int mode, hipStream_t st) {
  dim3 g(N >> 7, M >> 7, nb * kspl), blk(256, 1, 1);
  if (mode == 0)
    gemm_nt<0><<<g, blk, 0, st>>>((const u16*)A, (const u16*)B, C, M, N, K, lda, ldb, sA, sB, sC, kspl);
  else if (mode == 2)
    gemm_nt<2><<<g, blk, 0, st>>>((const u16*)A, (const u16*)B, C, M, N, K, lda, ldb, sA, sB, sC, kspl);
  else
    gemm_nt<3><<<g, blk, 0, st>>>((const u16*)A, (const u16*)B, C, M, N, K, lda, ldb, sA, sB, sC, kspl);
}

static void gemm3_launch(const void* Ah, const void* Al, const void* Bh, const void* Bl,
                         float* C, int M, int N, int K, int lda, int ldb,
                         long sA, long sB, long sC, int nb, int kspl, int mode,
                         hipStream_t st) {
  dim3 g(N >> 7, M >> 7, nb * kspl), blk(256, 1, 1);
  if (mode == 0)
    gemm3_nt<0><<<g, blk, 0, st>>>((const u16*)Ah, (const u16*)Al, (const u16*)Bh,
                                   (const u16*)Bl, C, M, N, K, lda, ldb, sA, sB, sC, kspl);
  else
    gemm3_nt<3><<<g, blk, 0, st>>>((const u16*)Ah, (const u16*)Al, (const u16*)Bh,
                                   (const u16*)Bl, C, M, N, K, lda, ldb, sA, sB, sC, kspl);
}

extern "C" void kernel_launch(void* const* d_in, const int* in_sizes, int n_in,
                              void* d_out, int out_size, void* d_ws, size_t ws_size,
                              hipStream_t stream) {
  (void)in_sizes; (void)n_in; (void)out_size;
  const float* x_in  = (const float*)d_in[0];
  const float* ln1_g = (const float*)d_in[4];
  const float* ln1_b = (const float*)d_in[5];
  const float* w_qkv = (const float*)d_in[6];
  const float* w_out = (const float*)d_in[7];
  const float* gatew = (const float*)d_in[8];
  const float* eg    = (const float*)d_in[9];
  const float* eu    = (const float*)d_in[10];
  const float* ed    = (const float*)d_in[11];
  const float* sg    = (const float*)d_in[12];
  const float* su    = (const float*)d_in[13];
  const float* sd    = (const float*)d_in[14];
  const float* ln2_g = (const float*)d_in[15];
  const float* ln2_b = (const float*)d_in[16];

  float* xc = (float*)d_out;
  char* W = (char*)d_ws;
  size_t off = 0;
  auto alloc = [&](size_t bytes) {
    size_t o = off; off = (off + bytes + 255) & ~(size_t)255; return o;
  };
  size_t o_cos  = alloc((size_t)S_LEN * HDIM * 4);
  size_t o_sin  = alloc((size_t)S_LEN * HDIM * 4);
  size_t o_xnh  = alloc((size_t)NTOK * DM * 2);
  size_t o_xnl  = alloc((size_t)NTOK * DM * 2);
  size_t o_qkv  = alloc((size_t)NTOK * 3 * DM * 4);
  size_t o_qph  = alloc((size_t)NBH * S_LEN * HDP * 2);
  size_t o_qpl  = alloc((size_t)NBH * S_LEN * HDP * 2);
  size_t o_kph  = alloc((size_t)NBH * S_LEN * HDP * 2);
  size_t o_kpl  = alloc((size_t)NBH * S_LEN * HDP * 2);
  size_t o_vth  = alloc((size_t)NBH * HDP * S_LEN * 2);
  size_t o_vtl  = alloc((size_t)NBH * HDP * S_LEN * 2);
  size_t o_omh  = alloc((size_t)NTOK * DM * 2);
  size_t o_oml  = alloc((size_t)NTOK * DM * 2);
  size_t o_tmp  = alloc((size_t)NTOK * DM * 4);
  size_t o_comb = alloc((size_t)NTOK * 4 * 4);
  size_t o_mask = alloc((size_t)NTOK * 4);
  size_t o_perm = alloc((size_t)NEXP * NTOK * 4);
  size_t o_cnt  = alloc(256);
  size_t o_wqh  = alloc((size_t)3 * DM * DM * 2);
  size_t o_wql  = alloc((size_t)3 * DM * DM * 2);
  size_t o_woh  = alloc((size_t)DM * DM * 2);
  size_t o_wol  = alloc((size_t)DM * DM * 2);
  size_t o_sguh = alloc((size_t)FF2 * DM * 2);
  size_t o_sgul = alloc((size_t)FF2 * DM * 2);
  size_t o_sdh  = alloc((size_t)DM * FF * 2);
  size_t o_sdl  = alloc((size_t)DM * FF * 2);
  size_t o_eguh = alloc((size_t)FF2 * DM * 2);
  size_t o_egul = alloc((size_t)FF2 * DM * 2);
  size_t o_edh  = alloc((size_t)DM * FF * 2);
  size_t o_edl  = alloc((size_t)DM * FF * 2);
  size_t fixed_end = off;

  size_t avail = ws_size > fixed_end ? ws_size - fixed_end : 0;
  int mc = 1024;
  { const int c[3] = {4096, 2048, 1024};
    for (int i = 0; i < 3; ++i) if ((size_t)c[i] * FF * 12 <= avail) { mc = c[i]; break; } }

  size_t o_ga   = fixed_end;                        // mc*2FF f32 (fused gate|up)
  size_t o_hbh  = o_ga + (size_t)mc * FF2 * 4;
  size_t o_hbl  = o_hbh + (size_t)mc * FF * 2;
  size_t o_ga16 = fixed_end;                        // mc*2FF bf16 (layer-1)
  size_t o_hb16 = o_ga16 + (size_t)mc * FF2 * 2;

  float* cosT = (float*)(W + o_cos);
  float* sinT = (float*)(W + o_sin);
  u16*   xnh  = (u16*)(W + o_xnh);
  u16*   xnl  = (u16*)(W + o_xnl);
  float* qkv  = (float*)(W + o_qkv);
  u16 *qph = (u16*)(W + o_qph), *qpl = (u16*)(W + o_qpl);
  u16 *kph = (u16*)(W + o_kph), *kpl = (u16*)(W + o_kpl);
  u16 *vth = (u16*)(W + o_vth), *vtl = (u16*)(W + o_vtl);
  u16 *omh = (u16*)(W + o_omh), *oml = (u16*)(W + o_oml);
  float* tmp  = (float*)(W + o_tmp);
  float* comb = (float*)(W + o_comb);
  int* maskb  = (int*)(W + o_mask);
  int* permb  = (int*)(W + o_perm);
  int* cntb   = (int*)(W + o_cnt);
  u16 *wqh = (u16*)(W + o_wqh), *wql = (u16*)(W + o_wql);
  u16 *woh = (u16*)(W + o_woh), *wol = (u16*)(W + o_wol);
  u16 *sguh = (u16*)(W + o_sguh), *sgul = (u16*)(W + o_sgul);
  u16 *sdh = (u16*)(W + o_sdh), *sdl = (u16*)(W + o_sdl);
  u16 *eguh = (u16*)(W + o_eguh), *egul = (u16*)(W + o_egul);
  u16 *edh = (u16*)(W + o_edh), *edl = (u16*)(W + o_edl);
  float* gaF = (float*)(W + o_ga);
  u16 *hbh = (u16*)(W + o_hbh), *hbl = (u16*)(W + o_hbl);
  u16 *ga16 = (u16*)(W + o_ga16), *hb16 = (u16*)(W + o_hb16);

  const long ND = (long)NTOK * DM;
  const int gND = (int)((ND + 255) / 256);

  hipMemcpyAsync(xc, x_in, (size_t)ND * 4, hipMemcpyDeviceToDevice, stream);
  rope_tables_k<<<S_LEN, HDIM, 0, stream>>>(cosT, sinT);

  dim3 tb(32, 8, 1);
  const int nch = NTOK / mc;
  for (int l = 0; l < 2; ++l) {
    const float* wqkv_l = w_qkv + (size_t)l * DM * 3 * DM;
    const float* wout_l = w_out + (size_t)l * DM * DM;
    const float* gw_l   = gatew + (size_t)l * DM * 4;
    const float* eg_l = eg + (size_t)l * NEXP * DM * FF;
    const float* eu_l = eu + (size_t)l * NEXP * DM * FF;
    const float* ed_l = ed + (size_t)l * NEXP * FF * DM;
    const float* sg_l = sg + (size_t)l * DM * FF;
    const float* su_l = su + (size_t)l * DM * FF;
    const float* sd_l = sd + (size_t)l * FF * DM;

    wconv_t<<<dim3(3 * DM / 32, DM / 32), tb, 0, stream>>>(wqkv_l, wqh, wql, DM, 3 * DM);
    wconv_t<<<dim3(DM / 32, DM / 32), tb, 0, stream>>>(wout_l, woh, wol, DM, DM);
    wconv_t<<<dim3(FF / 32, DM / 32), tb, 0, stream>>>(sg_l, sguh, sgul, DM, FF);
    wconv_t<<<dim3(FF / 32, DM / 32), tb, 0, stream>>>(su_l, sguh + (size_t)FF * DM,
                                                       sgul + (size_t)FF * DM, DM, FF);
    wconv_t<<<dim3(DM / 32, FF / 32), tb, 0, stream>>>(sd_l, sdh, sdl, FF, DM);

    // --- attention (fp32-equivalent via bf16x3 + flash) ---
    ln_k<<<NTOK, 256, 0, stream>>>(xc, ln1_g + l * DM, ln1_b + l * DM, nullptr, xnh, xnl);
    gemm3_launch(xnh, xnl, wqh, wql, qkv, NTOK, 3 * DM, DM, DM, DM, 0, 0, 0, 1, 1, 0, stream);
    rope_apply_k<<<NTOK, 256, 0, stream>>>(qkv, cosT, sinT, qph, qpl, kph, kpl);
    v_transpose_k<<<dim3(S_LEN / 32, HDP / 32, NBH), tb, 0, stream>>>(qkv, vth, vtl);
    fattn_k<<<dim3(NBH, S_LEN / 64), dim3(256), 0, stream>>>(
        qph, qpl, kph, kpl, vth, vtl, omh, oml, 0.10206207261596575f);
    zero_k<<<gND, 256, 0, stream>>>(tmp, ND);
    gemm3_launch(omh, oml, woh, wol, tmp, NTOK, DM, DM, DM, DM, 0, 0, 0, 1, 2, 3, stream);
    add_k<<<gND, 256, 0, stream>>>(xc, tmp, ND);

    // --- router + deterministic expert compaction ---
    router_k<<<NTOK / 4, 256, 0, stream>>>(xc, gw_l, comb, maskb);
    scan_k<<<1, 256, 0, stream>>>(maskb, permb, cntb);

    zero_k<<<gND, 256, 0, stream>>>(tmp, ND);
    if (l == 0) {
      f2bsplit_k<<<gND, 256, 0, stream>>>(xc, xnh, xnl, ND);
      // shared expert (dense)
      for (int c = 0; c < nch; ++c) {
        const u16 *xfh = xnh + (size_t)c * mc * DM, *xfl = xnl + (size_t)c * mc * DM;
        float* moc = tmp + (size_t)c * mc * DM;
        long nmc = (long)mc * FF;
        int gsz = (int)((nmc + 255) / 256);
        gemm3_launch(xfh, xfl, sguh, sgul, gaF, mc, FF2, DM, DM, DM, 0, 0, 0, 1, 1, 0, stream);
        silu3_k<<<gsz, 256, 0, stream>>>(gaF, nullptr, 0, hbh, hbl, nmc, c * mc);
        gemm3_launch(hbh, hbl, sdh, sdl, moc, mc, DM, FF, FF, FF, 0, 0, 0, 1, 4, 3, stream);
      }
      // routed experts (sparse, gather/scatter)
      for (int e = 0; e < NEXP; ++e) {
        wconv_t<<<dim3(FF / 32, DM / 32), tb, 0, stream>>>(eg_l + (size_t)e * DM * FF, eguh, egul, DM, FF);
        wconv_t<<<dim3(FF / 32, DM / 32), tb, 0, stream>>>(eu_l + (size_t)e * DM * FF,
                                                           eguh + (size_t)FF * DM,
                                                           egul + (size_t)FF * DM, DM, FF);
        wconv_t<<<dim3(DM / 32, FF / 32), tb, 0, stream>>>(ed_l + (size_t)e * FF * DM, edh, edl, FF, DM);
        const int* pe = permb + e * NTOK;
        const int* ce = cntb + e;
        for (int c = 0; c < nch; ++c) {
          int rowOff = c * mc;
          gemm3i_nt<0><<<dim3(FF2 >> 7, mc >> 7, 1), 256, 0, stream>>>(
              xnh, xnl, eguh, egul, gaF, FF2, DM, DM, DM, FF2, pe, ce, rowOff, 1);
          silu3i_k<<<dim3(FF / 256, mc), 256, 0, stream>>>(gaF, comb, pe, ce, e, hbh, hbl, rowOff);
          gemm3i_nt<1><<<dim3(DM >> 7, mc >> 7, 4), 256, 0, stream>>>(
              hbh, hbl, edh, edl, tmp, DM, FF, FF, FF, DM, pe, ce, rowOff, 4);
        }
      }
    } else {
      f2b_k<<<gND, 256, 0, stream>>>(xc, xnh, ND);
      for (int c = 0; c < nch; ++c) {
        const u16* xfh = xnh + (size_t)c * mc * DM;
        float* moc = tmp + (size_t)c * mc * DM;
        long nmc = (long)mc * FF;
        int gsz = (int)((nmc + 255) / 256);
        gemm_launch(xfh, sguh, ga16, mc, FF2, DM, DM, DM, 0, 0, 0, 1, 1, 2, stream);
        silu_mul_k<<<gsz, 256, 0, stream>>>(ga16, nullptr, 0, hb16, nmc, c * mc);
        gemm_launch(hb16, sdh, moc, mc, DM, FF, FF, FF, 0, 0, 0, 1, 4, 3, stream);
      }
      for (int e = 0; e < NEXP; ++e) {
        wconv_t<<<dim3(FF / 32, DM / 32), tb, 0, stream>>>(eg_l + (size_t)e * DM * FF, eguh, egul, DM, FF);
        wconv_t<<<dim3(FF / 32, DM / 32), tb, 0, stream>>>(eu_l + (size_t)e * DM * FF,
                                                           eguh + (size_t)FF * DM,
                                                           egul + (size_t)FF * DM, DM, FF);
        wconv_t<<<dim3(DM / 32, FF / 32), tb, 0, stream>>>(ed_l + (size_t)e * FF * DM, edh, edl, FF, DM);
        const int* pe = permb + e * NTOK;
        const int* ce = cntb + e;
        for (int c = 0; c < nch; ++c) {
          int rowOff = c * mc;
          gemmi_nt<2><<<dim3(FF2 >> 7, mc >> 7, 1), 256, 0, stream>>>(
              xnh, eguh, ga16, FF2, DM, DM, DM, FF2, pe, ce, rowOff, 1);
          silui_k<<<dim3(FF / 256, mc), 256, 0, stream>>>(ga16, comb, pe, ce, e, hb16, rowOff);
          gemmi_nt<3><<<dim3(DM >> 7, mc >> 7, 4), 256, 0, stream>>>(
              hb16, edh, tmp, DM, FF, FF, FF, DM, pe, ce, rowOff, 4);
        }
      }
    }
    add_k<<<gND, 256, 0, stream>>>(xc, tmp, ND);
    ln_k<<<NTOK, 256, 0, stream>>>(xc, ln2_g + l * DM, ln2_b + l * DM, xc, nullptr, nullptr);
  }
}

// Round 7
// 2139.731 us; speedup vs baseline: 2.5885x; 1.2963x over previous
//
#include <hip/hip_runtime.h>
#include <stdint.h>

#define S_LEN 2048
#define DM    768
#define NHEAD 8
#define HDIM  96
#define HDP   128
#define FF    3072
#define FF2   6144
#define NEXP  4
#define NTOK  4096
#define NBH   16

typedef unsigned short u16;
typedef short bf16x8 __attribute__((ext_vector_type(8)));
typedef float f32x4 __attribute__((ext_vector_type(4)));
typedef __attribute__((address_space(1))) void* gptr_t;
typedef __attribute__((address_space(3))) void* lptr_t;

__device__ __forceinline__ u16 f2bf(float f) {
  union { float f; uint32_t u; } v; v.f = f;
  uint32_t r = v.u + 0x7FFFu + ((v.u >> 16) & 1u);
  return (u16)(r >> 16);
}
__device__ __forceinline__ float bf2f(u16 h) {
  union { uint32_t u; float f; } v; v.u = ((uint32_t)h) << 16;
  return v.f;
}
__device__ __forceinline__ void split2(float f, u16& hi, u16& lo) {
  u16 h = f2bf(f);
  lo = f2bf(f - bf2f(h));
  hi = h;
}
__device__ __forceinline__ float siluf(float g) {
  return g / (1.0f + expf(-g));
}
__device__ __forceinline__ void gload16(const void* g, void* l) {
  __builtin_amdgcn_global_load_lds((gptr_t)(void*)g, (lptr_t)l, 16, 0, 0);
}

// ---------------------------------------------------------------------------
// Plain NT GEMM, 2-phase double-buffered. C[M,N] = A[M,K] @ B[N,K]^T.
// MODE: 0 f32 write, 2 bf16 write, 3 atomic f32,
//       5 fused gate/up silu epilogue -> hb bf16 (B rows 16-col interleaved).
// ---------------------------------------------------------------------------
template<int MODE>
__global__ __launch_bounds__(256) void gemm_nt(
    const u16* __restrict__ A, const u16* __restrict__ B, void* __restrict__ Cv,
    int M, int N, int K, int lda, int ldb, long sA, long sB, long sC, int kspl,
    u16* __restrict__ hb)
{
  __shared__ u16 As[2][128 * 32];
  __shared__ u16 Bs[2][128 * 32];
  const int z = blockIdx.z;
  const int bh = z / kspl;
  const int kc = z - bh * kspl;
  const u16* Az = A + (long)bh * sA;
  const u16* Bz = B + (long)bh * sB;
  const int brow = blockIdx.y << 7;
  const int bcol = blockIdx.x << 7;
  const int tid = threadIdx.x;
  const int wid = tid >> 6;
  const int lane = tid & 63;
  const int wr = (wid >> 1) << 6;
  const int wc = (wid & 1) << 6;

  f32x4 acc[4][4] = {};
  const int a0 = (wid << 11) + (lane << 4);

  auto stage = [&](int buf, int k0) {
#pragma unroll
    for (int c = 0; c < 2; ++c) {
      int ab = a0 + (c << 10);
      int row = ab >> 6;
      int kcol = (ab & 63) >> 1;
      int ld = (wid << 11) + (c << 10);
      gload16(Az + (long)(brow + row) * lda + (k0 + kcol), (char*)As[buf] + ld);
      gload16(Bz + (long)(bcol + row) * ldb + (k0 + kcol), (char*)Bs[buf] + ld);
    }
  };

  const int kt = K / kspl;
  const int kbeg = kc * kt;
  const int nt = kt >> 5;
  stage(0, kbeg);
  __syncthreads();
  for (int t = 0; t < nt; ++t) {
    const int cur = t & 1;
    if (t + 1 < nt) stage(cur ^ 1, kbeg + ((t + 1) << 5));
    bf16x8 af[4], bfr[4];
    const int lr = lane & 15;
    const int lk = (lane >> 4) << 4;
#pragma unroll
    for (int m = 0; m < 4; ++m)
      af[m] = *(const bf16x8*)((const char*)As[cur] + (((wr + m * 16 + lr) << 6) + lk));
#pragma unroll
    for (int n = 0; n < 4; ++n)
      bfr[n] = *(const bf16x8*)((const char*)Bs[cur] + (((wc + n * 16 + lr) << 6) + lk));
#pragma unroll
    for (int m = 0; m < 4; ++m)
#pragma unroll
      for (int n = 0; n < 4; ++n)
        acc[m][n] = __builtin_amdgcn_mfma_f32_16x16x32_bf16(af[m], bfr[n], acc[m][n], 0, 0, 0);
    if (t + 1 < nt) __syncthreads();
  }

  const int crow0 = brow + wr + ((lane >> 4) << 2);
  const int ccol0 = bcol + wc + (lane & 15);
  const long cbase = (long)bh * sC;
  if constexpr (MODE == 5) {
    const int pbase = (bcol + wc) >> 5;
#pragma unroll
    for (int m = 0; m < 4; ++m)
#pragma unroll
      for (int np = 0; np < 2; ++np)
#pragma unroll
        for (int j = 0; j < 4; ++j) {
          int r = crow0 + m * 16 + j;
          float g = acc[m][2 * np][j], u = acc[m][2 * np + 1][j];
          int hcol = ((pbase + np) << 4) + (lane & 15);
          hb[(long)r * FF + hcol] = f2bf(siluf(g) * u);
        }
  } else {
#pragma unroll
    for (int m = 0; m < 4; ++m)
#pragma unroll
      for (int n = 0; n < 4; ++n)
#pragma unroll
        for (int j = 0; j < 4; ++j) {
          long idx = cbase + (long)(crow0 + m * 16 + j) * N + (ccol0 + n * 16);
          float v = acc[m][n][j];
          if constexpr (MODE == 2) ((u16*)Cv)[idx] = f2bf(v);
          else if constexpr (MODE == 3) unsafeAtomicAdd((float*)Cv + idx, v);
          else ((float*)Cv)[idx] = v;
        }
  }
}

// ---------------------------------------------------------------------------
// Split (bf16x3) NT GEMM, dense. fp32-equivalent.
// MODE: 0 f32 write, 3 atomic f32, 5 fused gu silu -> hbh/hbl (split bf16).
// ---------------------------------------------------------------------------
template<int MODE>
__global__ __launch_bounds__(256) void gemm3_nt(
    const u16* __restrict__ Ah, const u16* __restrict__ Al,
    const u16* __restrict__ Bh, const u16* __restrict__ Bl,
    float* __restrict__ C,
    int M, int N, int K, int lda, int ldb, long sA, long sB, long sC, int kspl,
    u16* __restrict__ hbh, u16* __restrict__ hbl)
{
  __shared__ u16 Ash[2][128 * 32], Asl[2][128 * 32];
  __shared__ u16 Bsh[2][128 * 32], Bsl[2][128 * 32];
  const int z = blockIdx.z;
  const int bh = z / kspl;
  const int kc = z - bh * kspl;
  const u16* Azh = Ah + (long)bh * sA;
  const u16* Azl = Al + (long)bh * sA;
  const u16* Bzh = Bh + (long)bh * sB;
  const u16* Bzl = Bl + (long)bh * sB;
  const int brow = blockIdx.y << 7;
  const int bcol = blockIdx.x << 7;
  const int tid = threadIdx.x;
  const int wid = tid >> 6;
  const int lane = tid & 63;
  const int wr = (wid >> 1) << 6;
  const int wc = (wid & 1) << 6;

  f32x4 acc[4][4] = {};
  const int a0 = (wid << 11) + (lane << 4);

  auto stage = [&](int buf, int k0) {
#pragma unroll
    for (int c = 0; c < 2; ++c) {
      int ab = a0 + (c << 10);
      int row = ab >> 6;
      int kcol = (ab & 63) >> 1;
      long ao = (long)(brow + row) * lda + (k0 + kcol);
      long bo = (long)(bcol + row) * ldb + (k0 + kcol);
      int ld = (wid << 11) + (c << 10);
      gload16(Azh + ao, (char*)Ash[buf] + ld);
      gload16(Azl + ao, (char*)Asl[buf] + ld);
      gload16(Bzh + bo, (char*)Bsh[buf] + ld);
      gload16(Bzl + bo, (char*)Bsl[buf] + ld);
    }
  };

  const int kt = K / kspl;
  const int kbeg = kc * kt;
  const int nt = kt >> 5;
  stage(0, kbeg);
  __syncthreads();
  for (int t = 0; t < nt; ++t) {
    const int cur = t & 1;
    if (t + 1 < nt) stage(cur ^ 1, kbeg + ((t + 1) << 5));
    const int lr = lane & 15;
    const int lk = (lane >> 4) << 4;
    bf16x8 ah[4], al[4], bh_[4], bl[4];
#pragma unroll
    for (int m = 0; m < 4; ++m) {
      int off = ((wr + m * 16 + lr) << 6) + lk;
      ah[m] = *(const bf16x8*)((const char*)Ash[cur] + off);
      al[m] = *(const bf16x8*)((const char*)Asl[cur] + off);
    }
#pragma unroll
    for (int n = 0; n < 4; ++n) {
      int off = ((wc + n * 16 + lr) << 6) + lk;
      bh_[n] = *(const bf16x8*)((const char*)Bsh[cur] + off);
      bl[n] = *(const bf16x8*)((const char*)Bsl[cur] + off);
    }
#pragma unroll
    for (int m = 0; m < 4; ++m)
#pragma unroll
      for (int n = 0; n < 4; ++n) {
        acc[m][n] = __builtin_amdgcn_mfma_f32_16x16x32_bf16(al[m], bh_[n], acc[m][n], 0, 0, 0);
        acc[m][n] = __builtin_amdgcn_mfma_f32_16x16x32_bf16(ah[m], bl[n], acc[m][n], 0, 0, 0);
        acc[m][n] = __builtin_amdgcn_mfma_f32_16x16x32_bf16(ah[m], bh_[n], acc[m][n], 0, 0, 0);
      }
    if (t + 1 < nt) __syncthreads();
  }

  const int crow0 = brow + wr + ((lane >> 4) << 2);
  const int ccol0 = bcol + wc + (lane & 15);
  const long cbase = (long)bh * sC;
  if constexpr (MODE == 5) {
    const int pbase = (bcol + wc) >> 5;
#pragma unroll
    for (int m = 0; m < 4; ++m)
#pragma unroll
      for (int np = 0; np < 2; ++np)
#pragma unroll
        for (int j = 0; j < 4; ++j) {
          int r = crow0 + m * 16 + j;
          float g = acc[m][2 * np][j], u = acc[m][2 * np + 1][j];
          float h = siluf(g) * u;
          int hcol = ((pbase + np) << 4) + (lane & 15);
          u16 hh, ll; split2(h, hh, ll);
          hbh[(long)r * FF + hcol] = hh;
          hbl[(long)r * FF + hcol] = ll;
        }
  } else {
#pragma unroll
    for (int m = 0; m < 4; ++m)
#pragma unroll
      for (int n = 0; n < 4; ++n)
#pragma unroll
        for (int j = 0; j < 4; ++j) {
          long idx = cbase + (long)(crow0 + m * 16 + j) * N + (ccol0 + n * 16);
          if constexpr (MODE == 3) unsafeAtomicAdd(&C[idx], acc[m][n][j]);
          else C[idx] = acc[m][n][j];
        }
  }
}

// ---------------------------------------------------------------------------
// Indirect split GEMM (sparse MoE, compact token lists).
// MODE 1: compact-A, scatter-atomic f32 C to perm rows (ldc = DM).
// MODE 5: gather-A via perm, fused gu silu * comb -> compact hbh/hbl.
// ---------------------------------------------------------------------------
template<int MODE>
__global__ __launch_bounds__(256) void gemm3i_nt(
    const u16* __restrict__ Ah, const u16* __restrict__ Al,
    const u16* __restrict__ Bh, const u16* __restrict__ Bl,
    float* __restrict__ C, int N, int K, int lda, int ldb, int ldc,
    const int* __restrict__ perm, const int* __restrict__ cntp,
    int kspl, u16* __restrict__ hbh, u16* __restrict__ hbl,
    const float* __restrict__ comb, int eidx)
{
  const int cn = *cntp;
  const int brow = blockIdx.y << 7;
  if (brow >= cn) return;
  __shared__ u16 Ash[2][128 * 32], Asl[2][128 * 32];
  __shared__ u16 Bsh[2][128 * 32], Bsl[2][128 * 32];
  const int kc = blockIdx.z;
  const int bcol = blockIdx.x << 7;
  const int tid = threadIdx.x;
  const int wid = tid >> 6;
  const int lane = tid & 63;
  const int wr = (wid >> 1) << 6;
  const int wc = (wid & 1) << 6;

  f32x4 acc[4][4] = {};
  const int a0 = (wid << 11) + (lane << 4);

  int arow[2];
#pragma unroll
  for (int c = 0; c < 2; ++c) {
    int ab = a0 + (c << 10);
    int row = ab >> 6;
    if constexpr (MODE == 5) {
      int g = brow + row;
      arow[c] = (g < cn) ? perm[g] : perm[brow];
    } else {
      arow[c] = brow + row;
    }
  }

  auto stage = [&](int buf, int k0) {
#pragma unroll
    for (int c = 0; c < 2; ++c) {
      int ab = a0 + (c << 10);
      int row = ab >> 6;
      int kcol = (ab & 63) >> 1;
      int ld = (wid << 11) + (c << 10);
      gload16(Ah + (long)arow[c] * lda + (k0 + kcol), (char*)Ash[buf] + ld);
      gload16(Al + (long)arow[c] * lda + (k0 + kcol), (char*)Asl[buf] + ld);
      long bo = (long)(bcol + row) * ldb + (k0 + kcol);
      gload16(Bh + bo, (char*)Bsh[buf] + ld);
      gload16(Bl + bo, (char*)Bsl[buf] + ld);
    }
  };

  const int kt = K / kspl;
  const int kbeg = kc * kt;
  const int nt = kt >> 5;
  stage(0, kbeg);
  __syncthreads();
  for (int t = 0; t < nt; ++t) {
    const int cur = t & 1;
    if (t + 1 < nt) stage(cur ^ 1, kbeg + ((t + 1) << 5));
    const int lr = lane & 15;
    const int lk = (lane >> 4) << 4;
    bf16x8 ah[4], al[4], bh_[4], bl[4];
#pragma unroll
    for (int m = 0; m < 4; ++m) {
      int off = ((wr + m * 16 + lr) << 6) + lk;
      ah[m] = *(const bf16x8*)((const char*)Ash[cur] + off);
      al[m] = *(const bf16x8*)((const char*)Asl[cur] + off);
    }
#pragma unroll
    for (int n = 0; n < 4; ++n) {
      int off = ((wc + n * 16 + lr) << 6) + lk;
      bh_[n] = *(const bf16x8*)((const char*)Bsh[cur] + off);
      bl[n] = *(const bf16x8*)((const char*)Bsl[cur] + off);
    }
#pragma unroll
    for (int m = 0; m < 4; ++m)
#pragma unroll
      for (int n = 0; n < 4; ++n) {
        acc[m][n] = __builtin_amdgcn_mfma_f32_16x16x32_bf16(al[m], bh_[n], acc[m][n], 0, 0, 0);
        acc[m][n] = __builtin_amdgcn_mfma_f32_16x16x32_bf16(ah[m], bl[n], acc[m][n], 0, 0, 0);
        acc[m][n] = __builtin_amdgcn_mfma_f32_16x16x32_bf16(ah[m], bh_[n], acc[m][n], 0, 0, 0);
      }
    if (t + 1 < nt) __syncthreads();
  }

  const int crow0 = brow + wr + ((lane >> 4) << 2);
  const int ccol0 = bcol + wc + (lane & 15);
  if constexpr (MODE == 5) {
    const int pbase = (bcol + wc) >> 5;
#pragma unroll
    for (int m = 0; m < 4; ++m)
#pragma unroll
      for (int j = 0; j < 4; ++j) {
        int r = crow0 + m * 16 + j;
        if (r < cn) {
          float w = comb[perm[r] * 4 + eidx];
#pragma unroll
          for (int np = 0; np < 2; ++np) {
            float g = acc[m][2 * np][j], u = acc[m][2 * np + 1][j];
            float h = siluf(g) * u * w;
            int hcol = ((pbase + np) << 4) + (lane & 15);
            u16 hh, ll; split2(h, hh, ll);
            hbh[(long)r * FF + hcol] = hh;
            hbl[(long)r * FF + hcol] = ll;
          }
        }
      }
  } else {
#pragma unroll
    for (int m = 0; m < 4; ++m)
#pragma unroll
      for (int n = 0; n < 4; ++n)
#pragma unroll
        for (int j = 0; j < 4; ++j) {
          int r = crow0 + m * 16 + j;
          if (r < cn) {
            int col = ccol0 + n * 16;
            unsafeAtomicAdd(&C[(long)perm[r] * ldc + col], acc[m][n][j]);
          }
        }
  }
}

// ---------------------------------------------------------------------------
// Indirect plain bf16 GEMM (layer-1 experts).
// MODE 3: compact-A, scatter-atomic f32. MODE 5: gather-A, fused gu -> hb.
// ---------------------------------------------------------------------------
template<int MODE>
__global__ __launch_bounds__(256) void gemmi_nt(
    const u16* __restrict__ A, const u16* __restrict__ B, void* __restrict__ Cv,
    int N, int K, int lda, int ldb, int ldc,
    const int* __restrict__ perm, const int* __restrict__ cntp,
    int kspl, u16* __restrict__ hb, const float* __restrict__ comb, int eidx)
{
  const int cn = *cntp;
  const int brow = blockIdx.y << 7;
  if (brow >= cn) return;
  __shared__ u16 As[2][128 * 32];
  __shared__ u16 Bs[2][128 * 32];
  const int kc = blockIdx.z;
  const int bcol = blockIdx.x << 7;
  const int tid = threadIdx.x;
  const int wid = tid >> 6;
  const int lane = tid & 63;
  const int wr = (wid >> 1) << 6;
  const int wc = (wid & 1) << 6;

  f32x4 acc[4][4] = {};
  const int a0 = (wid << 11) + (lane << 4);

  int arow[2];
#pragma unroll
  for (int c = 0; c < 2; ++c) {
    int ab = a0 + (c << 10);
    int row = ab >> 6;
    if constexpr (MODE == 5) {
      int g = brow + row;
      arow[c] = (g < cn) ? perm[g] : perm[brow];
    } else {
      arow[c] = brow + row;
    }
  }

  auto stage = [&](int buf, int k0) {
#pragma unroll
    for (int c = 0; c < 2; ++c) {
      int ab = a0 + (c << 10);
      int row = ab >> 6;
      int kcol = (ab & 63) >> 1;
      int ld = (wid << 11) + (c << 10);
      gload16(A + (long)arow[c] * lda + (k0 + kcol), (char*)As[buf] + ld);
      gload16(B + (long)(bcol + row) * ldb + (k0 + kcol), (char*)Bs[buf] + ld);
    }
  };

  const int kt = K / kspl;
  const int kbeg = kc * kt;
  const int nt = kt >> 5;
  stage(0, kbeg);
  __syncthreads();
  for (int t = 0; t < nt; ++t) {
    const int cur = t & 1;
    if (t + 1 < nt) stage(cur ^ 1, kbeg + ((t + 1) << 5));
    bf16x8 af[4], bfr[4];
    const int lr = lane & 15;
    const int lk = (lane >> 4) << 4;
#pragma unroll
    for (int m = 0; m < 4; ++m)
      af[m] = *(const bf16x8*)((const char*)As[cur] + (((wr + m * 16 + lr) << 6) + lk));
#pragma unroll
    for (int n = 0; n < 4; ++n)
      bfr[n] = *(const bf16x8*)((const char*)Bs[cur] + (((wc + n * 16 + lr) << 6) + lk));
#pragma unroll
    for (int m = 0; m < 4; ++m)
#pragma unroll
      for (int n = 0; n < 4; ++n)
        acc[m][n] = __builtin_amdgcn_mfma_f32_16x16x32_bf16(af[m], bfr[n], acc[m][n], 0, 0, 0);
    if (t + 1 < nt) __syncthreads();
  }

  const int crow0 = brow + wr + ((lane >> 4) << 2);
  const int ccol0 = bcol + wc + (lane & 15);
  if constexpr (MODE == 5) {
    const int pbase = (bcol + wc) >> 5;
#pragma unroll
    for (int m = 0; m < 4; ++m)
#pragma unroll
      for (int j = 0; j < 4; ++j) {
        int r = crow0 + m * 16 + j;
        if (r < cn) {
          float w = comb[perm[r] * 4 + eidx];
#pragma unroll
          for (int np = 0; np < 2; ++np) {
            float g = acc[m][2 * np][j], u = acc[m][2 * np + 1][j];
            int hcol = ((pbase + np) << 4) + (lane & 15);
            hb[(long)r * FF + hcol] = f2bf(siluf(g) * u * w);
          }
        }
      }
  } else {
#pragma unroll
    for (int m = 0; m < 4; ++m)
#pragma unroll
      for (int n = 0; n < 4; ++n)
#pragma unroll
        for (int j = 0; j < 4; ++j) {
          int r = crow0 + m * 16 + j;
          if (r < cn) {
            int col = ccol0 + n * 16;
            unsafeAtomicAdd((float*)Cv + (long)perm[r] * ldc + col, acc[m][n][j]);
          }
        }
  }
}

// ---------------------------------------------------------------------------
// Fused flash attention (round-4 64-row variant, unchanged).
// ---------------------------------------------------------------------------
__global__ __launch_bounds__(256, 2) void fattn_k(
    const u16* __restrict__ qh, const u16* __restrict__ ql,
    const u16* __restrict__ kh, const u16* __restrict__ kl,
    const u16* __restrict__ vth, const u16* __restrict__ vtl,
    u16* __restrict__ omh, u16* __restrict__ oml, float scale)
{
  __shared__ u16 Ksh[64 * 128], Ksl[64 * 128];
  __shared__ u16 Vsh[128 * 64], Vsl[128 * 64];
  const int bh = blockIdx.x;
  const int qt = blockIdx.y;
  const int tid = threadIdx.x, wid = tid >> 6, lane = tid & 63;
  const int lr = lane & 15, lg = lane >> 4;
  const int q0 = qt * 64 + wid * 16;
  const long bhoff = (long)bh * S_LEN * HDP;
  const u16* Qh = qh + bhoff;  const u16* Ql = ql + bhoff;
  const u16* Kgh = kh + bhoff; const u16* Kgl = kl + bhoff;
  const u16* Vgh = vth + bhoff; const u16* Vgl = vtl + bhoff;

  bf16x8 qfh[4], qfl[4];
#pragma unroll
  for (int kk = 0; kk < 4; ++kk) {
    long o = (long)(q0 + lr) * HDP + kk * 32 + lg * 8;
    qfh[kk] = *(const bf16x8*)(Qh + o);
    qfl[kk] = *(const bf16x8*)(Ql + o);
  }

  f32x4 oacc[6] = {};
  float rm[4], rls[4];
#pragma unroll
  for (int j = 0; j < 4; ++j) { rm[j] = -1e30f; rls[j] = 0.f; }

  for (int t = 0; t < S_LEN / 64; ++t) {
    __syncthreads();
#pragma unroll
    for (int c = 0; c < 4; ++c) {
      int off = (tid + (c << 8)) << 4;
      {
        int lb = off ^ ((((off >> 8) & 7)) << 4);
        int row = lb >> 8, colh = (lb & 255) >> 1;
        long src = (long)(t * 64 + row) * HDP + colh;
        gload16(Kgh + src, (char*)Ksh + off);
        gload16(Kgl + src, (char*)Ksl + off);
      }
      {
        int lb = off ^ ((((off >> 7) & 7)) << 4);
        int row = lb >> 7, colh = (lb & 127) >> 1;
        long src = (long)row * S_LEN + t * 64 + colh;
        gload16(Vgh + src, (char*)Vsh + off);
        gload16(Vgl + src, (char*)Vsl + off);
      }
    }
    __syncthreads();

    f32x4 sacc[4] = {};
#pragma unroll
    for (int kk = 0; kk < 4; ++kk) {
      bf16x8 kbh[4], kbl[4];
#pragma unroll
      for (int n = 0; n < 4; ++n) {
        int byte = ((n * 16 + lr) << 8) + (kk << 6) + (lg << 4);
        byte ^= ((byte >> 8) & 7) << 4;
        kbh[n] = *(const bf16x8*)((const char*)Ksh + byte);
        kbl[n] = *(const bf16x8*)((const char*)Ksl + byte);
      }
      __builtin_amdgcn_s_setprio(1);
#pragma unroll
      for (int n = 0; n < 4; ++n) {
        sacc[n] = __builtin_amdgcn_mfma_f32_16x16x32_bf16(qfl[kk], kbh[n], sacc[n], 0, 0, 0);
        sacc[n] = __builtin_amdgcn_mfma_f32_16x16x32_bf16(qfh[kk], kbl[n], sacc[n], 0, 0, 0);
        sacc[n] = __builtin_amdgcn_mfma_f32_16x16x32_bf16(qfh[kk], kbh[n], sacc[n], 0, 0, 0);
      }
      __builtin_amdgcn_s_setprio(0);
    }
    __syncthreads();

#pragma unroll
    for (int j = 0; j < 4; ++j) {
      float mx = fmaxf(fmaxf(sacc[0][j], sacc[1][j]),
                       fmaxf(sacc[2][j], sacc[3][j])) * scale;
      mx = fmaxf(mx, __shfl_xor(mx, 1));
      mx = fmaxf(mx, __shfl_xor(mx, 2));
      mx = fmaxf(mx, __shfl_xor(mx, 4));
      mx = fmaxf(mx, __shfl_xor(mx, 8));
      float mnew = fmaxf(rm[j], mx);
      float corr = __expf(rm[j] - mnew);
      rm[j] = mnew;
      float ps = 0.f;
#pragma unroll
      for (int n = 0; n < 4; ++n) {
        float p = __expf(sacc[n][j] * scale - mnew);
        sacc[n][j] = p; ps += p;
      }
      ps += __shfl_xor(ps, 1); ps += __shfl_xor(ps, 2);
      ps += __shfl_xor(ps, 4); ps += __shfl_xor(ps, 8);
      rls[j] = rls[j] * corr + ps;
#pragma unroll
      for (int n2 = 0; n2 < 6; ++n2) oacc[n2][j] *= corr;
    }

    char* Pwh = (char*)Ksh + (wid << 11);
    char* Pwl = (char*)Ksl + (wid << 11);
#pragma unroll
    for (int n = 0; n < 4; ++n)
#pragma unroll
      for (int j = 0; j < 4; ++j) {
        int row = lg * 4 + j;
        int byte = (row << 7) + ((n * 16 + lr) << 1);
        byte ^= ((byte >> 7) & 7) << 4;
        u16 h, l; split2(sacc[n][j], h, l);
        *(u16*)(Pwh + byte) = h;
        *(u16*)(Pwl + byte) = l;
      }
    bf16x8 pah[2], pal[2];
#pragma unroll
    for (int kk = 0; kk < 2; ++kk) {
      int byte = (lr << 7) + (kk << 6) + (lg << 4);
      byte ^= ((byte >> 7) & 7) << 4;
      pah[kk] = *(const bf16x8*)(Pwh + byte);
      pal[kk] = *(const bf16x8*)(Pwl + byte);
    }

#pragma unroll
    for (int kk = 0; kk < 2; ++kk) {
      bf16x8 vbh[6], vbl[6];
#pragma unroll
      for (int n2 = 0; n2 < 6; ++n2) {
        int byte = ((n2 * 16 + lr) << 7) + (kk << 6) + (lg << 4);
        byte ^= ((byte >> 7) & 7) << 4;
        vbh[n2] = *(const bf16x8*)((const char*)Vsh + byte);
        vbl[n2] = *(const bf16x8*)((const char*)Vsl + byte);
      }
      __builtin_amdgcn_s_setprio(1);
#pragma unroll
      for (int n2 = 0; n2 < 6; ++n2) {
        oacc[n2] = __builtin_amdgcn_mfma_f32_16x16x32_bf16(pal[kk], vbh[n2], oacc[n2], 0, 0, 0);
        oacc[n2] = __builtin_amdgcn_mfma_f32_16x16x32_bf16(pah[kk], vbl[n2], oacc[n2], 0, 0, 0);
        oacc[n2] = __builtin_amdgcn_mfma_f32_16x16x32_bf16(pah[kk], vbh[n2], oacc[n2], 0, 0, 0);
      }
      __builtin_amdgcn_s_setprio(0);
    }
  }

  const int b = bh >> 3, h = bh & 7;
#pragma unroll
  for (int j = 0; j < 4; ++j) {
    float inv = 1.0f / rls[j];
    int q = q0 + lg * 4 + j;
    long base = ((long)(b * S_LEN + q)) * DM + h * HDIM;
#pragma unroll
    for (int n2 = 0; n2 < 6; ++n2) {
      int d = n2 * 16 + lr;
      u16 hh, ll; split2(oacc[n2][j] * inv, hh, ll);
      omh[base + d] = hh; oml[base + d] = ll;
    }
  }
}

// ---------------------------------------------------------------------------
// fp32 [R][C] -> bf16 hi/lo [C][R] transpose+split. ilv<0: linear rows.
// ilv in {0,1}: gate/up 16-row interleave: orow = (f>>4)*32 + ilv*16 + (f&15).
// ---------------------------------------------------------------------------
__global__ void wconv_t(const float* __restrict__ in, u16* __restrict__ outh,
                        u16* __restrict__ outl, int R, int C, int ilv) {
  __shared__ float tile[32][33];
  int c0 = blockIdx.x << 5, r0 = blockIdx.y << 5;
  int tx = threadIdx.x;
  for (int rr = threadIdx.y; rr < 32; rr += 8)
    tile[rr][tx] = in[(long)(r0 + rr) * C + (c0 + tx)];
  __syncthreads();
  for (int rr = threadIdx.y; rr < 32; rr += 8) {
    u16 h, l; split2(tile[tx][rr], h, l);
    int f = c0 + rr;
    long orow = (ilv < 0) ? f : (((f >> 4) << 5) + (ilv << 4) + (f & 15));
    long o = orow * R + (r0 + tx);
    outh[o] = h; outl[o] = l;
  }
}

__global__ __launch_bounds__(256) void ln_k(const float* __restrict__ in,
    const float* __restrict__ g, const float* __restrict__ b,
    float* __restrict__ outf, u16* __restrict__ outh, u16* __restrict__ outl) {
  int row = blockIdx.x;
  const float* x = in + (long)row * DM;
  int tid = threadIdx.x;
  float v[3], s = 0.f, ss = 0.f;
#pragma unroll
  for (int i = 0; i < 3; ++i) { v[i] = x[tid + (i << 8)]; s += v[i]; ss += v[i] * v[i]; }
  __shared__ float red[2][4];
  for (int o = 32; o; o >>= 1) { s += __shfl_down(s, o); ss += __shfl_down(ss, o); }
  int wid = tid >> 6, lane = tid & 63;
  if (!lane) { red[0][wid] = s; red[1][wid] = ss; }
  __syncthreads();
  s = red[0][0] + red[0][1] + red[0][2] + red[0][3];
  ss = red[1][0] + red[1][1] + red[1][2] + red[1][3];
  float mean = s * (1.f / DM);
  float var = ss * (1.f / DM) - mean * mean;
  float rs = rsqrtf(var + 1e-5f);
#pragma unroll
  for (int i = 0; i < 3; ++i) {
    int c = tid + (i << 8);
    float y = (v[i] - mean) * rs * g[c] + b[c];
    if (outf) outf[(long)row * DM + c] = y;
    if (outh) { u16 h, l; split2(y, h, l); outh[(long)row * DM + c] = h; outl[(long)row * DM + c] = l; }
  }
}

__global__ void rope_tables_k(float* __restrict__ cosT, float* __restrict__ sinT) {
  int s = blockIdx.x, d = threadIdx.x;
  int xc = s & 15, y = (s >> 4) & 15, t = s >> 8;
  int axis = d / 32, fi = d & 15;
  int coord = axis == 0 ? xc : (axis == 1 ? y : t);
  float inv = powf(10000.0f, -(float)fi / 16.0f);
  float ang = (float)coord * inv;
  cosT[s * HDIM + d] = cosf(ang);
  sinT[s * HDIM + d] = sinf(ang);
}

__global__ __launch_bounds__(256) void rope_apply_k(const float* __restrict__ qkv,
    const float* __restrict__ cosT, const float* __restrict__ sinT,
    u16* __restrict__ qh, u16* __restrict__ ql,
    u16* __restrict__ kh, u16* __restrict__ kl) {
  int bs = blockIdx.x;
  int b = bs >> 11, s = bs & 2047;
  const float* base = qkv + ((long)(b * S_LEN + s) * 3) * DM;
  for (int idx = threadIdx.x; idx < DM; idx += 256) {
    int h = idx / HDIM, d = idx - h * HDIM;
    float c = cosT[s * HDIM + d], sn = sinT[s * HDIM + d];
    int pair = (d < 48) ? idx + 48 : idx - 48;
    float qv = base[idx], kv = base[DM + idx];
    float qr = (d < 48) ? -base[pair] : base[pair];
    float kr = (d < 48) ? -base[DM + pair] : base[DM + pair];
    long o = ((long)(b * NHEAD + h) * S_LEN + s) * HDP + d;
    u16 hh, ll;
    split2(qv * c + qr * sn, hh, ll); qh[o] = hh; ql[o] = ll;
    split2(kv * c + kr * sn, hh, ll); kh[o] = hh; kl[o] = ll;
  }
  int t = threadIdx.x;
  int h = t >> 5, d = HDIM + (t & 31);
  long o = ((long)(b * NHEAD + h) * S_LEN + s) * HDP + d;
  qh[o] = 0; ql[o] = 0; kh[o] = 0; kl[o] = 0;
}

__global__ void v_transpose_k(const float* __restrict__ qkv,
                              u16* __restrict__ vh, u16* __restrict__ vl) {
  __shared__ float tile[32][33];
  int bh = blockIdx.z, b = bh >> 3, h = bh & 7;
  int s0 = blockIdx.x << 5, d0 = blockIdx.y << 5;
  int tx = threadIdx.x;
  for (int r = threadIdx.y; r < 32; r += 8) {
    int s = s0 + r, d = d0 + tx;
    float v = 0.f;
    if (d < HDIM) v = qkv[((long)(b * S_LEN + s) * 3 + 2) * DM + h * HDIM + d];
    tile[r][tx] = v;
  }
  __syncthreads();
  for (int r = threadIdx.y; r < 32; r += 8) {
    int d = d0 + r;
    u16 hh, ll; split2(tile[tx][r], hh, ll);
    long o = ((long)bh * HDP + d) * S_LEN + (s0 + tx);
    vh[o] = hh; vl[o] = ll;
  }
}

// Router: comb[tok][e] + top-2 bitmask per token.
__global__ __launch_bounds__(256) void router_k(const float* __restrict__ x,
    const float* __restrict__ gw, float* __restrict__ comb, int* __restrict__ mask) {
  int tok = blockIdx.x * 4 + (threadIdx.x >> 6);
  int lane = threadIdx.x & 63;
  const float* xr = x + (long)tok * DM;
  float a0 = 0, a1 = 0, a2 = 0, a3 = 0;
  for (int i = lane; i < DM; i += 64) {
    float xv = xr[i];
    const float* g = gw + i * 4;
    a0 += xv * g[0]; a1 += xv * g[1]; a2 += xv * g[2]; a3 += xv * g[3];
  }
  for (int o = 32; o; o >>= 1) {
    a0 += __shfl_down(a0, o); a1 += __shfl_down(a1, o);
    a2 += __shfl_down(a2, o); a3 += __shfl_down(a3, o);
  }
  if (lane == 0) {
    float p[4] = {a0, a1, a2, a3};
    float mx = fmaxf(fmaxf(p[0], p[1]), fmaxf(p[2], p[3]));
    float s = 0.f;
    for (int e = 0; e < 4; ++e) { p[e] = expf(p[e] - mx); s += p[e]; }
    for (int e = 0; e < 4; ++e) p[e] /= s;
    int i1 = 0;
    for (int e = 1; e < 4; ++e) if (p[e] > p[i1]) i1 = e;
    int i2 = -1;
    for (int e = 0; e < 4; ++e) if (e != i1 && (i2 < 0 || p[e] > p[i2])) i2 = e;
    float ssum = p[i1] + p[i2] + 1e-5f;
    float out[4] = {0, 0, 0, 0};
    out[i1] = p[i1] / ssum; out[i2] = p[i2] / ssum;
    for (int e = 0; e < 4; ++e) comb[tok * 4 + e] = out[e];
    mask[tok] = (1 << i1) | (1 << i2);
  }
}

// Deterministic per-expert compaction; one block per expert (grid = NEXP).
__global__ void scan_k(const int* __restrict__ mask, int* __restrict__ perm,
                       int* __restrict__ cnt) {
  __shared__ int sd[256];
  __shared__ int base;
  int tid = threadIdx.x;
  int e = blockIdx.x;
  if (tid == 0) base = 0;
  __syncthreads();
  for (int c = 0; c < NTOK / 256; ++c) {
    int tok = c * 256 + tid;
    int f = (mask[tok] >> e) & 1;
    sd[tid] = f;
    __syncthreads();
    for (int s = 1; s < 256; s <<= 1) {
      int v = (tid >= s) ? sd[tid - s] : 0;
      __syncthreads();
      sd[tid] += v;
      __syncthreads();
    }
    if (f) perm[e * NTOK + base + sd[tid] - 1] = tok;
    int tot = sd[255];
    __syncthreads();
    if (tid == 0) base += tot;
    __syncthreads();
  }
  if (tid == 0) cnt[e] = base;
}

__global__ void f2b_k(const float* __restrict__ src, u16* __restrict__ dst, long n) {
  long i = (long)blockIdx.x * 256 + threadIdx.x;
  if (i < n) dst[i] = f2bf(src[i]);
}

__global__ void f2bsplit_k(const float* __restrict__ src, u16* __restrict__ dh,
                           u16* __restrict__ dl, long n) {
  long i = (long)blockIdx.x * 256 + threadIdx.x;
  if (i < n) { u16 h, l; split2(src[i], h, l); dh[i] = h; dl[i] = l; }
}

extern "C" void kernel_launch(void* const* d_in, const int* in_sizes, int n_in,
                              void* d_out, int out_size, void* d_ws, size_t ws_size,
                              hipStream_t stream) {
  (void)in_sizes; (void)n_in; (void)out_size; (void)ws_size;
  const float* x_in  = (const float*)d_in[0];
  const float* ln1_g = (const float*)d_in[4];
  const float* ln1_b = (const float*)d_in[5];
  const float* w_qkv = (const float*)d_in[6];
  const float* w_out = (const float*)d_in[7];
  const float* gatew = (const float*)d_in[8];
  const float* eg    = (const float*)d_in[9];
  const float* eu    = (const float*)d_in[10];
  const float* ed    = (const float*)d_in[11];
  const float* sg    = (const float*)d_in[12];
  const float* su    = (const float*)d_in[13];
  const float* sd    = (const float*)d_in[14];
  const float* ln2_g = (const float*)d_in[15];
  const float* ln2_b = (const float*)d_in[16];

  float* xc = (float*)d_out;
  char* W = (char*)d_ws;
  size_t off = 0;
  auto alloc = [&](size_t bytes) {
    size_t o = off; off = (off + bytes + 255) & ~(size_t)255; return o;
  };
  size_t o_cos  = alloc((size_t)S_LEN * HDIM * 4);
  size_t o_sin  = alloc((size_t)S_LEN * HDIM * 4);
  size_t o_xnh  = alloc((size_t)NTOK * DM * 2);
  size_t o_xnl  = alloc((size_t)NTOK * DM * 2);
  size_t o_qkv  = alloc((size_t)NTOK * 3 * DM * 4);
  size_t o_qph  = alloc((size_t)NBH * S_LEN * HDP * 2);
  size_t o_qpl  = alloc((size_t)NBH * S_LEN * HDP * 2);
  size_t o_kph  = alloc((size_t)NBH * S_LEN * HDP * 2);
  size_t o_kpl  = alloc((size_t)NBH * S_LEN * HDP * 2);
  size_t o_vth  = alloc((size_t)NBH * HDP * S_LEN * 2);
  size_t o_vtl  = alloc((size_t)NBH * HDP * S_LEN * 2);
  size_t o_omh  = alloc((size_t)NTOK * DM * 2);
  size_t o_oml  = alloc((size_t)NTOK * DM * 2);
  size_t o_comb = alloc((size_t)NTOK * 4 * 4);
  size_t o_mask = alloc((size_t)NTOK * 4);
  size_t o_perm = alloc((size_t)NEXP * NTOK * 4);
  size_t o_cnt  = alloc(256);
  size_t o_wqh  = alloc((size_t)3 * DM * DM * 2);
  size_t o_wql  = alloc((size_t)3 * DM * DM * 2);
  size_t o_woh  = alloc((size_t)DM * DM * 2);
  size_t o_wol  = alloc((size_t)DM * DM * 2);
  size_t o_sguh = alloc((size_t)FF2 * DM * 2);
  size_t o_sgul = alloc((size_t)FF2 * DM * 2);
  size_t o_sdh  = alloc((size_t)DM * FF * 2);
  size_t o_sdl  = alloc((size_t)DM * FF * 2);
  size_t o_eguh = alloc((size_t)FF2 * DM * 2);
  size_t o_egul = alloc((size_t)FF2 * DM * 2);
  size_t o_edh  = alloc((size_t)DM * FF * 2);
  size_t o_edl  = alloc((size_t)DM * FF * 2);
  size_t o_hbh  = alloc((size_t)NTOK * FF * 2);
  size_t o_hbl  = alloc((size_t)NTOK * FF * 2);

  float* cosT = (float*)(W + o_cos);
  float* sinT = (float*)(W + o_sin);
  u16*   xnh  = (u16*)(W + o_xnh);
  u16*   xnl  = (u16*)(W + o_xnl);
  float* qkv  = (float*)(W + o_qkv);
  u16 *qph = (u16*)(W + o_qph), *qpl = (u16*)(W + o_qpl);
  u16 *kph = (u16*)(W + o_kph), *kpl = (u16*)(W + o_kpl);
  u16 *vth = (u16*)(W + o_vth), *vtl = (u16*)(W + o_vtl);
  u16 *omh = (u16*)(W + o_omh), *oml = (u16*)(W + o_oml);
  float* comb = (float*)(W + o_comb);
  int* maskb  = (int*)(W + o_mask);
  int* permb  = (int*)(W + o_perm);
  int* cntb   = (int*)(W + o_cnt);
  u16 *wqh = (u16*)(W + o_wqh), *wql = (u16*)(W + o_wql);
  u16 *woh = (u16*)(W + o_woh), *wol = (u16*)(W + o_wol);
  u16 *sguh = (u16*)(W + o_sguh), *sgul = (u16*)(W + o_sgul);
  u16 *sdh = (u16*)(W + o_sdh), *sdl = (u16*)(W + o_sdl);
  u16 *eguh = (u16*)(W + o_eguh), *egul = (u16*)(W + o_egul);
  u16 *edh = (u16*)(W + o_edh), *edl = (u16*)(W + o_edl);
  u16 *hbh = (u16*)(W + o_hbh), *hbl = (u16*)(W + o_hbl);

  const long ND = (long)NTOK * DM;
  const int gND = (int)((ND + 255) / 256);

  hipMemcpyAsync(xc, x_in, (size_t)ND * 4, hipMemcpyDeviceToDevice, stream);
  rope_tables_k<<<S_LEN, HDIM, 0, stream>>>(cosT, sinT);

  dim3 tb(32, 8, 1);
  for (int l = 0; l < 2; ++l) {
    const float* wqkv_l = w_qkv + (size_t)l * DM * 3 * DM;
    const float* wout_l = w_out + (size_t)l * DM * DM;
    const float* gw_l   = gatew + (size_t)l * DM * 4;
    const float* eg_l = eg + (size_t)l * NEXP * DM * FF;
    const float* eu_l = eu + (size_t)l * NEXP * DM * FF;
    const float* ed_l = ed + (size_t)l * NEXP * FF * DM;
    const float* sg_l = sg + (size_t)l * DM * FF;
    const float* su_l = su + (size_t)l * DM * FF;
    const float* sd_l = sd + (size_t)l * FF * DM;

    wconv_t<<<dim3(3 * DM / 32, DM / 32), tb, 0, stream>>>(wqkv_l, wqh, wql, DM, 3 * DM, -1);
    wconv_t<<<dim3(DM / 32, DM / 32), tb, 0, stream>>>(wout_l, woh, wol, DM, DM, -1);
    wconv_t<<<dim3(FF / 32, DM / 32), tb, 0, stream>>>(sg_l, sguh, sgul, DM, FF, 0);
    wconv_t<<<dim3(FF / 32, DM / 32), tb, 0, stream>>>(su_l, sguh, sgul, DM, FF, 1);
    wconv_t<<<dim3(DM / 32, FF / 32), tb, 0, stream>>>(sd_l, sdh, sdl, FF, DM, -1);

    // --- attention (fp32-equivalent via bf16x3 + flash) ---
    ln_k<<<NTOK, 256, 0, stream>>>(xc, ln1_g + l * DM, ln1_b + l * DM, nullptr, xnh, xnl);
    gemm3_nt<0><<<dim3(3 * DM >> 7, NTOK >> 7, 1), 256, 0, stream>>>(
        xnh, xnl, wqh, wql, qkv, NTOK, 3 * DM, DM, DM, DM, 0, 0, 0, 1, nullptr, nullptr);
    rope_apply_k<<<NTOK, 256, 0, stream>>>(qkv, cosT, sinT, qph, qpl, kph, kpl);
    v_transpose_k<<<dim3(S_LEN / 32, HDP / 32, NBH), tb, 0, stream>>>(qkv, vth, vtl);
    fattn_k<<<dim3(NBH, S_LEN / 64), dim3(256), 0, stream>>>(
        qph, qpl, kph, kpl, vth, vtl, omh, oml, 0.10206207261596575f);
    // out-proj: atomic accumulate directly into residual xc (split-K x2)
    gemm3_nt<3><<<dim3(DM >> 7, NTOK >> 7, 2), 256, 0, stream>>>(
        omh, oml, woh, wol, xc, NTOK, DM, DM, DM, DM, 0, 0, 0, 2, nullptr, nullptr);

    // --- router + deterministic expert compaction ---
    router_k<<<NTOK / 4, 256, 0, stream>>>(xc, gw_l, comb, maskb);
    scan_k<<<NEXP, 256, 0, stream>>>(maskb, permb, cntb);

    if (l == 0) {
      f2bsplit_k<<<gND, 256, 0, stream>>>(xc, xnh, xnl, ND);
      // shared expert: fused gu+silu, down atomic into xc
      gemm3_nt<5><<<dim3(FF2 >> 7, NTOK >> 7, 1), 256, 0, stream>>>(
          xnh, xnl, sguh, sgul, nullptr, NTOK, FF2, DM, DM, DM, 0, 0, 0, 1, hbh, hbl);
      gemm3_nt<3><<<dim3(DM >> 7, NTOK >> 7, 4), 256, 0, stream>>>(
          hbh, hbl, sdh, sdl, xc, NTOK, DM, FF, FF, FF, 0, 0, 0, 4, nullptr, nullptr);
      // routed experts: gather gu+silu*comb, scatter-atomic down into xc
      for (int e = 0; e < NEXP; ++e) {
        wconv_t<<<dim3(FF / 32, DM / 32), tb, 0, stream>>>(eg_l + (size_t)e * DM * FF, eguh, egul, DM, FF, 0);
        wconv_t<<<dim3(FF / 32, DM / 32), tb, 0, stream>>>(eu_l + (size_t)e * DM * FF, eguh, egul, DM, FF, 1);
        wconv_t<<<dim3(DM / 32, FF / 32), tb, 0, stream>>>(ed_l + (size_t)e * FF * DM, edh, edl, FF, DM, -1);
        const int* pe = permb + e * NTOK;
        const int* ce = cntb + e;
        gemm3i_nt<5><<<dim3(FF2 >> 7, NTOK >> 7, 1), 256, 0, stream>>>(
            xnh, xnl, eguh, egul, nullptr, FF2, DM, DM, DM, FF2, pe, ce, 1, hbh, hbl, comb, e);
        gemm3i_nt<1><<<dim3(DM >> 7, NTOK >> 7, 4), 256, 0, stream>>>(
            hbh, hbl, edh, edl, xc, DM, FF, FF, FF, DM, pe, ce, 4, nullptr, nullptr, nullptr, e);
      }
    } else {
      f2b_k<<<gND, 256, 0, stream>>>(xc, xnh, ND);
      gemm_nt<5><<<dim3(FF2 >> 7, NTOK >> 7, 1), 256, 0, stream>>>(
          xnh, sguh, nullptr, NTOK, FF2, DM, DM, DM, 0, 0, 0, 1, hbh);
      gemm_nt<3><<<dim3(DM >> 7, NTOK >> 7, 4), 256, 0, stream>>>(
          hbh, sdh, xc, NTOK, DM, FF, FF, FF, 0, 0, 0, 4, nullptr);
      for (int e = 0; e < NEXP; ++e) {
        wconv_t<<<dim3(FF / 32, DM / 32), tb, 0, stream>>>(eg_l + (size_t)e * DM * FF, eguh, egul, DM, FF, 0);
        wconv_t<<<dim3(FF / 32, DM / 32), tb, 0, stream>>>(eu_l + (size_t)e * DM * FF, eguh, egul, DM, FF, 1);
        wconv_t<<<dim3(DM / 32, FF / 32), tb, 0, stream>>>(ed_l + (size_t)e * FF * DM, edh, edl, FF, DM, -1);
        const int* pe = permb + e * NTOK;
        const int* ce = cntb + e;
        gemmi_nt<5><<<dim3(FF2 >> 7, NTOK >> 7, 1), 256, 0, stream>>>(
            xnh, eguh, nullptr, FF2, DM, DM, DM, FF2, pe, ce, 1, hbh, comb, e);
        gemmi_nt<3><<<dim3(DM >> 7, NTOK >> 7, 4), 256, 0, stream>>>(
            hbh, edh, xc, DM, FF, FF, FF, DM, pe, ce, 4, nullptr, nullptr, e);
      }
    }
    ln_k<<<NTOK, 256, 0, stream>>>(xc, ln2_g + l * DM, ln2_b + l * DM, xc, nullptr, nullptr);
  }
}

// Round 9
// 1860.204 us; speedup vs baseline: 2.9774x; 1.1503x over previous
//
#include <hip/hip_runtime.h>
#include <stdint.h>

#define S_LEN 2048
#define DM    768
#define NHEAD 8
#define HDIM  96
#define HDP   128
#define FF    3072
#define FF2   6144
#define NEXP  4
#define NTOK  4096
#define NBH   16
#define HBROWS (2 * NTOK)

typedef unsigned short u16;
typedef short bf16x8 __attribute__((ext_vector_type(8)));
typedef float f32x4 __attribute__((ext_vector_type(4)));
typedef __attribute__((address_space(1))) void* gptr_t;
typedef __attribute__((address_space(3))) void* lptr_t;

__device__ __forceinline__ u16 f2bf(float f) {
  union { float f; uint32_t u; } v; v.f = f;
  uint32_t r = v.u + 0x7FFFu + ((v.u >> 16) & 1u);
  return (u16)(r >> 16);
}
__device__ __forceinline__ float bf2f(u16 h) {
  union { uint32_t u; float f; } v; v.u = ((uint32_t)h) << 16;
  return v.f;
}
__device__ __forceinline__ void split2(float f, u16& hi, u16& lo) {
  u16 h = f2bf(f);
  lo = f2bf(f - bf2f(h));
  hi = h;
}
__device__ __forceinline__ float siluf(float g) {
  return g / (1.0f + expf(-g));
}
__device__ __forceinline__ void gload16(const void* g, void* l) {
  __builtin_amdgcn_global_load_lds((gptr_t)(void*)g, (lptr_t)l, 16, 0, 0);
}

// ---------------------------------------------------------------------------
// Plain NT GEMM, 2-phase double-buffered. C[M,N] = A[M,K] @ B[N,K]^T.
// MODE: 0 f32, 2 bf16, 3 atomic f32, 5 fused gate/up silu -> hb bf16.
// ---------------------------------------------------------------------------
template<int MODE>
__global__ __launch_bounds__(256) void gemm_nt(
    const u16* __restrict__ A, const u16* __restrict__ B, void* __restrict__ Cv,
    int M, int N, int K, int lda, int ldb, long sA, long sB, long sC, int kspl,
    u16* __restrict__ hb)
{
  __shared__ u16 As[2][128 * 32];
  __shared__ u16 Bs[2][128 * 32];
  const int z = blockIdx.z;
  const int bh = z / kspl;
  const int kc = z - bh * kspl;
  const u16* Az = A + (long)bh * sA;
  const u16* Bz = B + (long)bh * sB;
  const int brow = blockIdx.y << 7;
  const int bcol = blockIdx.x << 7;
  const int tid = threadIdx.x;
  const int wid = tid >> 6;
  const int lane = tid & 63;
  const int wr = (wid >> 1) << 6;
  const int wc = (wid & 1) << 6;

  f32x4 acc[4][4] = {};
  const int a0 = (wid << 11) + (lane << 4);

  auto stage = [&](int buf, int k0) {
#pragma unroll
    for (int c = 0; c < 2; ++c) {
      int ab = a0 + (c << 10);
      int row = ab >> 6;
      int kcol = (ab & 63) >> 1;
      int ld = (wid << 11) + (c << 10);
      gload16(Az + (long)(brow + row) * lda + (k0 + kcol), (char*)As[buf] + ld);
      gload16(Bz + (long)(bcol + row) * ldb + (k0 + kcol), (char*)Bs[buf] + ld);
    }
  };

  const int kt = K / kspl;
  const int kbeg = kc * kt;
  const int nt = kt >> 5;
  stage(0, kbeg);
  __syncthreads();
  for (int t = 0; t < nt; ++t) {
    const int cur = t & 1;
    if (t + 1 < nt) stage(cur ^ 1, kbeg + ((t + 1) << 5));
    bf16x8 af[4], bfr[4];
    const int lr = lane & 15;
    const int lk = (lane >> 4) << 4;
#pragma unroll
    for (int m = 0; m < 4; ++m)
      af[m] = *(const bf16x8*)((const char*)As[cur] + (((wr + m * 16 + lr) << 6) + lk));
#pragma unroll
    for (int n = 0; n < 4; ++n)
      bfr[n] = *(const bf16x8*)((const char*)Bs[cur] + (((wc + n * 16 + lr) << 6) + lk));
#pragma unroll
    for (int m = 0; m < 4; ++m)
#pragma unroll
      for (int n = 0; n < 4; ++n)
        acc[m][n] = __builtin_amdgcn_mfma_f32_16x16x32_bf16(af[m], bfr[n], acc[m][n], 0, 0, 0);
    if (t + 1 < nt) __syncthreads();
  }

  const int crow0 = brow + wr + ((lane >> 4) << 2);
  const int ccol0 = bcol + wc + (lane & 15);
  const long cbase = (long)bh * sC;
  if constexpr (MODE == 5) {
    const int pbase = (bcol + wc) >> 5;
#pragma unroll
    for (int m = 0; m < 4; ++m)
#pragma unroll
      for (int np = 0; np < 2; ++np)
#pragma unroll
        for (int j = 0; j < 4; ++j) {
          int r = crow0 + m * 16 + j;
          float g = acc[m][2 * np][j], u = acc[m][2 * np + 1][j];
          int hcol = ((pbase + np) << 4) + (lane & 15);
          hb[(long)r * FF + hcol] = f2bf(siluf(g) * u);
        }
  } else {
#pragma unroll
    for (int m = 0; m < 4; ++m)
#pragma unroll
      for (int n = 0; n < 4; ++n)
#pragma unroll
        for (int j = 0; j < 4; ++j) {
          long idx = cbase + (long)(crow0 + m * 16 + j) * N + (ccol0 + n * 16);
          float v = acc[m][n][j];
          if constexpr (MODE == 2) ((u16*)Cv)[idx] = f2bf(v);
          else if constexpr (MODE == 3) unsafeAtomicAdd((float*)Cv + idx, v);
          else ((float*)Cv)[idx] = v;
        }
  }
}

// ---------------------------------------------------------------------------
// Split (bf16x3) NT GEMM, dense. MODE: 0 f32, 3 atomic f32, 5 fused gu silu.
// ---------------------------------------------------------------------------
template<int MODE>
__global__ __launch_bounds__(256) void gemm3_nt(
    const u16* __restrict__ Ah, const u16* __restrict__ Al,
    const u16* __restrict__ Bh, const u16* __restrict__ Bl,
    float* __restrict__ C,
    int M, int N, int K, int lda, int ldb, long sA, long sB, long sC, int kspl,
    u16* __restrict__ hbh, u16* __restrict__ hbl)
{
  __shared__ u16 Ash[2][128 * 32], Asl[2][128 * 32];
  __shared__ u16 Bsh[2][128 * 32], Bsl[2][128 * 32];
  const int z = blockIdx.z;
  const int bh = z / kspl;
  const int kc = z - bh * kspl;
  const u16* Azh = Ah + (long)bh * sA;
  const u16* Azl = Al + (long)bh * sA;
  const u16* Bzh = Bh + (long)bh * sB;
  const u16* Bzl = Bl + (long)bh * sB;
  const int brow = blockIdx.y << 7;
  const int bcol = blockIdx.x << 7;
  const int tid = threadIdx.x;
  const int wid = tid >> 6;
  const int lane = tid & 63;
  const int wr = (wid >> 1) << 6;
  const int wc = (wid & 1) << 6;

  f32x4 acc[4][4] = {};
  const int a0 = (wid << 11) + (lane << 4);

  auto stage = [&](int buf, int k0) {
#pragma unroll
    for (int c = 0; c < 2; ++c) {
      int ab = a0 + (c << 10);
      int row = ab >> 6;
      int kcol = (ab & 63) >> 1;
      long ao = (long)(brow + row) * lda + (k0 + kcol);
      long bo = (long)(bcol + row) * ldb + (k0 + kcol);
      int ld = (wid << 11) + (c << 10);
      gload16(Azh + ao, (char*)Ash[buf] + ld);
      gload16(Azl + ao, (char*)Asl[buf] + ld);
      gload16(Bzh + bo, (char*)Bsh[buf] + ld);
      gload16(Bzl + bo, (char*)Bsl[buf] + ld);
    }
  };

  const int kt = K / kspl;
  const int kbeg = kc * kt;
  const int nt = kt >> 5;
  stage(0, kbeg);
  __syncthreads();
  for (int t = 0; t < nt; ++t) {
    const int cur = t & 1;
    if (t + 1 < nt) stage(cur ^ 1, kbeg + ((t + 1) << 5));
    const int lr = lane & 15;
    const int lk = (lane >> 4) << 4;
    bf16x8 ah[4], al[4], bh_[4], bl[4];
#pragma unroll
    for (int m = 0; m < 4; ++m) {
      int off = ((wr + m * 16 + lr) << 6) + lk;
      ah[m] = *(const bf16x8*)((const char*)Ash[cur] + off);
      al[m] = *(const bf16x8*)((const char*)Asl[cur] + off);
    }
#pragma unroll
    for (int n = 0; n < 4; ++n) {
      int off = ((wc + n * 16 + lr) << 6) + lk;
      bh_[n] = *(const bf16x8*)((const char*)Bsh[cur] + off);
      bl[n] = *(const bf16x8*)((const char*)Bsl[cur] + off);
    }
#pragma unroll
    for (int m = 0; m < 4; ++m)
#pragma unroll
      for (int n = 0; n < 4; ++n) {
        acc[m][n] = __builtin_amdgcn_mfma_f32_16x16x32_bf16(al[m], bh_[n], acc[m][n], 0, 0, 0);
        acc[m][n] = __builtin_amdgcn_mfma_f32_16x16x32_bf16(ah[m], bl[n], acc[m][n], 0, 0, 0);
        acc[m][n] = __builtin_amdgcn_mfma_f32_16x16x32_bf16(ah[m], bh_[n], acc[m][n], 0, 0, 0);
      }
    if (t + 1 < nt) __syncthreads();
  }

  const int crow0 = brow + wr + ((lane >> 4) << 2);
  const int ccol0 = bcol + wc + (lane & 15);
  const long cbase = (long)bh * sC;
  if constexpr (MODE == 5) {
    const int pbase = (bcol + wc) >> 5;
#pragma unroll
    for (int m = 0; m < 4; ++m)
#pragma unroll
      for (int np = 0; np < 2; ++np)
#pragma unroll
        for (int j = 0; j < 4; ++j) {
          int r = crow0 + m * 16 + j;
          float g = acc[m][2 * np][j], u = acc[m][2 * np + 1][j];
          float h = siluf(g) * u;
          int hcol = ((pbase + np) << 4) + (lane & 15);
          u16 hh, ll; split2(h, hh, ll);
          hbh[(long)r * FF + hcol] = hh;
          hbl[(long)r * FF + hcol] = ll;
        }
  } else {
#pragma unroll
    for (int m = 0; m < 4; ++m)
#pragma unroll
      for (int n = 0; n < 4; ++n)
#pragma unroll
        for (int j = 0; j < 4; ++j) {
          long idx = cbase + (long)(crow0 + m * 16 + j) * N + (ccol0 + n * 16);
          if constexpr (MODE == 3) unsafeAtomicAdd(&C[idx], acc[m][n][j]);
          else C[idx] = acc[m][n][j];
        }
  }
}

// ---------------------------------------------------------------------------
// Batched indirect split GEMM over experts (blockIdx.z = e*kspl+kc).
// MODE 5: gather-A via perm[e], fused gu silu * comb -> hb rows cbase[e]+r.
// MODE 1: compact-A rows cbase[e]+r (clamped to cn-1), scatter-atomic f32.
// ---------------------------------------------------------------------------
template<int MODE>
__global__ __launch_bounds__(256) void gemm3i_nt(
    const u16* __restrict__ Ah, const u16* __restrict__ Al,
    const u16* __restrict__ Bh, const u16* __restrict__ Bl,
    float* __restrict__ C, int N, int K, int lda, int ldb, int ldc,
    const int* __restrict__ perm, const int* __restrict__ cnt,
    const int* __restrict__ cbase, int kspl, long wstride,
    u16* __restrict__ hbh, u16* __restrict__ hbl, const float* __restrict__ comb)
{
  const int z = blockIdx.z;
  const int e = z / kspl;
  const int kc = z - e * kspl;
  const int cn = cnt[e];
  const int brow = blockIdx.y << 7;
  if (brow >= cn) return;
  const int cb = cbase[e];
  const int* pe = perm + e * NTOK;
  const u16* Bhe = Bh + (long)e * wstride;
  const u16* Ble = Bl + (long)e * wstride;
  __shared__ u16 Ash[2][128 * 32], Asl[2][128 * 32];
  __shared__ u16 Bsh[2][128 * 32], Bsl[2][128 * 32];
  const int bcol = blockIdx.x << 7;
  const int tid = threadIdx.x;
  const int wid = tid >> 6;
  const int lane = tid & 63;
  const int wr = (wid >> 1) << 6;
  const int wc = (wid & 1) << 6;

  f32x4 acc[4][4] = {};
  const int a0 = (wid << 11) + (lane << 4);

  int arow[2];
#pragma unroll
  for (int c = 0; c < 2; ++c) {
    int ab = a0 + (c << 10);
    int row = ab >> 6;
    int g = brow + row;
    if constexpr (MODE == 5) {
      arow[c] = (g < cn) ? pe[g] : pe[brow];
    } else {
      arow[c] = cb + ((g < cn) ? g : (cn - 1));
    }
  }

  auto stage = [&](int buf, int k0) {
#pragma unroll
    for (int c = 0; c < 2; ++c) {
      int ab = a0 + (c << 10);
      int row = ab >> 6;
      int kcol = (ab & 63) >> 1;
      int ld = (wid << 11) + (c << 10);
      gload16(Ah + (long)arow[c] * lda + (k0 + kcol), (char*)Ash[buf] + ld);
      gload16(Al + (long)arow[c] * lda + (k0 + kcol), (char*)Asl[buf] + ld);
      long bo = (long)(bcol + row) * ldb + (k0 + kcol);
      gload16(Bhe + bo, (char*)Bsh[buf] + ld);
      gload16(Ble + bo, (char*)Bsl[buf] + ld);
    }
  };

  const int kt = K / kspl;
  const int kbeg = kc * kt;
  const int nt = kt >> 5;
  stage(0, kbeg);
  __syncthreads();
  for (int t = 0; t < nt; ++t) {
    const int cur = t & 1;
    if (t + 1 < nt) stage(cur ^ 1, kbeg + ((t + 1) << 5));
    const int lr = lane & 15;
    const int lk = (lane >> 4) << 4;
    bf16x8 ah[4], al[4], bh_[4], bl[4];
#pragma unroll
    for (int m = 0; m < 4; ++m) {
      int off = ((wr + m * 16 + lr) << 6) + lk;
      ah[m] = *(const bf16x8*)((const char*)Ash[cur] + off);
      al[m] = *(const bf16x8*)((const char*)Asl[cur] + off);
    }
#pragma unroll
    for (int n = 0; n < 4; ++n) {
      int off = ((wc + n * 16 + lr) << 6) + lk;
      bh_[n] = *(const bf16x8*)((const char*)Bsh[cur] + off);
      bl[n] = *(const bf16x8*)((const char*)Bsl[cur] + off);
    }
#pragma unroll
    for (int m = 0; m < 4; ++m)
#pragma unroll
      for (int n = 0; n < 4; ++n) {
        acc[m][n] = __builtin_amdgcn_mfma_f32_16x16x32_bf16(al[m], bh_[n], acc[m][n], 0, 0, 0);
        acc[m][n] = __builtin_amdgcn_mfma_f32_16x16x32_bf16(ah[m], bl[n], acc[m][n], 0, 0, 0);
        acc[m][n] = __builtin_amdgcn_mfma_f32_16x16x32_bf16(ah[m], bh_[n], acc[m][n], 0, 0, 0);
      }
    if (t + 1 < nt) __syncthreads();
  }

  const int crow0 = brow + wr + ((lane >> 4) << 2);
  const int ccol0 = bcol + wc + (lane & 15);
  if constexpr (MODE == 5) {
    const int pbase = (bcol + wc) >> 5;
#pragma unroll
    for (int m = 0; m < 4; ++m)
#pragma unroll
      for (int j = 0; j < 4; ++j) {
        int r = crow0 + m * 16 + j;
        if (r < cn) {
          float w = comb[pe[r] * 4 + e];
#pragma unroll
          for (int np = 0; np < 2; ++np) {
            float g = acc[m][2 * np][j], u = acc[m][2 * np + 1][j];
            float h = siluf(g) * u * w;
            int hcol = ((pbase + np) << 4) + (lane & 15);
            u16 hh, ll; split2(h, hh, ll);
            hbh[(long)(cb + r) * FF + hcol] = hh;
            hbl[(long)(cb + r) * FF + hcol] = ll;
          }
        }
      }
  } else {
#pragma unroll
    for (int m = 0; m < 4; ++m)
#pragma unroll
      for (int n = 0; n < 4; ++n)
#pragma unroll
        for (int j = 0; j < 4; ++j) {
          int r = crow0 + m * 16 + j;
          if (r < cn) {
            int col = ccol0 + n * 16;
            unsafeAtomicAdd(&C[(long)pe[r] * ldc + col], acc[m][n][j]);
          }
        }
  }
}

// ---------------------------------------------------------------------------
// Batched indirect plain bf16 GEMM over experts (layer-1).
// MODE 5: gather-A, fused gu -> hb rows cbase[e]+r. MODE 3: compact-A, scatter.
// ---------------------------------------------------------------------------
template<int MODE>
__global__ __launch_bounds__(256) void gemmi_nt(
    const u16* __restrict__ A, const u16* __restrict__ B, void* __restrict__ Cv,
    int N, int K, int lda, int ldb, int ldc,
    const int* __restrict__ perm, const int* __restrict__ cnt,
    const int* __restrict__ cbase, int kspl, long wstride,
    u16* __restrict__ hb, const float* __restrict__ comb)
{
  const int z = blockIdx.z;
  const int e = z / kspl;
  const int kc = z - e * kspl;
  const int cn = cnt[e];
  const int brow = blockIdx.y << 7;
  if (brow >= cn) return;
  const int cb = cbase[e];
  const int* pe = perm + e * NTOK;
  const u16* Be = B + (long)e * wstride;
  __shared__ u16 As[2][128 * 32];
  __shared__ u16 Bs[2][128 * 32];
  const int bcol = blockIdx.x << 7;
  const int tid = threadIdx.x;
  const int wid = tid >> 6;
  const int lane = tid & 63;
  const int wr = (wid >> 1) << 6;
  const int wc = (wid & 1) << 6;

  f32x4 acc[4][4] = {};
  const int a0 = (wid << 11) + (lane << 4);

  int arow[2];
#pragma unroll
  for (int c = 0; c < 2; ++c) {
    int ab = a0 + (c << 10);
    int row = ab >> 6;
    int g = brow + row;
    if constexpr (MODE == 5) {
      arow[c] = (g < cn) ? pe[g] : pe[brow];
    } else {
      arow[c] = cb + ((g < cn) ? g : (cn - 1));
    }
  }

  auto stage = [&](int buf, int k0) {
#pragma unroll
    for (int c = 0; c < 2; ++c) {
      int ab = a0 + (c << 10);
      int row = ab >> 6;
      int kcol = (ab & 63) >> 1;
      int ld = (wid << 11) + (c << 10);
      gload16(A + (long)arow[c] * lda + (k0 + kcol), (char*)As[buf] + ld);
      gload16(Be + (long)(bcol + row) * ldb + (k0 + kcol), (char*)Bs[buf] + ld);
    }
  };

  const int kt = K / kspl;
  const int kbeg = kc * kt;
  const int nt = kt >> 5;
  stage(0, kbeg);
  __syncthreads();
  for (int t = 0; t < nt; ++t) {
    const int cur = t & 1;
    if (t + 1 < nt) stage(cur ^ 1, kbeg + ((t + 1) << 5));
    bf16x8 af[4], bfr[4];
    const int lr = lane & 15;
    const int lk = (lane >> 4) << 4;
#pragma unroll
    for (int m = 0; m < 4; ++m)
      af[m] = *(const bf16x8*)((const char*)As[cur] + (((wr + m * 16 + lr) << 6) + lk));
#pragma unroll
    for (int n = 0; n < 4; ++n)
      bfr[n] = *(const bf16x8*)((const char*)Bs[cur] + (((wc + n * 16 + lr) << 6) + lk));
#pragma unroll
    for (int m = 0; m < 4; ++m)
#pragma unroll
      for (int n = 0; n < 4; ++n)
        acc[m][n] = __builtin_amdgcn_mfma_f32_16x16x32_bf16(af[m], bfr[n], acc[m][n], 0, 0, 0);
    if (t + 1 < nt) __syncthreads();
  }

  const int crow0 = brow + wr + ((lane >> 4) << 2);
  const int ccol0 = bcol + wc + (lane & 15);
  if constexpr (MODE == 5) {
    const int pbase = (bcol + wc) >> 5;
#pragma unroll
    for (int m = 0; m < 4; ++m)
#pragma unroll
      for (int j = 0; j < 4; ++j) {
        int r = crow0 + m * 16 + j;
        if (r < cn) {
          float w = comb[pe[r] * 4 + e];
#pragma unroll
          for (int np = 0; np < 2; ++np) {
            float g = acc[m][2 * np][j], u = acc[m][2 * np + 1][j];
            int hcol = ((pbase + np) << 4) + (lane & 15);
            hb[(long)(cb + r) * FF + hcol] = f2bf(siluf(g) * u * w);
          }
        }
      }
  } else {
#pragma unroll
    for (int m = 0; m < 4; ++m)
#pragma unroll
      for (int n = 0; n < 4; ++n)
#pragma unroll
        for (int j = 0; j < 4; ++j) {
          int r = crow0 + m * 16 + j;
          if (r < cn) {
            int col = ccol0 + n * 16;
            unsafeAtomicAdd((float*)Cv + (long)pe[r] * ldc + col, acc[m][n][j]);
          }
        }
  }
}

// ---------------------------------------------------------------------------
// Fused flash attention (round-4 64-row variant, unchanged).
// ---------------------------------------------------------------------------
__global__ __launch_bounds__(256, 2) void fattn_k(
    const u16* __restrict__ qh, const u16* __restrict__ ql,
    const u16* __restrict__ kh, const u16* __restrict__ kl,
    const u16* __restrict__ vth, const u16* __restrict__ vtl,
    u16* __restrict__ omh, u16* __restrict__ oml, float scale)
{
  __shared__ u16 Ksh[64 * 128], Ksl[64 * 128];
  __shared__ u16 Vsh[128 * 64], Vsl[128 * 64];
  const int bh = blockIdx.x;
  const int qt = blockIdx.y;
  const int tid = threadIdx.x, wid = tid >> 6, lane = tid & 63;
  const int lr = lane & 15, lg = lane >> 4;
  const int q0 = qt * 64 + wid * 16;
  const long bhoff = (long)bh * S_LEN * HDP;
  const u16* Qh = qh + bhoff;  const u16* Ql = ql + bhoff;
  const u16* Kgh = kh + bhoff; const u16* Kgl = kl + bhoff;
  const u16* Vgh = vth + bhoff; const u16* Vgl = vtl + bhoff;

  bf16x8 qfh[4], qfl[4];
#pragma unroll
  for (int kk = 0; kk < 4; ++kk) {
    long o = (long)(q0 + lr) * HDP + kk * 32 + lg * 8;
    qfh[kk] = *(const bf16x8*)(Qh + o);
    qfl[kk] = *(const bf16x8*)(Ql + o);
  }

  f32x4 oacc[6] = {};
  float rm[4], rls[4];
#pragma unroll
  for (int j = 0; j < 4; ++j) { rm[j] = -1e30f; rls[j] = 0.f; }

  for (int t = 0; t < S_LEN / 64; ++t) {
    __syncthreads();
#pragma unroll
    for (int c = 0; c < 4; ++c) {
      int off = (tid + (c << 8)) << 4;
      {
        int lb = off ^ ((((off >> 8) & 7)) << 4);
        int row = lb >> 8, colh = (lb & 255) >> 1;
        long src = (long)(t * 64 + row) * HDP + colh;
        gload16(Kgh + src, (char*)Ksh + off);
        gload16(Kgl + src, (char*)Ksl + off);
      }
      {
        int lb = off ^ ((((off >> 7) & 7)) << 4);
        int row = lb >> 7, colh = (lb & 127) >> 1;
        long src = (long)row * S_LEN + t * 64 + colh;
        gload16(Vgh + src, (char*)Vsh + off);
        gload16(Vgl + src, (char*)Vsl + off);
      }
    }
    __syncthreads();

    f32x4 sacc[4] = {};
#pragma unroll
    for (int kk = 0; kk < 4; ++kk) {
      bf16x8 kbh[4], kbl[4];
#pragma unroll
      for (int n = 0; n < 4; ++n) {
        int byte = ((n * 16 + lr) << 8) + (kk << 6) + (lg << 4);
        byte ^= ((byte >> 8) & 7) << 4;
        kbh[n] = *(const bf16x8*)((const char*)Ksh + byte);
        kbl[n] = *(const bf16x8*)((const char*)Ksl + byte);
      }
      __builtin_amdgcn_s_setprio(1);
#pragma unroll
      for (int n = 0; n < 4; ++n) {
        sacc[n] = __builtin_amdgcn_mfma_f32_16x16x32_bf16(qfl[kk], kbh[n], sacc[n], 0, 0, 0);
        sacc[n] = __builtin_amdgcn_mfma_f32_16x16x32_bf16(qfh[kk], kbl[n], sacc[n], 0, 0, 0);
        sacc[n] = __builtin_amdgcn_mfma_f32_16x16x32_bf16(qfh[kk], kbh[n], sacc[n], 0, 0, 0);
      }
      __builtin_amdgcn_s_setprio(0);
    }
    __syncthreads();

#pragma unroll
    for (int j = 0; j < 4; ++j) {
      float mx = fmaxf(fmaxf(sacc[0][j], sacc[1][j]),
                       fmaxf(sacc[2][j], sacc[3][j])) * scale;
      mx = fmaxf(mx, __shfl_xor(mx, 1));
      mx = fmaxf(mx, __shfl_xor(mx, 2));
      mx = fmaxf(mx, __shfl_xor(mx, 4));
      mx = fmaxf(mx, __shfl_xor(mx, 8));
      float mnew = fmaxf(rm[j], mx);
      float corr = __expf(rm[j] - mnew);
      rm[j] = mnew;
      float ps = 0.f;
#pragma unroll
      for (int n = 0; n < 4; ++n) {
        float p = __expf(sacc[n][j] * scale - mnew);
        sacc[n][j] = p; ps += p;
      }
      ps += __shfl_xor(ps, 1); ps += __shfl_xor(ps, 2);
      ps += __shfl_xor(ps, 4); ps += __shfl_xor(ps, 8);
      rls[j] = rls[j] * corr + ps;
#pragma unroll
      for (int n2 = 0; n2 < 6; ++n2) oacc[n2][j] *= corr;
    }

    char* Pwh = (char*)Ksh + (wid << 11);
    char* Pwl = (char*)Ksl + (wid << 11);
#pragma unroll
    for (int n = 0; n < 4; ++n)
#pragma unroll
      for (int j = 0; j < 4; ++j) {
        int row = lg * 4 + j;
        int byte = (row << 7) + ((n * 16 + lr) << 1);
        byte ^= ((byte >> 7) & 7) << 4;
        u16 h, l; split2(sacc[n][j], h, l);
        *(u16*)(Pwh + byte) = h;
        *(u16*)(Pwl + byte) = l;
      }
    bf16x8 pah[2], pal[2];
#pragma unroll
    for (int kk = 0; kk < 2; ++kk) {
      int byte = (lr << 7) + (kk << 6) + (lg << 4);
      byte ^= ((byte >> 7) & 7) << 4;
      pah[kk] = *(const bf16x8*)(Pwh + byte);
      pal[kk] = *(const bf16x8*)(Pwl + byte);
    }

#pragma unroll
    for (int kk = 0; kk < 2; ++kk) {
      bf16x8 vbh[6], vbl[6];
#pragma unroll
      for (int n2 = 0; n2 < 6; ++n2) {
        int byte = ((n2 * 16 + lr) << 7) + (kk << 6) + (lg << 4);
        byte ^= ((byte >> 7) & 7) << 4;
        vbh[n2] = *(const bf16x8*)((const char*)Vsh + byte);
        vbl[n2] = *(const bf16x8*)((const char*)Vsl + byte);
      }
      __builtin_amdgcn_s_setprio(1);
#pragma unroll
      for (int n2 = 0; n2 < 6; ++n2) {
        oacc[n2] = __builtin_amdgcn_mfma_f32_16x16x32_bf16(pal[kk], vbh[n2], oacc[n2], 0, 0, 0);
        oacc[n2] = __builtin_amdgcn_mfma_f32_16x16x32_bf16(pah[kk], vbl[n2], oacc[n2], 0, 0, 0);
        oacc[n2] = __builtin_amdgcn_mfma_f32_16x16x32_bf16(pah[kk], vbh[n2], oacc[n2], 0, 0, 0);
      }
      __builtin_amdgcn_s_setprio(0);
    }
  }

  const int b = bh >> 3, h = bh & 7;
#pragma unroll
  for (int j = 0; j < 4; ++j) {
    float inv = 1.0f / rls[j];
    int q = q0 + lg * 4 + j;
    long base = ((long)(b * S_LEN + q)) * DM + h * HDIM;
#pragma unroll
    for (int n2 = 0; n2 < 6; ++n2) {
      int d = n2 * 16 + lr;
      u16 hh, ll; split2(oacc[n2][j] * inv, hh, ll);
      omh[base + d] = hh; oml[base + d] = ll;
    }
  }
}

// ---------------------------------------------------------------------------
// fp32 [R][C] -> bf16 hi/lo [C][R] transpose+split, z-batched.
// ilv<0: linear rows; ilv in {0,1}: gate/up 16-row interleave.
// ---------------------------------------------------------------------------
__global__ void wconv_t(const float* __restrict__ in, u16* __restrict__ outh,
                        u16* __restrict__ outl, int R, int C, int ilv,
                        long inStride, long outStride) {
  __shared__ float tile[32][33];
  long z = blockIdx.z;
  in += z * inStride; outh += z * outStride; outl += z * outStride;
  int c0 = blockIdx.x << 5, r0 = blockIdx.y << 5;
  int tx = threadIdx.x;
  for (int rr = threadIdx.y; rr < 32; rr += 8)
    tile[rr][tx] = in[(long)(r0 + rr) * C + (c0 + tx)];
  __syncthreads();
  for (int rr = threadIdx.y; rr < 32; rr += 8) {
    u16 h, l; split2(tile[tx][rr], h, l);
    int f = c0 + rr;
    long orow = (ilv < 0) ? f : (((f >> 4) << 5) + (ilv << 4) + (f & 15));
    long o = orow * R + (r0 + tx);
    outh[o] = h; outl[o] = l;
  }
}

__global__ __launch_bounds__(256) void ln_k(const float* __restrict__ in,
    const float* __restrict__ g, const float* __restrict__ b,
    float* __restrict__ outf, u16* __restrict__ outh, u16* __restrict__ outl) {
  int row = blockIdx.x;
  const float* x = in + (long)row * DM;
  int tid = threadIdx.x;
  float v[3], s = 0.f, ss = 0.f;
#pragma unroll
  for (int i = 0; i < 3; ++i) { v[i] = x[tid + (i << 8)]; s += v[i]; ss += v[i] * v[i]; }
  __shared__ float red[2][4];
  for (int o = 32; o; o >>= 1) { s += __shfl_down(s, o); ss += __shfl_down(ss, o); }
  int wid = tid >> 6, lane = tid & 63;
  if (!lane) { red[0][wid] = s; red[1][wid] = ss; }
  __syncthreads();
  s = red[0][0] + red[0][1] + red[0][2] + red[0][3];
  ss = red[1][0] + red[1][1] + red[1][2] + red[1][3];
  float mean = s * (1.f / DM);
  float var = ss * (1.f / DM) - mean * mean;
  float rs = rsqrtf(var + 1e-5f);
#pragma unroll
  for (int i = 0; i < 3; ++i) {
    int c = tid + (i << 8);
    float y = (v[i] - mean) * rs * g[c] + b[c];
    if (outf) outf[(long)row * DM + c] = y;
    if (outh) { u16 h, l; split2(y, h, l); outh[(long)row * DM + c] = h; outl[(long)row * DM + c] = l; }
  }
}

__global__ void rope_tables_k(float* __restrict__ cosT, float* __restrict__ sinT) {
  int s = blockIdx.x, d = threadIdx.x;
  int xc = s & 15, y = (s >> 4) & 15, t = s >> 8;
  int axis = d / 32, fi = d & 15;
  int coord = axis == 0 ? xc : (axis == 1 ? y : t);
  float inv = powf(10000.0f, -(float)fi / 16.0f);
  float ang = (float)coord * inv;
  cosT[s * HDIM + d] = cosf(ang);
  sinT[s * HDIM + d] = sinf(ang);
}

__global__ __launch_bounds__(256) void rope_apply_k(const float* __restrict__ qkv,
    const float* __restrict__ cosT, const float* __restrict__ sinT,
    u16* __restrict__ qh, u16* __restrict__ ql,
    u16* __restrict__ kh, u16* __restrict__ kl) {
  int bs = blockIdx.x;
  int b = bs >> 11, s = bs & 2047;
  const float* base = qkv + ((long)(b * S_LEN + s) * 3) * DM;
  for (int idx = threadIdx.x; idx < DM; idx += 256) {
    int h = idx / HDIM, d = idx - h * HDIM;
    float c = cosT[s * HDIM + d], sn = sinT[s * HDIM + d];
    int pair = (d < 48) ? idx + 48 : idx - 48;
    float qv = base[idx], kv = base[DM + idx];
    float qr = (d < 48) ? -base[pair] : base[pair];
    float kr = (d < 48) ? -base[DM + pair] : base[DM + pair];
    long o = ((long)(b * NHEAD + h) * S_LEN + s) * HDP + d;
    u16 hh, ll;
    split2(qv * c + qr * sn, hh, ll); qh[o] = hh; ql[o] = ll;
    split2(kv * c + kr * sn, hh, ll); kh[o] = hh; kl[o] = ll;
  }
  int t = threadIdx.x;
  int h = t >> 5, d = HDIM + (t & 31);
  long o = ((long)(b * NHEAD + h) * S_LEN + s) * HDP + d;
  qh[o] = 0; ql[o] = 0; kh[o] = 0; kl[o] = 0;
}

__global__ void v_transpose_k(const float* __restrict__ qkv,
                              u16* __restrict__ vh, u16* __restrict__ vl) {
  __shared__ float tile[32][33];
  int bh = blockIdx.z, b = bh >> 3, h = bh & 7;
  int s0 = blockIdx.x << 5, d0 = blockIdx.y << 5;
  int tx = threadIdx.x;
  for (int r = threadIdx.y; r < 32; r += 8) {
    int s = s0 + r, d = d0 + tx;
    float v = 0.f;
    if (d < HDIM) v = qkv[((long)(b * S_LEN + s) * 3 + 2) * DM + h * HDIM + d];
    tile[r][tx] = v;
  }
  __syncthreads();
  for (int r = threadIdx.y; r < 32; r += 8) {
    int d = d0 + r;
    u16 hh, ll; split2(tile[tx][r], hh, ll);
    long o = ((long)bh * HDP + d) * S_LEN + (s0 + tx);
    vh[o] = hh; vl[o] = ll;
  }
}

// Router: comb[tok][e] + top-2 bitmask per token.
__global__ __launch_bounds__(256) void router_k(const float* __restrict__ x,
    const float* __restrict__ gw, float* __restrict__ comb, int* __restrict__ mask) {
  int tok = blockIdx.x * 4 + (threadIdx.x >> 6);
  int lane = threadIdx.x & 63;
  const float* xr = x + (long)tok * DM;
  float a0 = 0, a1 = 0, a2 = 0, a3 = 0;
  for (int i = lane; i < DM; i += 64) {
    float xv = xr[i];
    const float* g = gw + i * 4;
    a0 += xv * g[0]; a1 += xv * g[1]; a2 += xv * g[2]; a3 += xv * g[3];
  }
  for (int o = 32; o; o >>= 1) {
    a0 += __shfl_down(a0, o); a1 += __shfl_down(a1, o);
    a2 += __shfl_down(a2, o); a3 += __shfl_down(a3, o);
  }
  if (lane == 0) {
    float p[4] = {a0, a1, a2, a3};
    float mx = fmaxf(fmaxf(p[0], p[1]), fmaxf(p[2], p[3]));
    float s = 0.f;
    for (int e = 0; e < 4; ++e) { p[e] = expf(p[e] - mx); s += p[e]; }
    for (int e = 0; e < 4; ++e) p[e] /= s;
    int i1 = 0;
    for (int e = 1; e < 4; ++e) if (p[e] > p[i1]) i1 = e;
    int i2 = -1;
    for (int e = 0; e < 4; ++e) if (e != i1 && (i2 < 0 || p[e] > p[i2])) i2 = e;
    float ssum = p[i1] + p[i2] + 1e-5f;
    float out[4] = {0, 0, 0, 0};
    out[i1] = p[i1] / ssum; out[i2] = p[i2] / ssum;
    for (int e = 0; e < 4; ++e) comb[tok * 4 + e] = out[e];
    mask[tok] = (1 << i1) | (1 << i2);
  }
}

// Deterministic per-expert compaction; one block per expert (grid = NEXP).
__global__ void scan_k(const int* __restrict__ mask, int* __restrict__ perm,
                       int* __restrict__ cnt) {
  __shared__ int sd[256];
  __shared__ int base;
  int tid = threadIdx.x;
  int e = blockIdx.x;
  if (tid == 0) base = 0;
  __syncthreads();
  for (int c = 0; c < NTOK / 256; ++c) {
    int tok = c * 256 + tid;
    int f = (mask[tok] >> e) & 1;
    sd[tid] = f;
    __syncthreads();
    for (int s = 1; s < 256; s <<= 1) {
      int v = (tid >= s) ? sd[tid - s] : 0;
      __syncthreads();
      sd[tid] += v;
      __syncthreads();
    }
    if (f) perm[e * NTOK + base + sd[tid] - 1] = tok;
    int tot = sd[255];
    __syncthreads();
    if (tid == 0) base += tot;
    __syncthreads();
  }
  if (tid == 0) cnt[e] = base;
}

__global__ void cbase_k(const int* __restrict__ cnt, int* __restrict__ cbase) {
  if (threadIdx.x == 0) {
    int b = 0;
    for (int e = 0; e < NEXP; ++e) { cbase[e] = b; b += cnt[e]; }
  }
}

__global__ void f2b_k(const float* __restrict__ src, u16* __restrict__ dst, long n) {
  long i = (long)blockIdx.x * 256 + threadIdx.x;
  if (i < n) dst[i] = f2bf(src[i]);
}

__global__ void f2bsplit_k(const float* __restrict__ src, u16* __restrict__ dh,
                           u16* __restrict__ dl, long n) {
  long i = (long)blockIdx.x * 256 + threadIdx.x;
  if (i < n) { u16 h, l; split2(src[i], h, l); dh[i] = h; dl[i] = l; }
}

extern "C" void kernel_launch(void* const* d_in, const int* in_sizes, int n_in,
                              void* d_out, int out_size, void* d_ws, size_t ws_size,
                              hipStream_t stream) {
  (void)in_sizes; (void)n_in; (void)out_size; (void)ws_size;
  const float* x_in  = (const float*)d_in[0];
  const float* ln1_g = (const float*)d_in[4];
  const float* ln1_b = (const float*)d_in[5];
  const float* w_qkv = (const float*)d_in[6];
  const float* w_out = (const float*)d_in[7];
  const float* gatew = (const float*)d_in[8];
  const float* eg    = (const float*)d_in[9];
  const float* eu    = (const float*)d_in[10];
  const float* ed    = (const float*)d_in[11];
  const float* sg    = (const float*)d_in[12];
  const float* su    = (const float*)d_in[13];
  const float* sd    = (const float*)d_in[14];
  const float* ln2_g = (const float*)d_in[15];
  const float* ln2_b = (const float*)d_in[16];

  float* xc = (float*)d_out;
  char* W = (char*)d_ws;
  size_t off = 0;
  auto alloc = [&](size_t bytes) {
    size_t o = off; off = (off + bytes + 255) & ~(size_t)255; return o;
  };
  // ---- persistent region (~14.3 MB) ----
  size_t o_cos  = alloc((size_t)S_LEN * HDIM * 4);
  size_t o_sin  = alloc((size_t)S_LEN * HDIM * 4);
  size_t o_xnh  = alloc((size_t)NTOK * DM * 2);
  size_t o_xnl  = alloc((size_t)NTOK * DM * 2);
  size_t o_comb = alloc((size_t)NTOK * 4 * 4);
  size_t o_mask = alloc((size_t)NTOK * 4);
  size_t o_perm = alloc((size_t)NEXP * NTOK * 4);
  size_t o_cnt  = alloc(256);
  size_t o_cb   = alloc(256);
  // ---- region A (union, 103.8 MB) ----
  const size_t EGU_B = (size_t)NEXP * FF2 * DM * 2;          // 37,748,736
  const size_t SGU_B = (size_t)FF2 * DM * 2;                 //  9,437,184
  const size_t SD_B  = (size_t)DM * FF * 2;                  //  4,718,592
  const size_t A_BYTES = 2 * EGU_B + 2 * SGU_B + 2 * SD_B;   // 103,809,024
  size_t oA = alloc(A_BYTES);
  // attention view of A
  size_t o_qkv = oA;                                          // 37,748,736 f32
  size_t o_qph = oA + (size_t)NTOK * 3 * DM * 4;
  size_t o_qpl = o_qph + (size_t)NBH * S_LEN * HDP * 2;
  size_t o_kph = o_qpl + (size_t)NBH * S_LEN * HDP * 2;
  size_t o_kpl = o_kph + (size_t)NBH * S_LEN * HDP * 2;
  size_t o_vth = o_kpl + (size_t)NBH * S_LEN * HDP * 2;
  size_t o_vtl = o_vth + (size_t)NBH * HDP * S_LEN * 2;
  size_t o_omh = o_vtl + (size_t)NBH * HDP * S_LEN * 2;
  size_t o_oml = o_omh + (size_t)NTOK * DM * 2;
  // moe view of A
  size_t o_eguh = oA;
  size_t o_egul = oA + EGU_B;
  size_t o_sguh = oA + 2 * EGU_B;
  size_t o_sgul = o_sguh + SGU_B;
  size_t o_sdh  = o_sgul + SGU_B;
  size_t o_sdl  = o_sdh + SD_B;
  size_t o_edh  = oA;                      // overlays egu (dead after expert-gu)
  size_t o_edl  = oA + (size_t)NEXP * DM * FF * 2;
  // ---- region H (union, 100.7 MB) ----
  const size_t H_BYTES = (size_t)2 * HBROWS * FF * 2;         // 100,663,296
  size_t oH = alloc(H_BYTES);
  size_t o_wqh = oH;
  size_t o_wql = o_wqh + (size_t)3 * DM * DM * 2;
  size_t o_woh = o_wql + (size_t)3 * DM * DM * 2;
  size_t o_wol = o_woh + (size_t)DM * DM * 2;
  size_t o_hbh = oH;
  size_t o_hbl = oH + (size_t)HBROWS * FF * 2;

  float* cosT = (float*)(W + o_cos);
  float* sinT = (float*)(W + o_sin);
  u16*   xnh  = (u16*)(W + o_xnh);
  u16*   xnl  = (u16*)(W + o_xnl);
  float* comb = (float*)(W + o_comb);
  int* maskb  = (int*)(W + o_mask);
  int* permb  = (int*)(W + o_perm);
  int* cntb   = (int*)(W + o_cnt);
  int* cbaseb = (int*)(W + o_cb);
  float* qkv  = (float*)(W + o_qkv);
  u16 *qph = (u16*)(W + o_qph), *qpl = (u16*)(W + o_qpl);
  u16 *kph = (u16*)(W + o_kph), *kpl = (u16*)(W + o_kpl);
  u16 *vth = (u16*)(W + o_vth), *vtl = (u16*)(W + o_vtl);
  u16 *omh = (u16*)(W + o_omh), *oml = (u16*)(W + o_oml);
  u16 *eguh = (u16*)(W + o_eguh), *egul = (u16*)(W + o_egul);
  u16 *sguh = (u16*)(W + o_sguh), *sgul = (u16*)(W + o_sgul);
  u16 *sdh = (u16*)(W + o_sdh), *sdl = (u16*)(W + o_sdl);
  u16 *edh = (u16*)(W + o_edh), *edl = (u16*)(W + o_edl);
  u16 *wqh = (u16*)(W + o_wqh), *wql = (u16*)(W + o_wql);
  u16 *woh = (u16*)(W + o_woh), *wol = (u16*)(W + o_wol);
  u16 *hbh = (u16*)(W + o_hbh), *hbl = (u16*)(W + o_hbl);

  const long ND = (long)NTOK * DM;
  const int gND = (int)((ND + 255) / 256);

  hipMemcpyAsync(xc, x_in, (size_t)ND * 4, hipMemcpyDeviceToDevice, stream);
  rope_tables_k<<<S_LEN, HDIM, 0, stream>>>(cosT, sinT);

  dim3 tb(32, 8, 1);
  for (int l = 0; l < 2; ++l) {
    const float* wqkv_l = w_qkv + (size_t)l * DM * 3 * DM;
    const float* wout_l = w_out + (size_t)l * DM * DM;
    const float* gw_l   = gatew + (size_t)l * DM * 4;
    const float* eg_l = eg + (size_t)l * NEXP * DM * FF;
    const float* eu_l = eu + (size_t)l * NEXP * DM * FF;
    const float* ed_l = ed + (size_t)l * NEXP * FF * DM;
    const float* sg_l = sg + (size_t)l * DM * FF;
    const float* su_l = su + (size_t)l * DM * FF;
    const float* sd_l = sd + (size_t)l * FF * DM;

    // attention weights into region H (hb is dead here)
    wconv_t<<<dim3(3 * DM / 32, DM / 32, 1), tb, 0, stream>>>(wqkv_l, wqh, wql, DM, 3 * DM, -1, 0, 0);
    wconv_t<<<dim3(DM / 32, DM / 32, 1), tb, 0, stream>>>(wout_l, woh, wol, DM, DM, -1, 0, 0);

    // --- attention (fp32-equivalent via bf16x3 + flash) ---
    ln_k<<<NTOK, 256, 0, stream>>>(xc, ln1_g + l * DM, ln1_b + l * DM, nullptr, xnh, xnl);
    gemm3_nt<0><<<dim3(3 * DM >> 7, NTOK >> 7, 1), 256, 0, stream>>>(
        xnh, xnl, wqh, wql, qkv, NTOK, 3 * DM, DM, DM, DM, 0, 0, 0, 1, nullptr, nullptr);
    rope_apply_k<<<NTOK, 256, 0, stream>>>(qkv, cosT, sinT, qph, qpl, kph, kpl);
    v_transpose_k<<<dim3(S_LEN / 32, HDP / 32, NBH), tb, 0, stream>>>(qkv, vth, vtl);
    fattn_k<<<dim3(NBH, S_LEN / 64), dim3(256), 0, stream>>>(
        qph, qpl, kph, kpl, vth, vtl, omh, oml, 0.10206207261596575f);
    gemm3_nt<3><<<dim3(DM >> 7, NTOK >> 7, 2), 256, 0, stream>>>(
        omh, oml, woh, wol, xc, NTOK, DM, DM, DM, DM, 0, 0, 0, 2, nullptr, nullptr);

    // --- router + deterministic expert compaction (CSR) ---
    router_k<<<NTOK / 4, 256, 0, stream>>>(xc, gw_l, comb, maskb);
    scan_k<<<NEXP, 256, 0, stream>>>(maskb, permb, cntb);
    cbase_k<<<1, 64, 0, stream>>>(cntb, cbaseb);

    // MoE weight conversion into region A (attention buffers dead now)
    wconv_t<<<dim3(FF / 32, DM / 32, 1), tb, 0, stream>>>(sg_l, sguh, sgul, DM, FF, 0, 0, 0);
    wconv_t<<<dim3(FF / 32, DM / 32, 1), tb, 0, stream>>>(su_l, sguh, sgul, DM, FF, 1, 0, 0);
    wconv_t<<<dim3(DM / 32, FF / 32, 1), tb, 0, stream>>>(sd_l, sdh, sdl, FF, DM, -1, 0, 0);
    wconv_t<<<dim3(FF / 32, DM / 32, NEXP), tb, 0, stream>>>(
        eg_l, eguh, egul, DM, FF, 0, (long)DM * FF, (long)FF2 * DM);
    wconv_t<<<dim3(FF / 32, DM / 32, NEXP), tb, 0, stream>>>(
        eu_l, eguh, egul, DM, FF, 1, (long)DM * FF, (long)FF2 * DM);

    if (l == 0) {
      f2bsplit_k<<<gND, 256, 0, stream>>>(xc, xnh, xnl, ND);
      // shared expert: fused gu+silu -> hb[0..NTOK), down atomic into xc
      gemm3_nt<5><<<dim3(FF2 >> 7, NTOK >> 7, 1), 256, 0, stream>>>(
          xnh, xnl, sguh, sgul, nullptr, NTOK, FF2, DM, DM, DM, 0, 0, 0, 1, hbh, hbl);
      gemm3_nt<3><<<dim3(DM >> 7, NTOK >> 7, 4), 256, 0, stream>>>(
          hbh, hbl, sdh, sdl, xc, NTOK, DM, FF, FF, FF, 0, 0, 0, 4, nullptr, nullptr);
      // all 4 routed experts batched (z = expert)
      gemm3i_nt<5><<<dim3(FF2 >> 7, NTOK >> 7, NEXP), 256, 0, stream>>>(
          xnh, xnl, eguh, egul, nullptr, FF2, DM, DM, DM, FF2,
          permb, cntb, cbaseb, 1, (long)FF2 * DM, hbh, hbl, comb);
      // ed conversion overlays dead egu region, then batched down-scatter
      wconv_t<<<dim3(DM / 32, FF / 32, NEXP), tb, 0, stream>>>(
          ed_l, edh, edl, FF, DM, -1, (long)FF * DM, (long)DM * FF);
      gemm3i_nt<1><<<dim3(DM >> 7, NTOK >> 7, NEXP * 2), 256, 0, stream>>>(
          hbh, hbl, edh, edl, xc, DM, FF, FF, FF, DM,
          permb, cntb, cbaseb, 2, (long)DM * FF, nullptr, nullptr, nullptr);
    } else {
      f2b_k<<<gND, 256, 0, stream>>>(xc, xnh, ND);
      gemm_nt<5><<<dim3(FF2 >> 7, NTOK >> 7, 1), 256, 0, stream>>>(
          xnh, sguh, nullptr, NTOK, FF2, DM, DM, DM, 0, 0, 0, 1, hbh);
      gemm_nt<3><<<dim3(DM >> 7, NTOK >> 7, 4), 256, 0, stream>>>(
          hbh, sdh, xc, NTOK, DM, FF, FF, FF, 0, 0, 0, 4, nullptr);
      gemmi_nt<5><<<dim3(FF2 >> 7, NTOK >> 7, NEXP), 256, 0, stream>>>(
          xnh, eguh, nullptr, FF2, DM, DM, DM, FF2,
          permb, cntb, cbaseb, 1, (long)FF2 * DM, hbh, comb);
      wconv_t<<<dim3(DM / 32, FF / 32, NEXP), tb, 0, stream>>>(
          ed_l, edh, edl, FF, DM, -1, (long)FF * DM, (long)DM * FF);
      gemmi_nt<3><<<dim3(DM >> 7, NTOK >> 7, NEXP * 2), 256, 0, stream>>>(
          hbh, edh, xc, DM, FF, FF, FF, DM,
          permb, cntb, cbaseb, 2, (long)DM * FF, nullptr, nullptr);
    }
    ln_k<<<NTOK, 256, 0, stream>>>(xc, ln2_g + l * DM, ln2_b + l * DM, xc, nullptr, nullptr);
  }
}

// Round 10
// 1849.612 us; speedup vs baseline: 2.9945x; 1.0057x over previous
//
#include <hip/hip_runtime.h>
#include <stdint.h>

#define S_LEN 2048
#define DM    768
#define NHEAD 8
#define HDIM  96
#define HDP   128
#define FF    3072
#define FF2   6144
#define NEXP  4
#define NTOK  4096
#define NBH   16
#define HBROWS (2 * NTOK)

typedef unsigned short u16;
typedef short bf16x8 __attribute__((ext_vector_type(8)));
typedef float f32x4 __attribute__((ext_vector_type(4)));
typedef __attribute__((address_space(1))) void* gptr_t;
typedef __attribute__((address_space(3))) void* lptr_t;

__device__ __forceinline__ u16 f2bf(float f) {
  union { float f; uint32_t u; } v; v.f = f;
  uint32_t r = v.u + 0x7FFFu + ((v.u >> 16) & 1u);
  return (u16)(r >> 16);
}
__device__ __forceinline__ float bf2f(u16 h) {
  union { uint32_t u; float f; } v; v.u = ((uint32_t)h) << 16;
  return v.f;
}
__device__ __forceinline__ void split2(float f, u16& hi, u16& lo) {
  u16 h = f2bf(f);
  lo = f2bf(f - bf2f(h));
  hi = h;
}
__device__ __forceinline__ float siluf(float g) {
  return g / (1.0f + expf(-g));
}
__device__ __forceinline__ void gload16(const void* g, void* l) {
  __builtin_amdgcn_global_load_lds((gptr_t)(void*)g, (lptr_t)l, 16, 0, 0);
}
// GEMM-tile LDS swizzle (64B rows): chunk bits 4-5 XOR row bits 1-2 (byte 7-8).
__device__ __forceinline__ int swz(int byte) {
  return byte ^ (((byte >> 7) & 3) << 4);
}

// ---------------------------------------------------------------------------
// Plain NT GEMM, 2-phase double-buffered. C[M,N] = A[M,K] @ B[N,K]^T.
// MODE: 0 f32, 2 bf16, 3 atomic f32, 5 fused gate/up silu -> hb bf16.
// ---------------------------------------------------------------------------
template<int MODE>
__global__ __launch_bounds__(256) void gemm_nt(
    const u16* __restrict__ A, const u16* __restrict__ B, void* __restrict__ Cv,
    int M, int N, int K, int lda, int ldb, long sA, long sB, long sC, int kspl,
    u16* __restrict__ hb)
{
  __shared__ u16 As[2][128 * 32];
  __shared__ u16 Bs[2][128 * 32];
  const int z = blockIdx.z;
  const int bh = z / kspl;
  const int kc = z - bh * kspl;
  const u16* Az = A + (long)bh * sA;
  const u16* Bz = B + (long)bh * sB;
  const int brow = blockIdx.y << 7;
  const int bcol = blockIdx.x << 7;
  const int tid = threadIdx.x;
  const int wid = tid >> 6;
  const int lane = tid & 63;
  const int wr = (wid >> 1) << 6;
  const int wc = (wid & 1) << 6;

  f32x4 acc[4][4] = {};
  const int a0 = (wid << 11) + (lane << 4);

  auto stage = [&](int buf, int k0) {
#pragma unroll
    for (int c = 0; c < 2; ++c) {
      int ab = a0 + (c << 10);
      int lb = swz(ab);
      int row = ab >> 6;
      int kcol = (lb & 63) >> 1;
      int ld = (wid << 11) + (c << 10);
      gload16(Az + (long)(brow + row) * lda + (k0 + kcol), (char*)As[buf] + ld);
      gload16(Bz + (long)(bcol + row) * ldb + (k0 + kcol), (char*)Bs[buf] + ld);
    }
  };

  const int kt = K / kspl;
  const int kbeg = kc * kt;
  const int nt = kt >> 5;
  stage(0, kbeg);
  __syncthreads();
  for (int t = 0; t < nt; ++t) {
    const int cur = t & 1;
    if (t + 1 < nt) stage(cur ^ 1, kbeg + ((t + 1) << 5));
    bf16x8 af[4], bfr[4];
    const int lr = lane & 15;
    const int lk = (lane >> 4) << 4;
#pragma unroll
    for (int m = 0; m < 4; ++m)
      af[m] = *(const bf16x8*)((const char*)As[cur] + swz((((wr + m * 16 + lr) << 6) + lk)));
#pragma unroll
    for (int n = 0; n < 4; ++n)
      bfr[n] = *(const bf16x8*)((const char*)Bs[cur] + swz((((wc + n * 16 + lr) << 6) + lk)));
#pragma unroll
    for (int m = 0; m < 4; ++m)
#pragma unroll
      for (int n = 0; n < 4; ++n)
        acc[m][n] = __builtin_amdgcn_mfma_f32_16x16x32_bf16(af[m], bfr[n], acc[m][n], 0, 0, 0);
    if (t + 1 < nt) __syncthreads();
  }

  const int crow0 = brow + wr + ((lane >> 4) << 2);
  const int ccol0 = bcol + wc + (lane & 15);
  const long cbase = (long)bh * sC;
  if constexpr (MODE == 5) {
    const int pbase = (bcol + wc) >> 5;
#pragma unroll
    for (int m = 0; m < 4; ++m)
#pragma unroll
      for (int np = 0; np < 2; ++np)
#pragma unroll
        for (int j = 0; j < 4; ++j) {
          int r = crow0 + m * 16 + j;
          float g = acc[m][2 * np][j], u = acc[m][2 * np + 1][j];
          int hcol = ((pbase + np) << 4) + (lane & 15);
          hb[(long)r * FF + hcol] = f2bf(siluf(g) * u);
        }
  } else {
#pragma unroll
    for (int m = 0; m < 4; ++m)
#pragma unroll
      for (int n = 0; n < 4; ++n)
#pragma unroll
        for (int j = 0; j < 4; ++j) {
          long idx = cbase + (long)(crow0 + m * 16 + j) * N + (ccol0 + n * 16);
          float v = acc[m][n][j];
          if constexpr (MODE == 2) ((u16*)Cv)[idx] = f2bf(v);
          else if constexpr (MODE == 3) unsafeAtomicAdd((float*)Cv + idx, v);
          else ((float*)Cv)[idx] = v;
        }
  }
}

// ---------------------------------------------------------------------------
// Split (bf16x3) NT GEMM, dense. MODE: 0 f32, 3 atomic f32, 5 fused gu silu.
// ---------------------------------------------------------------------------
template<int MODE>
__global__ __launch_bounds__(256) void gemm3_nt(
    const u16* __restrict__ Ah, const u16* __restrict__ Al,
    const u16* __restrict__ Bh, const u16* __restrict__ Bl,
    float* __restrict__ C,
    int M, int N, int K, int lda, int ldb, long sA, long sB, long sC, int kspl,
    u16* __restrict__ hbh, u16* __restrict__ hbl)
{
  __shared__ u16 Ash[2][128 * 32], Asl[2][128 * 32];
  __shared__ u16 Bsh[2][128 * 32], Bsl[2][128 * 32];
  const int z = blockIdx.z;
  const int bh = z / kspl;
  const int kc = z - bh * kspl;
  const u16* Azh = Ah + (long)bh * sA;
  const u16* Azl = Al + (long)bh * sA;
  const u16* Bzh = Bh + (long)bh * sB;
  const u16* Bzl = Bl + (long)bh * sB;
  const int brow = blockIdx.y << 7;
  const int bcol = blockIdx.x << 7;
  const int tid = threadIdx.x;
  const int wid = tid >> 6;
  const int lane = tid & 63;
  const int wr = (wid >> 1) << 6;
  const int wc = (wid & 1) << 6;

  f32x4 acc[4][4] = {};
  const int a0 = (wid << 11) + (lane << 4);

  auto stage = [&](int buf, int k0) {
#pragma unroll
    for (int c = 0; c < 2; ++c) {
      int ab = a0 + (c << 10);
      int lb = swz(ab);
      int row = ab >> 6;
      int kcol = (lb & 63) >> 1;
      long ao = (long)(brow + row) * lda + (k0 + kcol);
      long bo = (long)(bcol + row) * ldb + (k0 + kcol);
      int ld = (wid << 11) + (c << 10);
      gload16(Azh + ao, (char*)Ash[buf] + ld);
      gload16(Azl + ao, (char*)Asl[buf] + ld);
      gload16(Bzh + bo, (char*)Bsh[buf] + ld);
      gload16(Bzl + bo, (char*)Bsl[buf] + ld);
    }
  };

  const int kt = K / kspl;
  const int kbeg = kc * kt;
  const int nt = kt >> 5;
  stage(0, kbeg);
  __syncthreads();
  for (int t = 0; t < nt; ++t) {
    const int cur = t & 1;
    if (t + 1 < nt) stage(cur ^ 1, kbeg + ((t + 1) << 5));
    const int lr = lane & 15;
    const int lk = (lane >> 4) << 4;
    bf16x8 ah[4], al[4], bh_[4], bl[4];
#pragma unroll
    for (int m = 0; m < 4; ++m) {
      int off = swz(((wr + m * 16 + lr) << 6) + lk);
      ah[m] = *(const bf16x8*)((const char*)Ash[cur] + off);
      al[m] = *(const bf16x8*)((const char*)Asl[cur] + off);
    }
#pragma unroll
    for (int n = 0; n < 4; ++n) {
      int off = swz(((wc + n * 16 + lr) << 6) + lk);
      bh_[n] = *(const bf16x8*)((const char*)Bsh[cur] + off);
      bl[n] = *(const bf16x8*)((const char*)Bsl[cur] + off);
    }
#pragma unroll
    for (int m = 0; m < 4; ++m)
#pragma unroll
      for (int n = 0; n < 4; ++n) {
        acc[m][n] = __builtin_amdgcn_mfma_f32_16x16x32_bf16(al[m], bh_[n], acc[m][n], 0, 0, 0);
        acc[m][n] = __builtin_amdgcn_mfma_f32_16x16x32_bf16(ah[m], bl[n], acc[m][n], 0, 0, 0);
        acc[m][n] = __builtin_amdgcn_mfma_f32_16x16x32_bf16(ah[m], bh_[n], acc[m][n], 0, 0, 0);
      }
    if (t + 1 < nt) __syncthreads();
  }

  const int crow0 = brow + wr + ((lane >> 4) << 2);
  const int ccol0 = bcol + wc + (lane & 15);
  const long cbase = (long)bh * sC;
  if constexpr (MODE == 5) {
    const int pbase = (bcol + wc) >> 5;
#pragma unroll
    for (int m = 0; m < 4; ++m)
#pragma unroll
      for (int np = 0; np < 2; ++np)
#pragma unroll
        for (int j = 0; j < 4; ++j) {
          int r = crow0 + m * 16 + j;
          float g = acc[m][2 * np][j], u = acc[m][2 * np + 1][j];
          float h = siluf(g) * u;
          int hcol = ((pbase + np) << 4) + (lane & 15);
          u16 hh, ll; split2(h, hh, ll);
          hbh[(long)r * FF + hcol] = hh;
          hbl[(long)r * FF + hcol] = ll;
        }
  } else {
#pragma unroll
    for (int m = 0; m < 4; ++m)
#pragma unroll
      for (int n = 0; n < 4; ++n)
#pragma unroll
        for (int j = 0; j < 4; ++j) {
          long idx = cbase + (long)(crow0 + m * 16 + j) * N + (ccol0 + n * 16);
          if constexpr (MODE == 3) unsafeAtomicAdd(&C[idx], acc[m][n][j]);
          else C[idx] = acc[m][n][j];
        }
  }
}

// ---------------------------------------------------------------------------
// Batched indirect split GEMM over experts (blockIdx.z = e*kspl+kc).
// MODE 5: gather-A via perm[e], fused gu silu * comb -> hb rows cbase[e]+r.
// MODE 1: compact-A rows cbase[e]+r (clamped to cn-1), scatter-atomic f32.
// ---------------------------------------------------------------------------
template<int MODE>
__global__ __launch_bounds__(256) void gemm3i_nt(
    const u16* __restrict__ Ah, const u16* __restrict__ Al,
    const u16* __restrict__ Bh, const u16* __restrict__ Bl,
    float* __restrict__ C, int N, int K, int lda, int ldb, int ldc,
    const int* __restrict__ perm, const int* __restrict__ cnt,
    const int* __restrict__ cbase, int kspl, long wstride,
    u16* __restrict__ hbh, u16* __restrict__ hbl, const float* __restrict__ comb)
{
  const int z = blockIdx.z;
  const int e = z / kspl;
  const int kc = z - e * kspl;
  const int cn = cnt[e];
  const int brow = blockIdx.y << 7;
  if (brow >= cn) return;
  const int cb = cbase[e];
  const int* pe = perm + e * NTOK;
  const u16* Bhe = Bh + (long)e * wstride;
  const u16* Ble = Bl + (long)e * wstride;
  __shared__ u16 Ash[2][128 * 32], Asl[2][128 * 32];
  __shared__ u16 Bsh[2][128 * 32], Bsl[2][128 * 32];
  const int bcol = blockIdx.x << 7;
  const int tid = threadIdx.x;
  const int wid = tid >> 6;
  const int lane = tid & 63;
  const int wr = (wid >> 1) << 6;
  const int wc = (wid & 1) << 6;

  f32x4 acc[4][4] = {};
  const int a0 = (wid << 11) + (lane << 4);

  int arow[2];
#pragma unroll
  for (int c = 0; c < 2; ++c) {
    int ab = a0 + (c << 10);
    int row = ab >> 6;
    int g = brow + row;
    if constexpr (MODE == 5) {
      arow[c] = (g < cn) ? pe[g] : pe[brow];
    } else {
      arow[c] = cb + ((g < cn) ? g : (cn - 1));
    }
  }

  auto stage = [&](int buf, int k0) {
#pragma unroll
    for (int c = 0; c < 2; ++c) {
      int ab = a0 + (c << 10);
      int lb = swz(ab);
      int row = ab >> 6;
      int kcol = (lb & 63) >> 1;
      int ld = (wid << 11) + (c << 10);
      gload16(Ah + (long)arow[c] * lda + (k0 + kcol), (char*)Ash[buf] + ld);
      gload16(Al + (long)arow[c] * lda + (k0 + kcol), (char*)Asl[buf] + ld);
      long bo = (long)(bcol + row) * ldb + (k0 + kcol);
      gload16(Bhe + bo, (char*)Bsh[buf] + ld);
      gload16(Ble + bo, (char*)Bsl[buf] + ld);
    }
  };

  const int kt = K / kspl;
  const int kbeg = kc * kt;
  const int nt = kt >> 5;
  stage(0, kbeg);
  __syncthreads();
  for (int t = 0; t < nt; ++t) {
    const int cur = t & 1;
    if (t + 1 < nt) stage(cur ^ 1, kbeg + ((t + 1) << 5));
    const int lr = lane & 15;
    const int lk = (lane >> 4) << 4;
    bf16x8 ah[4], al[4], bh_[4], bl[4];
#pragma unroll
    for (int m = 0; m < 4; ++m) {
      int off = swz(((wr + m * 16 + lr) << 6) + lk);
      ah[m] = *(const bf16x8*)((const char*)Ash[cur] + off);
      al[m] = *(const bf16x8*)((const char*)Asl[cur] + off);
    }
#pragma unroll
    for (int n = 0; n < 4; ++n) {
      int off = swz(((wc + n * 16 + lr) << 6) + lk);
      bh_[n] = *(const bf16x8*)((const char*)Bsh[cur] + off);
      bl[n] = *(const bf16x8*)((const char*)Bsl[cur] + off);
    }
#pragma unroll
    for (int m = 0; m < 4; ++m)
#pragma unroll
      for (int n = 0; n < 4; ++n) {
        acc[m][n] = __builtin_amdgcn_mfma_f32_16x16x32_bf16(al[m], bh_[n], acc[m][n], 0, 0, 0);
        acc[m][n] = __builtin_amdgcn_mfma_f32_16x16x32_bf16(ah[m], bl[n], acc[m][n], 0, 0, 0);
        acc[m][n] = __builtin_amdgcn_mfma_f32_16x16x32_bf16(ah[m], bh_[n], acc[m][n], 0, 0, 0);
      }
    if (t + 1 < nt) __syncthreads();
  }

  const int crow0 = brow + wr + ((lane >> 4) << 2);
  const int ccol0 = bcol + wc + (lane & 15);
  if constexpr (MODE == 5) {
    const int pbase = (bcol + wc) >> 5;
#pragma unroll
    for (int m = 0; m < 4; ++m)
#pragma unroll
      for (int j = 0; j < 4; ++j) {
        int r = crow0 + m * 16 + j;
        if (r < cn) {
          float w = comb[pe[r] * 4 + e];
#pragma unroll
          for (int np = 0; np < 2; ++np) {
            float g = acc[m][2 * np][j], u = acc[m][2 * np + 1][j];
            float h = siluf(g) * u * w;
            int hcol = ((pbase + np) << 4) + (lane & 15);
            u16 hh, ll; split2(h, hh, ll);
            hbh[(long)(cb + r) * FF + hcol] = hh;
            hbl[(long)(cb + r) * FF + hcol] = ll;
          }
        }
      }
  } else {
#pragma unroll
    for (int m = 0; m < 4; ++m)
#pragma unroll
      for (int n = 0; n < 4; ++n)
#pragma unroll
        for (int j = 0; j < 4; ++j) {
          int r = crow0 + m * 16 + j;
          if (r < cn) {
            int col = ccol0 + n * 16;
            unsafeAtomicAdd(&C[(long)pe[r] * ldc + col], acc[m][n][j]);
          }
        }
  }
}

// ---------------------------------------------------------------------------
// Batched indirect plain bf16 GEMM over experts (layer-1).
// MODE 5: gather-A, fused gu -> hb rows cbase[e]+r. MODE 3: compact-A, scatter.
// ---------------------------------------------------------------------------
template<int MODE>
__global__ __launch_bounds__(256) void gemmi_nt(
    const u16* __restrict__ A, const u16* __restrict__ B, void* __restrict__ Cv,
    int N, int K, int lda, int ldb, int ldc,
    const int* __restrict__ perm, const int* __restrict__ cnt,
    const int* __restrict__ cbase, int kspl, long wstride,
    u16* __restrict__ hb, const float* __restrict__ comb)
{
  const int z = blockIdx.z;
  const int e = z / kspl;
  const int kc = z - e * kspl;
  const int cn = cnt[e];
  const int brow = blockIdx.y << 7;
  if (brow >= cn) return;
  const int cb = cbase[e];
  const int* pe = perm + e * NTOK;
  const u16* Be = B + (long)e * wstride;
  __shared__ u16 As[2][128 * 32];
  __shared__ u16 Bs[2][128 * 32];
  const int bcol = blockIdx.x << 7;
  const int tid = threadIdx.x;
  const int wid = tid >> 6;
  const int lane = tid & 63;
  const int wr = (wid >> 1) << 6;
  const int wc = (wid & 1) << 6;

  f32x4 acc[4][4] = {};
  const int a0 = (wid << 11) + (lane << 4);

  int arow[2];
#pragma unroll
  for (int c = 0; c < 2; ++c) {
    int ab = a0 + (c << 10);
    int row = ab >> 6;
    int g = brow + row;
    if constexpr (MODE == 5) {
      arow[c] = (g < cn) ? pe[g] : pe[brow];
    } else {
      arow[c] = cb + ((g < cn) ? g : (cn - 1));
    }
  }

  auto stage = [&](int buf, int k0) {
#pragma unroll
    for (int c = 0; c < 2; ++c) {
      int ab = a0 + (c << 10);
      int lb = swz(ab);
      int row = ab >> 6;
      int kcol = (lb & 63) >> 1;
      int ld = (wid << 11) + (c << 10);
      gload16(A + (long)arow[c] * lda + (k0 + kcol), (char*)As[buf] + ld);
      gload16(Be + (long)(bcol + row) * ldb + (k0 + kcol), (char*)Bs[buf] + ld);
    }
  };

  const int kt = K / kspl;
  const int kbeg = kc * kt;
  const int nt = kt >> 5;
  stage(0, kbeg);
  __syncthreads();
  for (int t = 0; t < nt; ++t) {
    const int cur = t & 1;
    if (t + 1 < nt) stage(cur ^ 1, kbeg + ((t + 1) << 5));
    bf16x8 af[4], bfr[4];
    const int lr = lane & 15;
    const int lk = (lane >> 4) << 4;
#pragma unroll
    for (int m = 0; m < 4; ++m)
      af[m] = *(const bf16x8*)((const char*)As[cur] + swz((((wr + m * 16 + lr) << 6) + lk)));
#pragma unroll
    for (int n = 0; n < 4; ++n)
      bfr[n] = *(const bf16x8*)((const char*)Bs[cur] + swz((((wc + n * 16 + lr) << 6) + lk)));
#pragma unroll
    for (int m = 0; m < 4; ++m)
#pragma unroll
      for (int n = 0; n < 4; ++n)
        acc[m][n] = __builtin_amdgcn_mfma_f32_16x16x32_bf16(af[m], bfr[n], acc[m][n], 0, 0, 0);
    if (t + 1 < nt) __syncthreads();
  }

  const int crow0 = brow + wr + ((lane >> 4) << 2);
  const int ccol0 = bcol + wc + (lane & 15);
  if constexpr (MODE == 5) {
    const int pbase = (bcol + wc) >> 5;
#pragma unroll
    for (int m = 0; m < 4; ++m)
#pragma unroll
      for (int j = 0; j < 4; ++j) {
        int r = crow0 + m * 16 + j;
        if (r < cn) {
          float w = comb[pe[r] * 4 + e];
#pragma unroll
          for (int np = 0; np < 2; ++np) {
            float g = acc[m][2 * np][j], u = acc[m][2 * np + 1][j];
            int hcol = ((pbase + np) << 4) + (lane & 15);
            hb[(long)(cb + r) * FF + hcol] = f2bf(siluf(g) * u * w);
          }
        }
      }
  } else {
#pragma unroll
    for (int m = 0; m < 4; ++m)
#pragma unroll
      for (int n = 0; n < 4; ++n)
#pragma unroll
        for (int j = 0; j < 4; ++j) {
          int r = crow0 + m * 16 + j;
          if (r < cn) {
            int col = ccol0 + n * 16;
            unsafeAtomicAdd((float*)Cv + (long)pe[r] * ldc + col, acc[m][n][j]);
          }
        }
  }
}

// ---------------------------------------------------------------------------
// Fused flash attention (round-4 64-row variant, unchanged).
// ---------------------------------------------------------------------------
__global__ __launch_bounds__(256, 2) void fattn_k(
    const u16* __restrict__ qh, const u16* __restrict__ ql,
    const u16* __restrict__ kh, const u16* __restrict__ kl,
    const u16* __restrict__ vth, const u16* __restrict__ vtl,
    u16* __restrict__ omh, u16* __restrict__ oml, float scale)
{
  __shared__ u16 Ksh[64 * 128], Ksl[64 * 128];
  __shared__ u16 Vsh[128 * 64], Vsl[128 * 64];
  const int bh = blockIdx.x;
  const int qt = blockIdx.y;
  const int tid = threadIdx.x, wid = tid >> 6, lane = tid & 63;
  const int lr = lane & 15, lg = lane >> 4;
  const int q0 = qt * 64 + wid * 16;
  const long bhoff = (long)bh * S_LEN * HDP;
  const u16* Qh = qh + bhoff;  const u16* Ql = ql + bhoff;
  const u16* Kgh = kh + bhoff; const u16* Kgl = kl + bhoff;
  const u16* Vgh = vth + bhoff; const u16* Vgl = vtl + bhoff;

  bf16x8 qfh[4], qfl[4];
#pragma unroll
  for (int kk = 0; kk < 4; ++kk) {
    long o = (long)(q0 + lr) * HDP + kk * 32 + lg * 8;
    qfh[kk] = *(const bf16x8*)(Qh + o);
    qfl[kk] = *(const bf16x8*)(Ql + o);
  }

  f32x4 oacc[6] = {};
  float rm[4], rls[4];
#pragma unroll
  for (int j = 0; j < 4; ++j) { rm[j] = -1e30f; rls[j] = 0.f; }

  for (int t = 0; t < S_LEN / 64; ++t) {
    __syncthreads();
#pragma unroll
    for (int c = 0; c < 4; ++c) {
      int off = (tid + (c << 8)) << 4;
      {
        int lb = off ^ ((((off >> 8) & 7)) << 4);
        int row = lb >> 8, colh = (lb & 255) >> 1;
        long src = (long)(t * 64 + row) * HDP + colh;
        gload16(Kgh + src, (char*)Ksh + off);
        gload16(Kgl + src, (char*)Ksl + off);
      }
      {
        int lb = off ^ ((((off >> 7) & 7)) << 4);
        int row = lb >> 7, colh = (lb & 127) >> 1;
        long src = (long)row * S_LEN + t * 64 + colh;
        gload16(Vgh + src, (char*)Vsh + off);
        gload16(Vgl + src, (char*)Vsl + off);
      }
    }
    __syncthreads();

    f32x4 sacc[4] = {};
#pragma unroll
    for (int kk = 0; kk < 4; ++kk) {
      bf16x8 kbh[4], kbl[4];
#pragma unroll
      for (int n = 0; n < 4; ++n) {
        int byte = ((n * 16 + lr) << 8) + (kk << 6) + (lg << 4);
        byte ^= ((byte >> 8) & 7) << 4;
        kbh[n] = *(const bf16x8*)((const char*)Ksh + byte);
        kbl[n] = *(const bf16x8*)((const char*)Ksl + byte);
      }
      __builtin_amdgcn_s_setprio(1);
#pragma unroll
      for (int n = 0; n < 4; ++n) {
        sacc[n] = __builtin_amdgcn_mfma_f32_16x16x32_bf16(qfl[kk], kbh[n], sacc[n], 0, 0, 0);
        sacc[n] = __builtin_amdgcn_mfma_f32_16x16x32_bf16(qfh[kk], kbl[n], sacc[n], 0, 0, 0);
        sacc[n] = __builtin_amdgcn_mfma_f32_16x16x32_bf16(qfh[kk], kbh[n], sacc[n], 0, 0, 0);
      }
      __builtin_amdgcn_s_setprio(0);
    }
    __syncthreads();

#pragma unroll
    for (int j = 0; j < 4; ++j) {
      float mx = fmaxf(fmaxf(sacc[0][j], sacc[1][j]),
                       fmaxf(sacc[2][j], sacc[3][j])) * scale;
      mx = fmaxf(mx, __shfl_xor(mx, 1));
      mx = fmaxf(mx, __shfl_xor(mx, 2));
      mx = fmaxf(mx, __shfl_xor(mx, 4));
      mx = fmaxf(mx, __shfl_xor(mx, 8));
      float mnew = fmaxf(rm[j], mx);
      float corr = __expf(rm[j] - mnew);
      rm[j] = mnew;
      float ps = 0.f;
#pragma unroll
      for (int n = 0; n < 4; ++n) {
        float p = __expf(sacc[n][j] * scale - mnew);
        sacc[n][j] = p; ps += p;
      }
      ps += __shfl_xor(ps, 1); ps += __shfl_xor(ps, 2);
      ps += __shfl_xor(ps, 4); ps += __shfl_xor(ps, 8);
      rls[j] = rls[j] * corr + ps;
#pragma unroll
      for (int n2 = 0; n2 < 6; ++n2) oacc[n2][j] *= corr;
    }

    char* Pwh = (char*)Ksh + (wid << 11);
    char* Pwl = (char*)Ksl + (wid << 11);
#pragma unroll
    for (int n = 0; n < 4; ++n)
#pragma unroll
      for (int j = 0; j < 4; ++j) {
        int row = lg * 4 + j;
        int byte = (row << 7) + ((n * 16 + lr) << 1);
        byte ^= ((byte >> 7) & 7) << 4;
        u16 h, l; split2(sacc[n][j], h, l);
        *(u16*)(Pwh + byte) = h;
        *(u16*)(Pwl + byte) = l;
      }
    bf16x8 pah[2], pal[2];
#pragma unroll
    for (int kk = 0; kk < 2; ++kk) {
      int byte = (lr << 7) + (kk << 6) + (lg << 4);
      byte ^= ((byte >> 7) & 7) << 4;
      pah[kk] = *(const bf16x8*)(Pwh + byte);
      pal[kk] = *(const bf16x8*)(Pwl + byte);
    }

#pragma unroll
    for (int kk = 0; kk < 2; ++kk) {
      bf16x8 vbh[6], vbl[6];
#pragma unroll
      for (int n2 = 0; n2 < 6; ++n2) {
        int byte = ((n2 * 16 + lr) << 7) + (kk << 6) + (lg << 4);
        byte ^= ((byte >> 7) & 7) << 4;
        vbh[n2] = *(const bf16x8*)((const char*)Vsh + byte);
        vbl[n2] = *(const bf16x8*)((const char*)Vsl + byte);
      }
      __builtin_amdgcn_s_setprio(1);
#pragma unroll
      for (int n2 = 0; n2 < 6; ++n2) {
        oacc[n2] = __builtin_amdgcn_mfma_f32_16x16x32_bf16(pal[kk], vbh[n2], oacc[n2], 0, 0, 0);
        oacc[n2] = __builtin_amdgcn_mfma_f32_16x16x32_bf16(pah[kk], vbl[n2], oacc[n2], 0, 0, 0);
        oacc[n2] = __builtin_amdgcn_mfma_f32_16x16x32_bf16(pah[kk], vbh[n2], oacc[n2], 0, 0, 0);
      }
      __builtin_amdgcn_s_setprio(0);
    }
  }

  const int b = bh >> 3, h = bh & 7;
#pragma unroll
  for (int j = 0; j < 4; ++j) {
    float inv = 1.0f / rls[j];
    int q = q0 + lg * 4 + j;
    long base = ((long)(b * S_LEN + q)) * DM + h * HDIM;
#pragma unroll
    for (int n2 = 0; n2 < 6; ++n2) {
      int d = n2 * 16 + lr;
      u16 hh, ll; split2(oacc[n2][j] * inv, hh, ll);
      omh[base + d] = hh; oml[base + d] = ll;
    }
  }
}

// ---------------------------------------------------------------------------
// fp32 [R][C] -> bf16 hi/lo [C][R] transpose+split, z-batched.
// ilv<0: linear rows; ilv in {0,1}: gate/up 16-row interleave.
// outl may be null (hi-only conversion for plain-bf16 consumers).
// ---------------------------------------------------------------------------
__global__ void wconv_t(const float* __restrict__ in, u16* __restrict__ outh,
                        u16* __restrict__ outl, int R, int C, int ilv,
                        long inStride, long outStride) {
  __shared__ float tile[32][33];
  long z = blockIdx.z;
  in += z * inStride; outh += z * outStride;
  if (outl) outl += z * outStride;
  int c0 = blockIdx.x << 5, r0 = blockIdx.y << 5;
  int tx = threadIdx.x;
  for (int rr = threadIdx.y; rr < 32; rr += 8)
    tile[rr][tx] = in[(long)(r0 + rr) * C + (c0 + tx)];
  __syncthreads();
  for (int rr = threadIdx.y; rr < 32; rr += 8) {
    u16 h, l; split2(tile[tx][rr], h, l);
    int f = c0 + rr;
    long orow = (ilv < 0) ? f : (((f >> 4) << 5) + (ilv << 4) + (f & 15));
    long o = orow * R + (r0 + tx);
    outh[o] = h;
    if (outl) outl[o] = l;
  }
}

__global__ __launch_bounds__(256) void ln_k(const float* __restrict__ in,
    const float* __restrict__ g, const float* __restrict__ b,
    float* __restrict__ outf, u16* __restrict__ outh, u16* __restrict__ outl) {
  int row = blockIdx.x;
  const float* x = in + (long)row * DM;
  int tid = threadIdx.x;
  float v[3], s = 0.f, ss = 0.f;
#pragma unroll
  for (int i = 0; i < 3; ++i) { v[i] = x[tid + (i << 8)]; s += v[i]; ss += v[i] * v[i]; }
  __shared__ float red[2][4];
  for (int o = 32; o; o >>= 1) { s += __shfl_down(s, o); ss += __shfl_down(ss, o); }
  int wid = tid >> 6, lane = tid & 63;
  if (!lane) { red[0][wid] = s; red[1][wid] = ss; }
  __syncthreads();
  s = red[0][0] + red[0][1] + red[0][2] + red[0][3];
  ss = red[1][0] + red[1][1] + red[1][2] + red[1][3];
  float mean = s * (1.f / DM);
  float var = ss * (1.f / DM) - mean * mean;
  float rs = rsqrtf(var + 1e-5f);
#pragma unroll
  for (int i = 0; i < 3; ++i) {
    int c = tid + (i << 8);
    float y = (v[i] - mean) * rs * g[c] + b[c];
    if (outf) outf[(long)row * DM + c] = y;
    if (outh) { u16 h, l; split2(y, h, l); outh[(long)row * DM + c] = h; outl[(long)row * DM + c] = l; }
  }
}

__global__ void rope_tables_k(float* __restrict__ cosT, float* __restrict__ sinT) {
  int s = blockIdx.x, d = threadIdx.x;
  int xc = s & 15, y = (s >> 4) & 15, t = s >> 8;
  int axis = d / 32, fi = d & 15;
  int coord = axis == 0 ? xc : (axis == 1 ? y : t);
  float inv = powf(10000.0f, -(float)fi / 16.0f);
  float ang = (float)coord * inv;
  cosT[s * HDIM + d] = cosf(ang);
  sinT[s * HDIM + d] = sinf(ang);
}

__global__ __launch_bounds__(256) void rope_apply_k(const float* __restrict__ qkv,
    const float* __restrict__ cosT, const float* __restrict__ sinT,
    u16* __restrict__ qh, u16* __restrict__ ql,
    u16* __restrict__ kh, u16* __restrict__ kl) {
  int bs = blockIdx.x;
  int b = bs >> 11, s = bs & 2047;
  const float* base = qkv + ((long)(b * S_LEN + s) * 3) * DM;
  for (int idx = threadIdx.x; idx < DM; idx += 256) {
    int h = idx / HDIM, d = idx - h * HDIM;
    float c = cosT[s * HDIM + d], sn = sinT[s * HDIM + d];
    int pair = (d < 48) ? idx + 48 : idx - 48;
    float qv = base[idx], kv = base[DM + idx];
    float qr = (d < 48) ? -base[pair] : base[pair];
    float kr = (d < 48) ? -base[DM + pair] : base[DM + pair];
    long o = ((long)(b * NHEAD + h) * S_LEN + s) * HDP + d;
    u16 hh, ll;
    split2(qv * c + qr * sn, hh, ll); qh[o] = hh; ql[o] = ll;
    split2(kv * c + kr * sn, hh, ll); kh[o] = hh; kl[o] = ll;
  }
  int t = threadIdx.x;
  int h = t >> 5, d = HDIM + (t & 31);
  long o = ((long)(b * NHEAD + h) * S_LEN + s) * HDP + d;
  qh[o] = 0; ql[o] = 0; kh[o] = 0; kl[o] = 0;
}

__global__ void v_transpose_k(const float* __restrict__ qkv,
                              u16* __restrict__ vh, u16* __restrict__ vl) {
  __shared__ float tile[32][33];
  int bh = blockIdx.z, b = bh >> 3, h = bh & 7;
  int s0 = blockIdx.x << 5, d0 = blockIdx.y << 5;
  int tx = threadIdx.x;
  for (int r = threadIdx.y; r < 32; r += 8) {
    int s = s0 + r, d = d0 + tx;
    float v = 0.f;
    if (d < HDIM) v = qkv[((long)(b * S_LEN + s) * 3 + 2) * DM + h * HDIM + d];
    tile[r][tx] = v;
  }
  __syncthreads();
  for (int r = threadIdx.y; r < 32; r += 8) {
    int d = d0 + r;
    u16 hh, ll; split2(tile[tx][r], hh, ll);
    long o = ((long)bh * HDP + d) * S_LEN + (s0 + tx);
    vh[o] = hh; vl[o] = ll;
  }
}

// Router: comb[tok][e] + top-2 bitmask per token.
__global__ __launch_bounds__(256) void router_k(const float* __restrict__ x,
    const float* __restrict__ gw, float* __restrict__ comb, int* __restrict__ mask) {
  int tok = blockIdx.x * 4 + (threadIdx.x >> 6);
  int lane = threadIdx.x & 63;
  const float* xr = x + (long)tok * DM;
  float a0 = 0, a1 = 0, a2 = 0, a3 = 0;
  for (int i = lane; i < DM; i += 64) {
    float xv = xr[i];
    const float* g = gw + i * 4;
    a0 += xv * g[0]; a1 += xv * g[1]; a2 += xv * g[2]; a3 += xv * g[3];
  }
  for (int o = 32; o; o >>= 1) {
    a0 += __shfl_down(a0, o); a1 += __shfl_down(a1, o);
    a2 += __shfl_down(a2, o); a3 += __shfl_down(a3, o);
  }
  if (lane == 0) {
    float p[4] = {a0, a1, a2, a3};
    float mx = fmaxf(fmaxf(p[0], p[1]), fmaxf(p[2], p[3]));
    float s = 0.f;
    for (int e = 0; e < 4; ++e) { p[e] = expf(p[e] - mx); s += p[e]; }
    for (int e = 0; e < 4; ++e) p[e] /= s;
    int i1 = 0;
    for (int e = 1; e < 4; ++e) if (p[e] > p[i1]) i1 = e;
    int i2 = -1;
    for (int e = 0; e < 4; ++e) if (e != i1 && (i2 < 0 || p[e] > p[i2])) i2 = e;
    float ssum = p[i1] + p[i2] + 1e-5f;
    float out[4] = {0, 0, 0, 0};
    out[i1] = p[i1] / ssum; out[i2] = p[i2] / ssum;
    for (int e = 0; e < 4; ++e) comb[tok * 4 + e] = out[e];
    mask[tok] = (1 << i1) | (1 << i2);
  }
}

// Deterministic per-expert compaction; one block per expert (grid = NEXP).
__global__ void scan_k(const int* __restrict__ mask, int* __restrict__ perm,
                       int* __restrict__ cnt) {
  __shared__ int sd[256];
  __shared__ int base;
  int tid = threadIdx.x;
  int e = blockIdx.x;
  if (tid == 0) base = 0;
  __syncthreads();
  for (int c = 0; c < NTOK / 256; ++c) {
    int tok = c * 256 + tid;
    int f = (mask[tok] >> e) & 1;
    sd[tid] = f;
    __syncthreads();
    for (int s = 1; s < 256; s <<= 1) {
      int v = (tid >= s) ? sd[tid - s] : 0;
      __syncthreads();
      sd[tid] += v;
      __syncthreads();
    }
    if (f) perm[e * NTOK + base + sd[tid] - 1] = tok;
    int tot = sd[255];
    __syncthreads();
    if (tid == 0) base += tot;
    __syncthreads();
  }
  if (tid == 0) cnt[e] = base;
}

__global__ void cbase_k(const int* __restrict__ cnt, int* __restrict__ cbase) {
  if (threadIdx.x == 0) {
    int b = 0;
    for (int e = 0; e < NEXP; ++e) { cbase[e] = b; b += cnt[e]; }
  }
}

__global__ void f2b_k(const float* __restrict__ src, u16* __restrict__ dst, long n) {
  long i = (long)blockIdx.x * 256 + threadIdx.x;
  if (i < n) dst[i] = f2bf(src[i]);
}

__global__ void f2bsplit_k(const float* __restrict__ src, u16* __restrict__ dh,
                           u16* __restrict__ dl, long n) {
  long i = (long)blockIdx.x * 256 + threadIdx.x;
  if (i < n) { u16 h, l; split2(src[i], h, l); dh[i] = h; dl[i] = l; }
}

extern "C" void kernel_launch(void* const* d_in, const int* in_sizes, int n_in,
                              void* d_out, int out_size, void* d_ws, size_t ws_size,
                              hipStream_t stream) {
  (void)in_sizes; (void)n_in; (void)out_size; (void)ws_size;
  const float* x_in  = (const float*)d_in[0];
  const float* ln1_g = (const float*)d_in[4];
  const float* ln1_b = (const float*)d_in[5];
  const float* w_qkv = (const float*)d_in[6];
  const float* w_out = (const float*)d_in[7];
  const float* gatew = (const float*)d_in[8];
  const float* eg    = (const float*)d_in[9];
  const float* eu    = (const float*)d_in[10];
  const float* ed    = (const float*)d_in[11];
  const float* sg    = (const float*)d_in[12];
  const float* su    = (const float*)d_in[13];
  const float* sd    = (const float*)d_in[14];
  const float* ln2_g = (const float*)d_in[15];
  const float* ln2_b = (const float*)d_in[16];

  float* xc = (float*)d_out;
  char* W = (char*)d_ws;
  size_t off = 0;
  auto alloc = [&](size_t bytes) {
    size_t o = off; off = (off + bytes + 255) & ~(size_t)255; return o;
  };
  // ---- persistent region (~14.3 MB) ----
  size_t o_cos  = alloc((size_t)S_LEN * HDIM * 4);
  size_t o_sin  = alloc((size_t)S_LEN * HDIM * 4);
  size_t o_xnh  = alloc((size_t)NTOK * DM * 2);
  size_t o_xnl  = alloc((size_t)NTOK * DM * 2);
  size_t o_comb = alloc((size_t)NTOK * 4 * 4);
  size_t o_mask = alloc((size_t)NTOK * 4);
  size_t o_perm = alloc((size_t)NEXP * NTOK * 4);
  size_t o_cnt  = alloc(256);
  size_t o_cb   = alloc(256);
  // ---- region A (union, 103.8 MB) ----
  const size_t EGU_B = (size_t)NEXP * FF2 * DM * 2;          // 37,748,736
  const size_t SGU_B = (size_t)FF2 * DM * 2;                 //  9,437,184
  const size_t SD_B  = (size_t)DM * FF * 2;                  //  4,718,592
  const size_t A_BYTES = 2 * EGU_B + 2 * SGU_B + 2 * SD_B;   // 103,809,024
  size_t oA = alloc(A_BYTES);
  // attention view of A
  size_t o_qkv = oA;                                          // 37,748,736 f32
  size_t o_qph = oA + (size_t)NTOK * 3 * DM * 4;
  size_t o_qpl = o_qph + (size_t)NBH * S_LEN * HDP * 2;
  size_t o_kph = o_qpl + (size_t)NBH * S_LEN * HDP * 2;
  size_t o_kpl = o_kph + (size_t)NBH * S_LEN * HDP * 2;
  size_t o_vth = o_kpl + (size_t)NBH * S_LEN * HDP * 2;
  size_t o_vtl = o_vth + (size_t)NBH * HDP * S_LEN * 2;
  size_t o_omh = o_vtl + (size_t)NBH * HDP * S_LEN * 2;
  size_t o_oml = o_omh + (size_t)NTOK * DM * 2;
  // moe view of A
  size_t o_eguh = oA;
  size_t o_egul = oA + EGU_B;
  size_t o_sguh = oA + 2 * EGU_B;
  size_t o_sgul = o_sguh + SGU_B;
  size_t o_sdh  = o_sgul + SGU_B;
  size_t o_sdl  = o_sdh + SD_B;
  size_t o_edh  = oA;                      // overlays egu (dead after expert-gu)
  size_t o_edl  = oA + (size_t)NEXP * DM * FF * 2;
  // ---- region H (union, 100.7 MB) ----
  const size_t H_BYTES = (size_t)2 * HBROWS * FF * 2;         // 100,663,296
  size_t oH = alloc(H_BYTES);
  size_t o_wqh = oH;
  size_t o_wql = o_wqh + (size_t)3 * DM * DM * 2;
  size_t o_woh = o_wql + (size_t)3 * DM * DM * 2;
  size_t o_wol = o_woh + (size_t)DM * DM * 2;
  size_t o_hbh = oH;
  size_t o_hbl = oH + (size_t)HBROWS * FF * 2;

  float* cosT = (float*)(W + o_cos);
  float* sinT = (float*)(W + o_sin);
  u16*   xnh  = (u16*)(W + o_xnh);
  u16*   xnl  = (u16*)(W + o_xnl);
  float* comb = (float*)(W + o_comb);
  int* maskb  = (int*)(W + o_mask);
  int* permb  = (int*)(W + o_perm);
  int* cntb   = (int*)(W + o_cnt);
  int* cbaseb = (int*)(W + o_cb);
  float* qkv  = (float*)(W + o_qkv);
  u16 *qph = (u16*)(W + o_qph), *qpl = (u16*)(W + o_qpl);
  u16 *kph = (u16*)(W + o_kph), *kpl = (u16*)(W + o_kpl);
  u16 *vth = (u16*)(W + o_vth), *vtl = (u16*)(W + o_vtl);
  u16 *omh = (u16*)(W + o_omh), *oml = (u16*)(W + o_oml);
  u16 *eguh = (u16*)(W + o_eguh), *egul = (u16*)(W + o_egul);
  u16 *sguh = (u16*)(W + o_sguh), *sgul = (u16*)(W + o_sgul);
  u16 *sdh = (u16*)(W + o_sdh), *sdl = (u16*)(W + o_sdl);
  u16 *edh = (u16*)(W + o_edh), *edl = (u16*)(W + o_edl);
  u16 *wqh = (u16*)(W + o_wqh), *wql = (u16*)(W + o_wql);
  u16 *woh = (u16*)(W + o_woh), *wol = (u16*)(W + o_wol);
  u16 *hbh = (u16*)(W + o_hbh), *hbl = (u16*)(W + o_hbl);

  const long ND = (long)NTOK * DM;
  const int gND = (int)((ND + 255) / 256);

  hipMemcpyAsync(xc, x_in, (size_t)ND * 4, hipMemcpyDeviceToDevice, stream);
  rope_tables_k<<<S_LEN, HDIM, 0, stream>>>(cosT, sinT);

  dim3 tb(32, 8, 1);
  for (int l = 0; l < 2; ++l) {
    const float* wqkv_l = w_qkv + (size_t)l * DM * 3 * DM;
    const float* wout_l = w_out + (size_t)l * DM * DM;
    const float* gw_l   = gatew + (size_t)l * DM * 4;
    const float* eg_l = eg + (size_t)l * NEXP * DM * FF;
    const float* eu_l = eu + (size_t)l * NEXP * DM * FF;
    const float* ed_l = ed + (size_t)l * NEXP * FF * DM;
    const float* sg_l = sg + (size_t)l * DM * FF;
    const float* su_l = su + (size_t)l * DM * FF;
    const float* sd_l = sd + (size_t)l * FF * DM;

    // attention weights into region H (hb is dead here)
    wconv_t<<<dim3(3 * DM / 32, DM / 32, 1), tb, 0, stream>>>(wqkv_l, wqh, wql, DM, 3 * DM, -1, 0, 0);
    wconv_t<<<dim3(DM / 32, DM / 32, 1), tb, 0, stream>>>(wout_l, woh, wol, DM, DM, -1, 0, 0);

    // --- attention (fp32-equivalent via bf16x3 + flash) ---
    ln_k<<<NTOK, 256, 0, stream>>>(xc, ln1_g + l * DM, ln1_b + l * DM, nullptr, xnh, xnl);
    gemm3_nt<0><<<dim3(3 * DM >> 7, NTOK >> 7, 1), 256, 0, stream>>>(
        xnh, xnl, wqh, wql, qkv, NTOK, 3 * DM, DM, DM, DM, 0, 0, 0, 1, nullptr, nullptr);
    rope_apply_k<<<NTOK, 256, 0, stream>>>(qkv, cosT, sinT, qph, qpl, kph, kpl);
    v_transpose_k<<<dim3(S_LEN / 32, HDP / 32, NBH), tb, 0, stream>>>(qkv, vth, vtl);
    fattn_k<<<dim3(NBH, S_LEN / 64), dim3(256), 0, stream>>>(
        qph, qpl, kph, kpl, vth, vtl, omh, oml, 0.10206207261596575f);
    gemm3_nt<3><<<dim3(DM >> 7, NTOK >> 7, 2), 256, 0, stream>>>(
        omh, oml, woh, wol, xc, NTOK, DM, DM, DM, DM, 0, 0, 0, 2, nullptr, nullptr);

    // --- router + deterministic expert compaction (CSR) ---
    router_k<<<NTOK / 4, 256, 0, stream>>>(xc, gw_l, comb, maskb);
    scan_k<<<NEXP, 256, 0, stream>>>(maskb, permb, cntb);
    cbase_k<<<1, 64, 0, stream>>>(cntb, cbaseb);

    // MoE weight conversion into region A (attention buffers dead now)
    if (l == 0) {
      wconv_t<<<dim3(FF / 32, DM / 32, 1), tb, 0, stream>>>(sg_l, sguh, sgul, DM, FF, 0, 0, 0);
      wconv_t<<<dim3(FF / 32, DM / 32, 1), tb, 0, stream>>>(su_l, sguh, sgul, DM, FF, 1, 0, 0);
      wconv_t<<<dim3(DM / 32, FF / 32, 1), tb, 0, stream>>>(sd_l, sdh, sdl, FF, DM, -1, 0, 0);
      wconv_t<<<dim3(FF / 32, DM / 32, NEXP), tb, 0, stream>>>(
          eg_l, eguh, egul, DM, FF, 0, (long)DM * FF, (long)FF2 * DM);
      wconv_t<<<dim3(FF / 32, DM / 32, NEXP), tb, 0, stream>>>(
          eu_l, eguh, egul, DM, FF, 1, (long)DM * FF, (long)FF2 * DM);

      f2bsplit_k<<<gND, 256, 0, stream>>>(xc, xnh, xnl, ND);
      // shared expert: fused gu+silu -> hb[0..NTOK), down atomic into xc
      gemm3_nt<5><<<dim3(FF2 >> 7, NTOK >> 7, 1), 256, 0, stream>>>(
          xnh, xnl, sguh, sgul, nullptr, NTOK, FF2, DM, DM, DM, 0, 0, 0, 1, hbh, hbl);
      gemm3_nt<3><<<dim3(DM >> 7, NTOK >> 7, 4), 256, 0, stream>>>(
          hbh, hbl, sdh, sdl, xc, NTOK, DM, FF, FF, FF, 0, 0, 0, 4, nullptr, nullptr);
      // all 4 routed experts batched (z = expert)
      gemm3i_nt<5><<<dim3(FF2 >> 7, NTOK >> 7, NEXP), 256, 0, stream>>>(
          xnh, xnl, eguh, egul, nullptr, FF2, DM, DM, DM, FF2,
          permb, cntb, cbaseb, 1, (long)FF2 * DM, hbh, hbl, comb);
      // ed conversion overlays dead egu region, then batched down-scatter
      wconv_t<<<dim3(DM / 32, FF / 32, NEXP), tb, 0, stream>>>(
          ed_l, edh, edl, FF, DM, -1, (long)FF * DM, (long)DM * FF);
      gemm3i_nt<1><<<dim3(DM >> 7, NTOK >> 7, NEXP * 2), 256, 0, stream>>>(
          hbh, hbl, edh, edl, xc, DM, FF, FF, FF, DM,
          permb, cntb, cbaseb, 2, (long)DM * FF, nullptr, nullptr, nullptr);
    } else {
      // layer-1: plain bf16 path -> convert hi only (skip lo writes)
      wconv_t<<<dim3(FF / 32, DM / 32, 1), tb, 0, stream>>>(sg_l, sguh, nullptr, DM, FF, 0, 0, 0);
      wconv_t<<<dim3(FF / 32, DM / 32, 1), tb, 0, stream>>>(su_l, sguh, nullptr, DM, FF, 1, 0, 0);
      wconv_t<<<dim3(DM / 32, FF / 32, 1), tb, 0, stream>>>(sd_l, sdh, nullptr, FF, DM, -1, 0, 0);
      wconv_t<<<dim3(FF / 32, DM / 32, NEXP), tb, 0, stream>>>(
          eg_l, eguh, nullptr, DM, FF, 0, (long)DM * FF, (long)FF2 * DM);
      wconv_t<<<dim3(FF / 32, DM / 32, NEXP), tb, 0, stream>>>(
          eu_l, eguh, nullptr, DM, FF, 1, (long)DM * FF, (long)FF2 * DM);

      f2b_k<<<gND, 256, 0, stream>>>(xc, xnh, ND);
      gemm_nt<5><<<dim3(FF2 >> 7, NTOK >> 7, 1), 256, 0, stream>>>(
          xnh, sguh, nullptr, NTOK, FF2, DM, DM, DM, 0, 0, 0, 1, hbh);
      gemm_nt<3><<<dim3(DM >> 7, NTOK >> 7, 4), 256, 0, stream>>>(
          hbh, sdh, xc, NTOK, DM, FF, FF, FF, 0, 0, 0, 4, nullptr);
      gemmi_nt<5><<<dim3(FF2 >> 7, NTOK >> 7, NEXP), 256, 0, stream>>>(
          xnh, eguh, nullptr, FF2, DM, DM, DM, FF2,
          permb, cntb, cbaseb, 1, (long)FF2 * DM, hbh, comb);
      wconv_t<<<dim3(DM / 32, FF / 32, NEXP), tb, 0, stream>>>(
          ed_l, edh, nullptr, FF, DM, -1, (long)FF * DM, (long)DM * FF);
      gemmi_nt<3><<<dim3(DM >> 7, NTOK >> 7, NEXP * 2), 256, 0, stream>>>(
          hbh, edh, xc, DM, FF, FF, FF, DM,
          permb, cntb, cbaseb, 2, (long)DM * FF, nullptr, nullptr);
    }
    ln_k<<<NTOK, 256, 0, stream>>>(xc, ln2_g + l * DM, ln2_b + l * DM, xc, nullptr, nullptr);
  }
}